// Round 9
// baseline (2864.363 us; speedup 1.0000x reference)
//
#include <hip/hip_runtime.h>
#include <hip/hip_bf16.h>
#include <cmath>

#define DEV __device__ __forceinline__

typedef short s16x8 __attribute__((ext_vector_type(8)));
typedef short s16x4 __attribute__((ext_vector_type(4)));
typedef float f32x4 __attribute__((ext_vector_type(4)));
typedef int   i32x2 __attribute__((ext_vector_type(2)));

DEV unsigned short f2bu(float x){
  __hip_bfloat16 h = __float2bfloat16(x);
  return *reinterpret_cast<unsigned short*>(&h);
}
DEV float bs2f(unsigned short v){ return __uint_as_float(((unsigned)v)<<16); }
DEV float bs2f(short v){ return bs2f((unsigned short)v); }

DEV unsigned cvtpk(float lo, float hi){
  unsigned r;
  asm("v_cvt_pk_bf16_f32 %0, %1, %2" : "=v"(r) : "v"(lo), "v"(hi));
  return r;
}
DEV float dppx1(float v){   // value from lane^1 (quad_perm 1,0,3,2)
  int r = __builtin_amdgcn_mov_dpp(__float_as_int(v), 0xB1, 0xF, 0xF, true);
  return __int_as_float(r);
}

#define BAR() do { asm volatile("s_waitcnt lgkmcnt(0)" ::: "memory"); \
                   __builtin_amdgcn_s_barrier(); \
                   __builtin_amdgcn_sched_barrier(0); } while(0)

// swizzled [R][64] bf16 tile helpers (row stride 128B, byte ^= (row&7)<<4)
DEV int swzo(int row, int col){
  return (row*128 + ((col*2) ^ ((row&7)<<4))) >> 1;
}
DEV s16x8 ldfrag(const short* tile, int t16, int lane, int kk){
  int row = t16 + (lane & 15);
  int c0  = (kk<<5) + ((lane>>4)<<3);
  int off = (row*128 + ((c0<<1) ^ ((row&7)<<4))) >> 1;
  return *(const s16x8*)(tile + off);
}
// swizzled [64][256] bf16 (V^T) tile: row stride 512B
DEV int swzv(int d, int t){
  return (d*512 + ((t*2) ^ ((d&7)<<4))) >> 1;
}

// ---------------------------------------------------------------------------
// K0: weight prep. Wqkv_t[192][64], Wo_t/W1_t/W2_t[64][64] (bf16 transposed),
//     Wg_t[3][2][64c][64k] (gate slices xt:0.. / Axt:192..) for k35,
//     Wg_h[3][2][64c][64k] (gate slices h:64.. / Ah:256..) for k4.
// ---------------------------------------------------------------------------
__global__ void k0_prep(const float* __restrict__ Wqkv, const float* __restrict__ Wo,
                        const float* __restrict__ W1, const float* __restrict__ W2,
                        const float* __restrict__ Wz, const float* __restrict__ Wr,
                        const float* __restrict__ Wc,
                        short* __restrict__ Wqkv_t, short* __restrict__ Wo_t,
                        short* __restrict__ W1_t, short* __restrict__ W2_t,
                        short* __restrict__ Wg_t, short* __restrict__ Wg_h)
{
  int t = blockIdx.x*256 + threadIdx.x;
  if (t < 12288){ int nn=t>>6, k=t&63; Wqkv_t[t]=(short)f2bu(Wqkv[k*192+nn]); }
  else if (t < 16384){ int e=t-12288; int nn=e>>6,k=e&63; Wo_t[e]=(short)f2bu(Wo[k*64+nn]); }
  else if (t < 20480){ int e=t-16384; int nn=e>>6,k=e&63; W1_t[e]=(short)f2bu(W1[k*64+nn]); }
  else if (t < 24576){ int e=t-20480; int nn=e>>6,k=e&63; W2_t[e]=(short)f2bu(W2[k*64+nn]); }
  else if (t < 49152){
    int e=t-24576;
    int g=e>>13, rem=e&8191, s=rem>>12, rem2=rem&4095, c=rem2>>6, k=rem2&63;
    const float* Wg = (g==0)?Wz:((g==1)?Wr:Wc);
    Wg_t[e] = (short)f2bu(Wg[((s?192:0)+k)*64 + c]);
  }
  else if (t < 73728){
    int e=t-49152;
    int g=e>>13, rem=e&8191, s=rem>>12, rem2=rem&4095, c=rem2>>6, k=rem2&63;
    const float* Wg = (g==0)?Wz:((g==1)?Wr:Wc);
    Wg_h[e] = (short)f2bu(Wg[((s?256:64)+k)*64 + c]);
  }
}

// ---------------------------------------------------------------------------
// K1: positional encoding pe[b,t,64], te-derived gate vectors U[b,t,6,64],
//     decay. 4 (b,t) pairs per 256-thread block: weight reads shared 4-way.
// ---------------------------------------------------------------------------
__global__ void k1_pe_u(const float* __restrict__ x, const float* __restrict__ delta_t,
                        const float* __restrict__ Wz, const float* __restrict__ bz,
                        const float* __restrict__ Wr, const float* __restrict__ br,
                        const float* __restrict__ Wc, const float* __restrict__ bc,
                        float* __restrict__ pe, float* __restrict__ U, float* __restrict__ decay)
{
  const int q  = threadIdx.x >> 6;          // sub-block 0..3
  const int d  = threadIdx.x & 63;          // 0..63
  const int bt = blockIdx.x*4 + q;          // b*256 + t
  __shared__ float pes[4][64];
  float tmv = x[(size_t)bt*129 + 128];      // times
  int j = d & 31;
  float ts = exp2f((float)j * (8.0f/31.0f));   // 256^(j/31)
  float st = tmv / ts;
  float v = (d < 32) ? sinf(st) : cosf(st);
  pes[q][d] = v;
  pe[(size_t)bt*64 + d] = v;
  __syncthreads();
  float a0=bz[d], a1=0.f, a2=br[d], a3=0.f, a4=bc[d], a5=0.f;
  for (int k=0;k<64;k++){
    float p = pes[q][k];
    a0 = fmaf(p, Wz[(128+k)*64+d], a0);
    a1 = fmaf(p, Wz[(320+k)*64+d], a1);
    a2 = fmaf(p, Wr[(128+k)*64+d], a2);
    a3 = fmaf(p, Wr[(320+k)*64+d], a3);
    a4 = fmaf(p, Wc[(128+k)*64+d], a4);
    a5 = fmaf(p, Wc[(320+k)*64+d], a5);
  }
  float* u = U + (size_t)bt*384;
  u[d]=a0; u[64+d]=a1; u[128+d]=a2; u[192+d]=a3; u[256+d]=a4; u[320+d]=a5;
  if (d==0) decay[bt] = expf(-fmaxf(delta_t[bt], 0.f));
}

// ---------------------------------------------------------------------------
// K2a: qf = xf@WQ_f, kf = xf@WK_f   (xf[b,n,t] = nufft[b,1,t,n])
// ---------------------------------------------------------------------------
__global__ void k2a_qfkf(const float* __restrict__ nufft, const float* __restrict__ WQf,
                         const float* __restrict__ WKf, float* __restrict__ qf, float* __restrict__ kf)
{
  const int bn = blockIdx.x, b = bn>>6, n = bn&63;
  const int u = threadIdx.x;  // 0..255
  __shared__ float xs[256];
  xs[u] = nufft[ ((((size_t)b*2)+1)*256 + u)*64 + n ];
  __syncthreads();
  float aq=0.f, ak=0.f;
  for (int t=0;t<256;t++){
    float xv = xs[t];
    aq = fmaf(xv, WQf[t*256+u], aq);
    ak = fmaf(xv, WKf[t*256+u], ak);
  }
  qf[(size_t)bn*256+u]=aq;
  kf[(size_t)bn*256+u]=ak;
}

// ---------------------------------------------------------------------------
// K2b: per-batch S=relu(qf·kf)/16, row-softmax -> soft[b,64,64]
// ---------------------------------------------------------------------------
__launch_bounds__(256, 1)
__global__ void k2b_soft(const float* __restrict__ qf, const float* __restrict__ kf,
                         float* __restrict__ soft)
{
  const int b = blockIdx.x, tid = threadIdx.x;
  __shared__ float qs[64*257];
  __shared__ float ksh[64*257];
  __shared__ float Ss[64*65];
  const float* qb = qf + ((size_t)b<<14);
  const float* kb = kf + ((size_t)b<<14);
  for (int e=tid; e<16384; e+=256){
    int r=e>>8, c=e&255;
    qs[r*257+c]=qb[e];
    ksh[r*257+c]=kb[e];
  }
  __syncthreads();
  const int n = tid>>2, m0 = (tid&3)<<4;
  float acc[16];
  #pragma unroll
  for (int i=0;i<16;i++) acc[i]=0.f;
  for (int t=0;t<256;t++){
    float qv = qs[n*257+t];
    #pragma unroll
    for (int i=0;i<16;i++) acc[i] = fmaf(qv, ksh[(m0+i)*257+t], acc[i]);
  }
  #pragma unroll
  for (int i=0;i<16;i++) Ss[n*65+m0+i] = fmaxf(acc[i],0.f)*(1.f/16.f);
  __syncthreads();
  if (tid < 64){
    float mx=-1e30f;
    for (int m=0;m<64;m++) mx=fmaxf(mx, Ss[tid*65+m]);
    float s=0.f;
    for (int m=0;m<64;m++) s += expf(Ss[tid*65+m]-mx);
    float inv=1.f/s;
    for (int m=0;m<64;m++) soft[((size_t)b<<12)+(tid<<6)+m] = expf(Ss[tid*65+m]-mx)*inv;
  }
}

// ---------------------------------------------------------------------------
// K2c: A = 0.5(sm+sm^T) with sm = softmax(0.5(A0+A0^T)); A0 = mean_b soft.
// ---------------------------------------------------------------------------
__global__ void k2c_A(const float* __restrict__ soft, short* __restrict__ Abf,
                      float* __restrict__ rs_out)
{
  const int tid = threadIdx.x; // 256
  __shared__ float A0[64*65];
  __shared__ float A1[64*65];
  for (int e=tid; e<4096; e+=256){
    int nn=e>>6, mm=e&63;
    float s=0.f;
    #pragma unroll
    for (int b=0;b<16;b++) s += soft[((size_t)b<<12)+e];
    A0[nn*65+mm] = s*(1.f/16.f);
  }
  __syncthreads();
  for (int e=tid; e<4096; e+=256){
    int nn=e>>6, mm=e&63;
    A1[nn*65+mm] = 0.5f*(A0[nn*65+mm]+A0[mm*65+nn]);
  }
  __syncthreads();
  if (tid < 64){
    float mx=-1e30f;
    for (int m=0;m<64;m++) mx=fmaxf(mx, A1[tid*65+m]);
    float s=0.f;
    for (int m=0;m<64;m++) s += expf(A1[tid*65+m]-mx);
    float inv=1.f/s;
    for (int m=0;m<64;m++) A0[tid*65+m] = expf(A1[tid*65+m]-mx)*inv;
  }
  __syncthreads();
  for (int e=tid; e<4096; e+=256){
    int nn=e>>6, mm=e&63;
    float a = 0.5f*(A0[nn*65+mm]+A0[mm*65+nn]);
    A1[nn*65+mm] = a;
    Abf[e] = (short)f2bu(a);
  }
  __syncthreads();
  if (tid < 64){
    float s=0.f;
    for (int m=0;m<64;m++) s += A1[tid*65+m];
    rs_out[tid]=s;
  }
}

// ---------------------------------------------------------------------------
// K3: per-(b,n) transformer head via MFMA -> x_tat (bf16).
// ---------------------------------------------------------------------------
__launch_bounds__(512, 1)
__global__ void k3_former(const float* __restrict__ x, const float* __restrict__ pe_g,
    const float* __restrict__ proj_w, const float* __restrict__ proj_b,
    const short* __restrict__ Wqkv_t, const float* __restrict__ bqkv,
    const short* __restrict__ Wo_t, const float* __restrict__ bo,
    const float* __restrict__ ln1g, const float* __restrict__ ln1b,
    const short* __restrict__ W1_t, const float* __restrict__ b1,
    const short* __restrict__ W2_t, const float* __restrict__ b2,
    const float* __restrict__ ln2g, const float* __restrict__ ln2b,
    const int* __restrict__ lengths, unsigned short* __restrict__ xtat)
{
  const int bn = blockIdx.x, b = bn>>6, n = bn&63;
  const int tid = threadIdx.x, w = tid>>6, lane = tid&63;
  const int l15 = lane&15, lhi = lane>>4;
  __shared__ short tp_s[16384];
  __shared__ short q_s[16384];
  __shared__ short k_s[16384];
  __shared__ short v_t[16384];
  __shared__ float valr[256], obsr[256];

  int len = lengths[b]; if (len<1) len=1;
  const int LT = (len+15)>>4;
  const int KB = (len+63)>>6;

  if (tid < 256){
    const float* xr = x + ((size_t)b*256+tid)*129;
    valr[tid]=xr[n]; obsr[tid]=xr[64+n];
  }
  for (int e=tid; e<16384; e+=512) v_t[e]=0;
  __syncthreads();

  const int nrows = LT<<4;
  for (int e=tid; e<(nrows<<6); e+=512){
    int t=e>>6, d=e&63;
    float ti = fmaf(valr[t],proj_w[d], fmaf(obsr[t],proj_w[64+d], proj_b[d]))
             + pe_g[(((size_t)b<<8)+t)*64+d];
    tp_s[swzo(t,d)] = (short)f2bu(ti);
  }
  __syncthreads();

  // ---- QKV ----
  #pragma unroll
  for (int j=0;j<2;j++){
    const int rt = w + (j<<3);
    if (rt < LT){
      s16x8 a0 = ldfrag(tp_s, rt<<4, lane, 0);
      s16x8 a1 = ldfrag(tp_s, rt<<4, lane, 1);
      const int rb = (rt<<4) + (lhi<<2);
      #pragma unroll
      for (int nt=0; nt<12; nt++){
        const short* wb = Wqkv_t + (((nt<<4)+l15)<<6) + (lhi<<3);
        s16x8 b0 = *(const s16x8*)wb;
        s16x8 b1v = *(const s16x8*)(wb+32);
        float bias = bqkv[(nt<<4)+l15];
        f32x4 acc = {bias,bias,bias,bias};
        acc = __builtin_amdgcn_mfma_f32_16x16x32_bf16(a0,b0,acc,0,0,0);
        acc = __builtin_amdgcn_mfma_f32_16x16x32_bf16(a1,b1v,acc,0,0,0);
        const int col = ((nt&3)<<4) + l15;
        if (nt<4){
          #pragma unroll
          for(int i=0;i<4;i++) q_s[swzo(rb+i,col)] = (short)f2bu(acc[i]*0.125f);
        } else if (nt<8){
          #pragma unroll
          for(int i=0;i<4;i++) k_s[swzo(rb+i,col)] = (short)f2bu(acc[i]);
        } else {
          #pragma unroll
          for(int i=0;i<4;i++) v_t[swzv(col, rb+i)] = (short)f2bu(acc[i]);
        }
      }
    }
  }
  __syncthreads();

  // ---- attention ----
  f32x4 Oac[2][4];
  float rsum[2][4];
  #pragma unroll
  for(int j=0;j<2;j++)
    #pragma unroll
    for(int dt=0;dt<4;dt++) Oac[j][dt]=(f32x4){0.f,0.f,0.f,0.f};
  #pragma unroll
  for(int j=0;j<2;j++)
    #pragma unroll
    for(int i=0;i<4;i++) rsum[j][i]=0.f;

  for (int kb=0; kb<KB; kb++){
    s16x8 kf[4][2];
    #pragma unroll
    for (int ct=0;ct<4;ct++){
      kf[ct][0]=ldfrag(k_s, (((kb<<2)+ct)<<4), lane, 0);
      kf[ct][1]=ldfrag(k_s, (((kb<<2)+ct)<<4), lane, 1);
    }
    #pragma unroll
    for (int j=0;j<2;j++){
      const int rt=w+(j<<3);
      if (rt < LT){
        s16x8 q0=ldfrag(q_s, rt<<4, lane, 0);
        s16x8 q1=ldfrag(q_s, rt<<4, lane, 1);
        const int rb=(rt<<4)+(lhi<<2);
        #pragma unroll
        for (int ct=0;ct<4;ct++){
          f32x4 s={0.f,0.f,0.f,0.f};
          s=__builtin_amdgcn_mfma_f32_16x16x32_bf16(q0,kf[ct][0],s,0,0,0);
          s=__builtin_amdgcn_mfma_f32_16x16x32_bf16(q1,kf[ct][1],s,0,0,0);
          const int key=(kb<<6)+(ct<<4)+l15;
          #pragma unroll
          for(int i=0;i<4;i++){
            float p = (key<len) ? __expf(s[i]) : 0.f;
            rsum[j][i]+=p;
            tp_s[swzo(rb+i,(ct<<4)+l15)] = (short)f2bu(p);
          }
        }
      }
    }
    __syncthreads();
    s16x8 vf[4][2];
    #pragma unroll
    for (int dt=0;dt<4;dt++){
      const int d=(dt<<4)+l15;
      #pragma unroll
      for (int kk=0;kk<2;kk++){
        const int k0=(kk<<5)+(lhi<<3);
        vf[dt][kk] = *(const s16x8*)(v_t + swzv(d, (kb<<6)+k0));
      }
    }
    #pragma unroll
    for (int j=0;j<2;j++){
      const int rt=w+(j<<3);
      if (rt < LT){
        s16x8 p0=ldfrag(tp_s, rt<<4, lane, 0);
        s16x8 p1=ldfrag(tp_s, rt<<4, lane, 1);
        #pragma unroll
        for (int dt=0;dt<4;dt++){
          Oac[j][dt]=__builtin_amdgcn_mfma_f32_16x16x32_bf16(p0,vf[dt][0],Oac[j][dt],0,0,0);
          Oac[j][dt]=__builtin_amdgcn_mfma_f32_16x16x32_bf16(p1,vf[dt][1],Oac[j][dt],0,0,0);
        }
      }
    }
    __syncthreads();
  }

  float inv[2][4];
  #pragma unroll
  for(int j=0;j<2;j++)
    #pragma unroll
    for(int i=0;i<4;i++){
      float v=rsum[j][i];
      v += __shfl_xor(v,1); v += __shfl_xor(v,2); v += __shfl_xor(v,4); v += __shfl_xor(v,8);
      inv[j][i]=1.f/v;
    }

  #pragma unroll
  for (int j=0;j<2;j++){
    const int rt=w+(j<<3);
    if (rt < LT){
      const int rb=(rt<<4)+(lhi<<2);
      #pragma unroll
      for (int dt=0;dt<4;dt++)
        #pragma unroll
        for (int i=0;i<4;i++)
          q_s[swzo(rb+i,(dt<<4)+l15)] = (short)f2bu(Oac[j][dt][i]*inv[j][i]);
    }
  }
  __syncthreads();

  f32x4 h1[2][4];
  #pragma unroll
  for (int j=0;j<2;j++){
    const int rt=w+(j<<3);
    if (rt < LT){
      s16x8 a0=ldfrag(q_s, rt<<4, lane, 0);
      s16x8 a1=ldfrag(q_s, rt<<4, lane, 1);
      const int rb=(rt<<4)+(lhi<<2);
      #pragma unroll
      for (int dt=0;dt<4;dt++){
        const int col=(dt<<4)+l15;
        const short* wb = Wo_t + (col<<6) + (lhi<<3);
        s16x8 b0=*(const s16x8*)wb, b1v=*(const s16x8*)(wb+32);
        float bias=bo[col];
        f32x4 acc={bias,bias,bias,bias};
        acc=__builtin_amdgcn_mfma_f32_16x16x32_bf16(a0,b0,acc,0,0,0);
        acc=__builtin_amdgcn_mfma_f32_16x16x32_bf16(a1,b1v,acc,0,0,0);
        #pragma unroll
        for(int i=0;i<4;i++){
          const int row=rb+i;
          acc[i]+= fmaf(valr[row],proj_w[col], fmaf(obsr[row],proj_w[64+col], proj_b[col]))
                 + pe_g[(((size_t)b<<8)+row)*64+col];
        }
        h1[j][dt]=acc;
      }
      f32x4 mu, rsq;
      #pragma unroll
      for(int i=0;i<4;i++){
        float sv = h1[j][0][i]+h1[j][1][i]+h1[j][2][i]+h1[j][3][i];
        sv += __shfl_xor(sv,1); sv+=__shfl_xor(sv,2); sv+=__shfl_xor(sv,4); sv+=__shfl_xor(sv,8);
        mu[i]=sv*(1.f/64.f);
      }
      #pragma unroll
      for(int i=0;i<4;i++){
        float sv=0.f;
        #pragma unroll
        for(int dt=0;dt<4;dt++){ float c=h1[j][dt][i]-mu[i]; sv=fmaf(c,c,sv); }
        sv += __shfl_xor(sv,1); sv+=__shfl_xor(sv,2); sv+=__shfl_xor(sv,4); sv+=__shfl_xor(sv,8);
        rsq[i]=1.f/sqrtf(sv*(1.f/64.f)+1e-5f);
      }
      #pragma unroll
      for(int dt=0;dt<4;dt++){
        const int col=(dt<<4)+l15;
        float g=ln1g[col], bb=ln1b[col];
        #pragma unroll
        for(int i=0;i<4;i++){
          float hv=(h1[j][dt][i]-mu[i])*rsq[i]*g+bb;
          h1[j][dt][i]=hv;
          k_s[swzo(rb+i,col)] = (short)f2bu(hv);
        }
      }
    }
  }
  __syncthreads();

  #pragma unroll
  for (int j=0;j<2;j++){
    const int rt=w+(j<<3);
    if (rt < LT){
      s16x8 a0=ldfrag(k_s, rt<<4, lane, 0);
      s16x8 a1=ldfrag(k_s, rt<<4, lane, 1);
      const int rb=(rt<<4)+(lhi<<2);
      #pragma unroll
      for (int dt=0;dt<4;dt++){
        const int col=(dt<<4)+l15;
        const short* wb = W1_t + (col<<6)+(lhi<<3);
        s16x8 b0=*(const s16x8*)wb, b1v=*(const s16x8*)(wb+32);
        float bias=b1[col];
        f32x4 acc={bias,bias,bias,bias};
        acc=__builtin_amdgcn_mfma_f32_16x16x32_bf16(a0,b0,acc,0,0,0);
        acc=__builtin_amdgcn_mfma_f32_16x16x32_bf16(a1,b1v,acc,0,0,0);
        #pragma unroll
        for(int i=0;i<4;i++) tp_s[swzo(rb+i,col)]=(short)f2bu(fmaxf(acc[i],0.f));
      }
    }
  }
  __syncthreads();

  #pragma unroll
  for (int j=0;j<2;j++){
    const int rt=w+(j<<3);
    if (rt < LT){
      s16x8 a0=ldfrag(tp_s, rt<<4, lane, 0);
      s16x8 a1=ldfrag(tp_s, rt<<4, lane, 1);
      const int rb=(rt<<4)+(lhi<<2);
      f32x4 to[4];
      #pragma unroll
      for (int dt=0;dt<4;dt++){
        const int col=(dt<<4)+l15;
        const short* wb = W2_t + (col<<6)+(lhi<<3);
        s16x8 b0=*(const s16x8*)wb, b1v=*(const s16x8*)(wb+32);
        float bias=b2[col];
        f32x4 acc={bias,bias,bias,bias};
        acc=__builtin_amdgcn_mfma_f32_16x16x32_bf16(a0,b0,acc,0,0,0);
        acc=__builtin_amdgcn_mfma_f32_16x16x32_bf16(a1,b1v,acc,0,0,0);
        acc += h1[j][dt];
        to[dt]=acc;
      }
      f32x4 mu, rsq;
      #pragma unroll
      for(int i=0;i<4;i++){
        float sv = to[0][i]+to[1][i]+to[2][i]+to[3][i];
        sv += __shfl_xor(sv,1); sv+=__shfl_xor(sv,2); sv+=__shfl_xor(sv,4); sv+=__shfl_xor(sv,8);
        mu[i]=sv*(1.f/64.f);
      }
      #pragma unroll
      for(int i=0;i<4;i++){
        float sv=0.f;
        #pragma unroll
        for(int dt=0;dt<4;dt++){ float c=to[dt][i]-mu[i]; sv=fmaf(c,c,sv); }
        sv += __shfl_xor(sv,1); sv+=__shfl_xor(sv,2); sv+=__shfl_xor(sv,4); sv+=__shfl_xor(sv,8);
        rsq[i]=1.f/sqrtf(sv*(1.f/64.f)+1e-5f);
      }
      #pragma unroll
      for(int dt=0;dt<4;dt++){
        const int col=(dt<<4)+l15;
        float g=ln2g[col], bb=ln2b[col];
        #pragma unroll
        for(int i=0;i<4;i++){
          const int row=rb+i;
          if (row < len){
            float tv=(to[dt][i]-mu[i])*rsq[i]*g+bb;
            float tin = fmaf(valr[row],proj_w[col], fmaf(obsr[row],proj_w[64+col], proj_b[col]))
                      + pe_g[(((size_t)b<<8)+row)*64+col];
            float ob = obsr[row];
            xtat[((size_t)bn<<14)+(row<<6)+col] = f2bu(ob*tin + (1.f-ob)*tv);
          }
        }
      }
    }
  }
}

// ---------------------------------------------------------------------------
// K35: precompute xt-dependent gate terms + fold u1+rs*u2.
//   Xall[b,t,g,d,n] (bf16) = (xt@Wg_x + (A@xt)@Wg_ax)[n,d] + u1g[d] + rs[n]*u2g[d]
// ---------------------------------------------------------------------------
__global__ void k35_xg(const unsigned short* __restrict__ xtat, const short* __restrict__ Abf,
                       const short* __restrict__ Wg_t, const int* __restrict__ lengths,
                       const float* __restrict__ U, const float* __restrict__ rs_g,
                       unsigned short* __restrict__ Xall)
{
  const int bt = blockIdx.x, b = bt>>8, t = bt&255;
  int len = lengths[b]; if (len<1) len=1;
  if (t >= len) return;
  const int tid = threadIdx.x, w = tid>>6, lane = tid&63;
  const int l15 = lane&15, lhi = lane>>4;
  __shared__ short xt_rm[4096], xt_tp[4096], axt_rm[4096];

  // load xt[n][d] = xtat[b,n,t,:]
  #pragma unroll
  for (int q=0;q<2;q++){
    int e = tid + (q<<8);
    int nn = e>>3, c0 = (e&7)<<3;
    s16x8 v = *(const s16x8*)((const short*)xtat + (((size_t)(b*64+nn)*256 + t)<<6) + c0);
    *(s16x8*)(xt_rm + swzo(nn,c0)) = v;
    #pragma unroll
    for (int jj=0;jj<8;jj++) xt_tp[swzo(c0+jj, nn)] = v[jj];
  }
  __syncthreads();

  // Axt = A @ xt ; wave w computes col-tile w (all 4 row tiles)
  {
    s16x8 bx[2];
    #pragma unroll
    for (int kk=0;kk<2;kk++) bx[kk]=ldfrag(xt_tp, w<<4, lane, kk);
    #pragma unroll
    for (int rt=0;rt<4;rt++){
      f32x4 acc={0.f,0.f,0.f,0.f};
      #pragma unroll
      for (int kk=0;kk<2;kk++){
        s16x8 af = *(const s16x8*)(Abf + ((rt<<4)+l15)*64 + (kk<<5) + (lhi<<3));
        acc=__builtin_amdgcn_mfma_f32_16x16x32_bf16(af,bx[kk],acc,0,0,0);
      }
      const int rb=(rt<<4)+(lhi<<2);
      #pragma unroll
      for(int i=0;i<4;i++) axt_rm[swzo(rb+i,(w<<4)+l15)] = (short)f2bu(acc[i]);
    }
  }
  __syncthreads();

  // Xg = xt@Wg_x + Axt@Wg_ax ; wave w -> out col-tile w for each gate
  s16x8 fx[4][2], fa[4][2];
  #pragma unroll
  for (int rt=0;rt<4;rt++)
    #pragma unroll
    for (int kk=0;kk<2;kk++){
      fx[rt][kk]=ldfrag(xt_rm, rt<<4, lane, kk);
      fa[rt][kk]=ldfrag(axt_rm, rt<<4, lane, kk);
    }
  const int dcol = (w<<4)+l15;
  f32x4 rsv[4];
  #pragma unroll
  for (int rt=0;rt<4;rt++) rsv[rt] = *(const f32x4*)(rs_g + (rt<<4) + (lhi<<2));
  const float* Ub = U + (size_t)bt*384;
  #pragma unroll
  for (int g=0; g<3; g++){
    s16x8 wbx[2], wba[2];
    #pragma unroll
    for (int kk=0;kk<2;kk++){
      wbx[kk] = *(const s16x8*)(Wg_t + (((g<<1)  )*64 + dcol)*64 + (kk<<5)+(lhi<<3));
      wba[kk] = *(const s16x8*)(Wg_t + (((g<<1)+1)*64 + dcol)*64 + (kk<<5)+(lhi<<3));
    }
    float u1 = Ub[(g<<7) + dcol];
    float u2 = Ub[(g<<7) + 64 + dcol];
    #pragma unroll
    for (int rt=0;rt<4;rt++){
      f32x4 acc={u1,u1,u1,u1};
      #pragma unroll
      for (int kk=0;kk<2;kk++){
        acc=__builtin_amdgcn_mfma_f32_16x16x32_bf16(fx[rt][kk],wbx[kk],acc,0,0,0);
        acc=__builtin_amdgcn_mfma_f32_16x16x32_bf16(fa[rt][kk],wba[kk],acc,0,0,0);
      }
      s16x4 pk;
      #pragma unroll
      for(int i=0;i<4;i++) pk[i]=(short)f2bu(acc[i] + rsv[rt][i]*u2);
      *(s16x4*)((short*)Xall + (((size_t)bt*3 + g)*64 + dcol)*64 + (rt<<4)+(lhi<<2)) = pk;
    }
  }
}

// ---------------------------------------------------------------------------
// K4: graph-GRU scan, 2 BATCHES PER BLOCK (16 waves = 2 groups x 8 waves).
//     Each group runs the proven R4 schedule (4 raw barriers/step, DPP+cvt_pk
//     staging, X prefetch) on its own batch and its own LDS tiles (grp<<13
//     byte offset folded into precomputed offsets). Both groups loop to the
//     pair max length so barrier counts stay uniform; inactive steps skip the
//     decay and h-update only. Independent batches co-resident per SIMD
//     (4 waves: 2+2) overlap each other's phase latencies.
// ---------------------------------------------------------------------------
__launch_bounds__(1024, 1)
__global__ void k4_scan(const unsigned short* __restrict__ Xall,
                        const float* __restrict__ decay, const short* __restrict__ Abf,
                        const short* __restrict__ Wg_h,
                        const int* __restrict__ lengths, float* __restrict__ hT)
{
  const int tid = threadIdx.x;
  const int grp = tid >> 9;               // batch group 0..1
  const int stid = tid & 511;             // tid within group
  const int w = stid>>6, lane = stid&63;
  const int l15 = lane&15, lhi = lane>>4;
  const int pe_ = l15&1;
  const int b = blockIdx.x*2 + grp;
  const int gofs = grp << 13;             // byte offset of group's LDS tile
  // gate partition: n-tile rnt, d-tile pair dp
  const int rnt = w>>1, dp = w&1;
  const int nb_ = (rnt<<4) + (lhi<<2);
  const int d0 = (dp<<5) + l15, d1 = (dp<<5) + 16 + l15;
  // A-mult partition: n-tile pair (tmA0,tmA1), d-tile dnA
  const int tmA0 = (w&1)<<1, tmA1 = tmA0+1;
  const int dnA = w>>1;

  __shared__ short h_rm[2][4096], h_tp[2][4096], ah_rm[2][4096];
  __shared__ short rh_rm[2][4096], rh_tp[2][4096], arh_rm[2][4096];
  __shared__ float dec_s[2][256];

  int lenA = lengths[blockIdx.x*2];   if (lenA<1) lenA=1;
  int lenB = lengths[blockIdx.x*2+1]; if (lenB<1) lenB=1;
  const int len = grp ? lenB : lenA;
  const int lenmax = (lenA>lenB)?lenA:lenB;
  for (int e=stid; e<256; e+=512) dec_s[grp][e] = decay[b*256+e];

  // static A fragments (A-operand rows tmA0/tmA1)
  s16x8 aA[2][2];
  #pragma unroll
  for (int t2=0;t2<2;t2++)
    #pragma unroll
    for (int kk=0;kk<2;kk++)
      aA[t2][kk] = *(const s16x8*)(Abf + (((t2?tmA1:tmA0)<<4) + l15)*64 + (kk<<5) + (lhi<<3));

  // static gate weight B-frags: wf[g][s][kk][e]  (s=0: h slice, s=1: Ah slice)
  s16x8 wf[3][2][2][2];
  #pragma unroll
  for (int g=0;g<3;g++)
    #pragma unroll
    for (int s=0;s<2;s++)
      #pragma unroll
      for (int kk=0;kk<2;kk++)
        #pragma unroll
        for (int e=0;e<2;e++)
          wf[g][s][kk][e] = *(const s16x8*)(Wg_h + (((g*2+s)*64 + (e?d1:d0))<<6) + (kk<<5) + (lhi<<3));

  // ---- precomputed LDS byte offsets (loop-invariant, group offset folded) ----
  int tpo[2];
  #pragma unroll
  for (int e=0;e<2;e++){ int r = e?d1:d0; tpo[e] = gofs + r*128 + (((nb_)*2) ^ ((r&7)<<4)); }
  int rmo[4];
  { int dPr = ((dp<<1) + pe_)*16 + (l15 & ~1);
    #pragma unroll
    for (int i=0;i<4;i++){ int n = nb_+i; rmo[i] = gofs + n*128 + ((dPr*2) ^ ((n&7)<<4)); } }
  int amo[4];
  { int dAr = (dnA<<4) + (l15 & ~1);
    int tb = (pe_? tmA1 : tmA0)<<4;
    #pragma unroll
    for (int i=0;i<4;i++){ int n = tb + (lhi<<2) + i; amo[i] = gofs + n*128 + ((dAr*2) ^ ((n&7)<<4)); } }
  int rdT[2], rdR[2];
  { int r = (dnA<<4)+l15;
    #pragma unroll
    for (int kk=0;kk<2;kk++) rdT[kk] = gofs + r*128 + (((kk<<6) + (lhi<<4)) ^ ((r&7)<<4)); }
  { int r = (rnt<<4)+l15;
    #pragma unroll
    for (int kk=0;kk<2;kk++) rdR[kk] = gofs + r*128 + (((kk<<6) + (lhi<<4)) ^ ((r&7)<<4)); }

  f32x4 hreg[2] = {{0.f,0.f,0.f,0.f},{0.f,0.f,0.f,0.f}};
  f32x4 zz[2];

  const short* Xb = (const short*)Xall;
  s16x4 xzc[2], xrc[2], xcc[2], xzn[2], xrn[2], xcn[2];
  #pragma unroll
  for (int e=0;e<2;e++){ xzc[e]=(s16x4){0,0,0,0}; xrc[e]=xzc[e]; xcc[e]=xzc[e]; }
  {
    const short* base = Xb + ((size_t)(b*256))*12288;
    #pragma unroll
    for (int e=0;e<2;e++){
      int de = e?d1:d0;
      xzc[e] = *(const s16x4*)(base + (0*64 + de)*64 + nb_);
      xrc[e] = *(const s16x4*)(base + (1*64 + de)*64 + nb_);
      xcc[e] = *(const s16x4*)(base + (2*64 + de)*64 + nb_);
    }
  }
  __syncthreads();

  for (int t=0; t<lenmax; t++){
    const bool act = (t < len);
    // decay (skip when this group's batch is done)
    float dc = act ? dec_s[grp][t] : 1.f;
    #pragma unroll
    for (int e=0;e<2;e++)
      #pragma unroll
      for (int i=0;i<4;i++) hreg[e][i] *= dc;

    // prefetch X for t+1 (stays in flight across raw barriers)
    #pragma unroll
    for (int e=0;e<2;e++){ xzn[e]=(s16x4){0,0,0,0}; xrn[e]=xzn[e]; xcn[e]=xzn[e]; }
    if (t+1 < len){
      const short* base = Xb + ((size_t)(b*256 + t+1))*12288;
      #pragma unroll
      for (int e=0;e<2;e++){
        int de = e?d1:d0;
        xzn[e] = *(const s16x4*)(base + (0*64 + de)*64 + nb_);
        xrn[e] = *(const s16x4*)(base + (1*64 + de)*64 + nb_);
        xcn[e] = *(const s16x4*)(base + (2*64 + de)*64 + nb_);
      }
    }

    // ---- P0: stage h (tp: b64 per e; rm: b32 pair via DPP) ----
    #pragma unroll
    for (int e=0;e<2;e++){
      i32x2 v; v[0] = (int)cvtpk(hreg[e][0], hreg[e][1]);
               v[1] = (int)cvtpk(hreg[e][2], hreg[e][3]);
      *(i32x2*)((char*)h_tp + tpo[e]) = v;
    }
    #pragma unroll
    for (int i=0;i<4;i++){
      float v0 = hreg[0][i], v1 = hreg[1][i];
      float n0 = dppx1(v0), n1 = dppx1(v1);
      float lo = pe_ ? n1 : v0;
      float hi = pe_ ? v1 : n0;
      *(unsigned*)((char*)h_rm + rmo[i]) = cvtpk(lo, hi);
    }
    BAR();

    // ---- P1: Ah = A@h -> ah_rm ----
    {
      s16x8 bh0 = *(const s16x8*)((const char*)h_tp + rdT[0]);
      s16x8 bh1 = *(const s16x8*)((const char*)h_tp + rdT[1]);
      f32x4 a0v={0.f,0.f,0.f,0.f}, a1v={0.f,0.f,0.f,0.f};
      a0v = __builtin_amdgcn_mfma_f32_16x16x32_bf16(aA[0][0], bh0, a0v, 0,0,0);
      a0v = __builtin_amdgcn_mfma_f32_16x16x32_bf16(aA[0][1], bh1, a0v, 0,0,0);
      a1v = __builtin_amdgcn_mfma_f32_16x16x32_bf16(aA[1][0], bh0, a1v, 0,0,0);
      a1v = __builtin_amdgcn_mfma_f32_16x16x32_bf16(aA[1][1], bh1, a1v, 0,0,0);
      #pragma unroll
      for (int i=0;i<4;i++){
        float n0 = dppx1(a0v[i]), n1 = dppx1(a1v[i]);
        float lo = pe_ ? n1 : a0v[i];
        float hi = pe_ ? a1v[i] : n0;
        *(unsigned*)((char*)ah_rm + amo[i]) = cvtpk(lo, hi);
      }
    }
    BAR();

    // ---- P2: z,r gates ----
    {
      s16x8 fh0 = *(const s16x8*)((const char*)h_rm  + rdR[0]);
      s16x8 fh1 = *(const s16x8*)((const char*)h_rm  + rdR[1]);
      s16x8 fa0 = *(const s16x8*)((const char*)ah_rm + rdR[0]);
      s16x8 fa1 = *(const s16x8*)((const char*)ah_rm + rdR[1]);
      f32x4 gz[2], gr[2], rh[2];
      #pragma unroll
      for (int e=0;e<2;e++)
        #pragma unroll
        for (int i=0;i<4;i++){ gz[e][i]=bs2f(xzc[e][i]); gr[e][i]=bs2f(xrc[e][i]); }
      #pragma unroll
      for (int e=0;e<2;e++){
        gz[e] = __builtin_amdgcn_mfma_f32_16x16x32_bf16(fh0, wf[0][0][0][e], gz[e], 0,0,0);
        gz[e] = __builtin_amdgcn_mfma_f32_16x16x32_bf16(fh1, wf[0][0][1][e], gz[e], 0,0,0);
        gz[e] = __builtin_amdgcn_mfma_f32_16x16x32_bf16(fa0, wf[0][1][0][e], gz[e], 0,0,0);
        gz[e] = __builtin_amdgcn_mfma_f32_16x16x32_bf16(fa1, wf[0][1][1][e], gz[e], 0,0,0);
        gr[e] = __builtin_amdgcn_mfma_f32_16x16x32_bf16(fh0, wf[1][0][0][e], gr[e], 0,0,0);
        gr[e] = __builtin_amdgcn_mfma_f32_16x16x32_bf16(fh1, wf[1][0][1][e], gr[e], 0,0,0);
        gr[e] = __builtin_amdgcn_mfma_f32_16x16x32_bf16(fa0, wf[1][1][0][e], gr[e], 0,0,0);
        gr[e] = __builtin_amdgcn_mfma_f32_16x16x32_bf16(fa1, wf[1][1][1][e], gr[e], 0,0,0);
      }
      #pragma unroll
      for (int e=0;e<2;e++)
        #pragma unroll
        for (int i=0;i<4;i++){
          float zv = 1.f/(1.f+__expf(-gz[e][i]));
          float rv = 1.f/(1.f+__expf(-gr[e][i]));
          zz[e][i] = zv;
          rh[e][i] = rv * hreg[e][i];
        }
      // stage rh: tp b64 per e + rm b32 pairs via DPP
      #pragma unroll
      for (int e=0;e<2;e++){
        i32x2 v; v[0] = (int)cvtpk(rh[e][0], rh[e][1]);
                 v[1] = (int)cvtpk(rh[e][2], rh[e][3]);
        *(i32x2*)((char*)rh_tp + tpo[e]) = v;
      }
      #pragma unroll
      for (int i=0;i<4;i++){
        float v0 = rh[0][i], v1 = rh[1][i];
        float n0 = dppx1(v0), n1 = dppx1(v1);
        float lo = pe_ ? n1 : v0;
        float hi = pe_ ? v1 : n0;
        *(unsigned*)((char*)rh_rm + rmo[i]) = cvtpk(lo, hi);
      }
    }
    BAR();

    // ---- P3: Arh = A@rh -> arh_rm ----
    {
      s16x8 br0 = *(const s16x8*)((const char*)rh_tp + rdT[0]);
      s16x8 br1 = *(const s16x8*)((const char*)rh_tp + rdT[1]);
      f32x4 a0v={0.f,0.f,0.f,0.f}, a1v={0.f,0.f,0.f,0.f};
      a0v = __builtin_amdgcn_mfma_f32_16x16x32_bf16(aA[0][0], br0, a0v, 0,0,0);
      a0v = __builtin_amdgcn_mfma_f32_16x16x32_bf16(aA[0][1], br1, a0v, 0,0,0);
      a1v = __builtin_amdgcn_mfma_f32_16x16x32_bf16(aA[1][0], br0, a1v, 0,0,0);
      a1v = __builtin_amdgcn_mfma_f32_16x16x32_bf16(aA[1][1], br1, a1v, 0,0,0);
      #pragma unroll
      for (int i=0;i<4;i++){
        float n0 = dppx1(a0v[i]), n1 = dppx1(a1v[i]);
        float lo = pe_ ? n1 : a0v[i];
        float hi = pe_ ? a1v[i] : n0;
        *(unsigned*)((char*)arh_rm + amo[i]) = cvtpk(lo, hi);
      }
    }
    BAR();

    // ---- P4: c gate + h update ----
    {
      s16x8 fr0 = *(const s16x8*)((const char*)rh_rm  + rdR[0]);
      s16x8 fr1 = *(const s16x8*)((const char*)rh_rm  + rdR[1]);
      s16x8 fb0 = *(const s16x8*)((const char*)arh_rm + rdR[0]);
      s16x8 fb1 = *(const s16x8*)((const char*)arh_rm + rdR[1]);
      f32x4 gc[2];
      #pragma unroll
      for (int e=0;e<2;e++)
        #pragma unroll
        for (int i=0;i<4;i++) gc[e][i]=bs2f(xcc[e][i]);
      #pragma unroll
      for (int e=0;e<2;e++){
        gc[e] = __builtin_amdgcn_mfma_f32_16x16x32_bf16(fr0, wf[2][0][0][e], gc[e], 0,0,0);
        gc[e] = __builtin_amdgcn_mfma_f32_16x16x32_bf16(fr1, wf[2][0][1][e], gc[e], 0,0,0);
        gc[e] = __builtin_amdgcn_mfma_f32_16x16x32_bf16(fb0, wf[2][1][0][e], gc[e], 0,0,0);
        gc[e] = __builtin_amdgcn_mfma_f32_16x16x32_bf16(fb1, wf[2][1][1][e], gc[e], 0,0,0);
      }
      if (act){
        #pragma unroll
        for (int e=0;e<2;e++)
          #pragma unroll
          for (int i=0;i<4;i++){
            float cv = 1.f - 2.f/(__expf(2.f*gc[e][i])+1.f);   // tanh
            hreg[e][i] = fmaf(zz[e][i], hreg[e][i]-cv, cv);
          }
      }
    }

    // rotate prefetch
    #pragma unroll
    for (int e=0;e<2;e++){ xzc[e]=xzn[e]; xrc[e]=xrn[e]; xcc[e]=xcn[e]; }
  }

  // suffix decay for t in [len,256)
  float sp = 1.f;
  for (int t=len; t<256; t++) sp *= dec_s[grp][t];
  #pragma unroll
  for (int e=0;e<2;e++)
    #pragma unroll
    for (int i=0;i<4;i++)
      hT[(((size_t)b<<6) + nb_ + i)*64 + (e?d1:d0)] = hreg[e][i]*sp;
}

// ---------------------------------------------------------------------------
// K5: classifier head
// ---------------------------------------------------------------------------
__global__ void k5_head(const float* __restrict__ hT, const float* __restrict__ Wfin,
                        const float* __restrict__ bfin,
                        const float* __restrict__ stat, const float* __restrict__ We,
                        const float* __restrict__ be,
                        const float* __restrict__ Wc1, const float* __restrict__ bc1,
                        const float* __restrict__ Wc2, const float* __restrict__ bc2,
                        float* __restrict__ out)
{
  const int b = blockIdx.x, tid = threadIdx.x;
  __shared__ float cat[128];
  __shared__ float hcl[200];
  if (tid < 64){
    const float* hr = hT + (((size_t)b<<6)+tid)*64;
    float a = bfin[0];
    #pragma unroll
    for (int d=0;d<64;d++) a = fmaf(hr[d], Wfin[d], a);
    cat[tid]=a;
  } else if (tid < 128){
    int nn = tid-64;
    float a = be[nn];
    #pragma unroll
    for (int k=0;k<9;k++) a = fmaf(stat[b*9+k], We[k*64+nn], a);
    cat[tid]=a;
  }
  __syncthreads();
  if (tid < 200){
    float a = bc1[tid];
    for (int k=0;k<128;k++) a = fmaf(cat[k], Wc1[k*200+tid], a);
    hcl[tid] = fmaxf(a, 0.f);
  }
  __syncthreads();
  if (tid < 2){
    float a = bc2[tid];
    for (int k=0;k<200;k++) a = fmaf(hcl[k], Wc2[k*2+tid], a);
    out[b*2+tid] = a;
  }
}

// ---------------------------------------------------------------------------
extern "C" void kernel_launch(void* const* d_in, const int* in_sizes, int n_in,
                              void* d_out, int out_size, void* d_ws, size_t ws_size,
                              hipStream_t stream)
{
  const float* x       = (const float*)d_in[0];
  const float* nufft   = (const float*)d_in[1];
  const float* delta_t = (const float*)d_in[2];
  const float* stat    = (const float*)d_in[3];
  const int*   lengths = (const int*)  d_in[4];
  const float* proj_w  = (const float*)d_in[5];
  const float* proj_b  = (const float*)d_in[6];
  const float* Wqkv    = (const float*)d_in[7];
  const float* bqkv    = (const float*)d_in[8];
  const float* Wo      = (const float*)d_in[9];
  const float* bo      = (const float*)d_in[10];
  const float* ln1g    = (const float*)d_in[11];
  const float* ln1b    = (const float*)d_in[12];
  const float* W1      = (const float*)d_in[13];
  const float* b1      = (const float*)d_in[14];
  const float* W2      = (const float*)d_in[15];
  const float* b2      = (const float*)d_in[16];
  const float* ln2g    = (const float*)d_in[17];
  const float* ln2b    = (const float*)d_in[18];
  const float* WQf     = (const float*)d_in[19];
  const float* WKf     = (const float*)d_in[20];
  const float* Wz      = (const float*)d_in[21];
  const float* bz      = (const float*)d_in[22];
  const float* Wr      = (const float*)d_in[23];
  const float* br      = (const float*)d_in[24];
  const float* Wc      = (const float*)d_in[25];
  const float* bc      = (const float*)d_in[26];
  const float* Wfin    = (const float*)d_in[27];
  const float* bfin    = (const float*)d_in[28];
  const float* We      = (const float*)d_in[29];
  const float* be      = (const float*)d_in[30];
  const float* Wc1     = (const float*)d_in[31];
  const float* bc1     = (const float*)d_in[32];
  const float* Wc2     = (const float*)d_in[33];
  const float* bc2     = (const float*)d_in[34];
  float* out = (float*)d_out;

  char* ws = (char*)d_ws;
  size_t o = 0;
  float* pe    = (float*)(ws+o); o += (size_t)4096*64*4;
  float* U     = (float*)(ws+o); o += (size_t)4096*384*4;
  float* decay = (float*)(ws+o); o += (size_t)4096*4;
  unsigned short* xtat = (unsigned short*)(ws+o); o += (size_t)1024*256*64*2;
  float* qf    = (float*)(ws+o); o += (size_t)1024*256*4;
  float* kf    = (float*)(ws+o); o += (size_t)1024*256*4;
  float* soft  = (float*)(ws+o); o += (size_t)16*4096*4;
  short* Abf   = (short*)(ws+o); o += (size_t)4096*2;
  float* rs    = (float*)(ws+o); o += (size_t)64*4;
  float* hT    = (float*)(ws+o); o += (size_t)16*64*64*4;
  short* Wqkv_t= (short*)(ws+o); o += (size_t)12288*2;
  short* Wo_t  = (short*)(ws+o); o += (size_t)4096*2;
  short* W1_t  = (short*)(ws+o); o += (size_t)4096*2;
  short* W2_t  = (short*)(ws+o); o += (size_t)4096*2;
  short* Wg_t  = (short*)(ws+o); o += (size_t)24576*2;
  short* Wg_h  = (short*)(ws+o); o += (size_t)24576*2;
  unsigned short* Xall = (unsigned short*)(ws+o); o += (size_t)4096*3*4096*2;  // ~100 MB
  (void)ws_size; (void)in_sizes; (void)n_in; (void)out_size;

  hipLaunchKernelGGL(k0_prep,   dim3(288),  dim3(256), 0, stream,
                     Wqkv, Wo, W1, W2, Wz, Wr, Wc, Wqkv_t, Wo_t, W1_t, W2_t, Wg_t, Wg_h);
  hipLaunchKernelGGL(k1_pe_u,   dim3(1024), dim3(256), 0, stream,
                     x, delta_t, Wz, bz, Wr, br, Wc, bc, pe, U, decay);
  hipLaunchKernelGGL(k2a_qfkf,  dim3(1024), dim3(256), 0, stream,
                     nufft, WQf, WKf, qf, kf);
  hipLaunchKernelGGL(k2b_soft,  dim3(16),   dim3(256), 0, stream, qf, kf, soft);
  hipLaunchKernelGGL(k2c_A,     dim3(1),    dim3(256), 0, stream, soft, Abf, rs);
  hipLaunchKernelGGL(k3_former, dim3(1024), dim3(512), 0, stream,
                     x, pe, proj_w, proj_b, Wqkv_t, bqkv, Wo_t, bo, ln1g, ln1b,
                     W1_t, b1, W2_t, b2, ln2g, ln2b, lengths, xtat);
  hipLaunchKernelGGL(k35_xg,    dim3(4096), dim3(256), 0, stream,
                     xtat, Abf, Wg_t, lengths, U, rs, Xall);
  hipLaunchKernelGGL(k4_scan,   dim3(8),    dim3(1024), 0, stream,
                     Xall, decay, Abf, Wg_h, lengths, hT);
  hipLaunchKernelGGL(k5_head,   dim3(16),   dim3(256), 0, stream,
                     hT, Wfin, bfin, stat, We, be, Wc1, bc1, Wc2, bc2, out);
}

// Round 10
// 2864.328 us; speedup vs baseline: 1.0000x; 1.0000x over previous
//
#include <hip/hip_runtime.h>
#include <hip/hip_bf16.h>
#include <cmath>

#define DEV __device__ __forceinline__

typedef short s16x8 __attribute__((ext_vector_type(8)));
typedef short s16x4 __attribute__((ext_vector_type(4)));
typedef float f32x4 __attribute__((ext_vector_type(4)));
typedef int   i32x2 __attribute__((ext_vector_type(2)));

DEV unsigned short f2bu(float x){
  __hip_bfloat16 h = __float2bfloat16(x);
  return *reinterpret_cast<unsigned short*>(&h);
}
DEV float bs2f(unsigned short v){ return __uint_as_float(((unsigned)v)<<16); }
DEV float bs2f(short v){ return bs2f((unsigned short)v); }

DEV unsigned cvtpk(float lo, float hi){
  unsigned r;
  asm("v_cvt_pk_bf16_f32 %0, %1, %2" : "=v"(r) : "v"(lo), "v"(hi));
  return r;
}
DEV float dppx1(float v){   // value from lane^1 (quad_perm 1,0,3,2)
  int r = __builtin_amdgcn_mov_dpp(__float_as_int(v), 0xB1, 0xF, 0xF, true);
  return __int_as_float(r);
}

#define BAR() do { asm volatile("s_waitcnt lgkmcnt(0)" ::: "memory"); \
                   __builtin_amdgcn_s_barrier(); \
                   __builtin_amdgcn_sched_barrier(0); } while(0)

// swizzled [R][64] bf16 tile helpers (row stride 128B, byte ^= (row&7)<<4)
DEV int swzo(int row, int col){
  return (row*128 + ((col*2) ^ ((row&7)<<4))) >> 1;
}
DEV s16x8 ldfrag(const short* tile, int t16, int lane, int kk){
  int row = t16 + (lane & 15);
  int c0  = (kk<<5) + ((lane>>4)<<3);
  int off = (row*128 + ((c0<<1) ^ ((row&7)<<4))) >> 1;
  return *(const s16x8*)(tile + off);
}
// swizzled [64][256] bf16 (V^T) tile: row stride 512B
DEV int swzv(int d, int t){
  return (d*512 + ((t*2) ^ ((d&7)<<4))) >> 1;
}

// ---------------------------------------------------------------------------
// K0: weight prep. Wqkv_t[192][64], Wo_t/W1_t/W2_t[64][64] (bf16 transposed),
//     Wg_t[3][2][64c][64k] (gate slices xt:0.. / Axt:192..) for k35,
//     Wg_h[3][2][64c][64k] (gate slices h:64.. / Ah:256..) for k4.
// ---------------------------------------------------------------------------
__global__ void k0_prep(const float* __restrict__ Wqkv, const float* __restrict__ Wo,
                        const float* __restrict__ W1, const float* __restrict__ W2,
                        const float* __restrict__ Wz, const float* __restrict__ Wr,
                        const float* __restrict__ Wc,
                        short* __restrict__ Wqkv_t, short* __restrict__ Wo_t,
                        short* __restrict__ W1_t, short* __restrict__ W2_t,
                        short* __restrict__ Wg_t, short* __restrict__ Wg_h)
{
  int t = blockIdx.x*256 + threadIdx.x;
  if (t < 12288){ int nn=t>>6, k=t&63; Wqkv_t[t]=(short)f2bu(Wqkv[k*192+nn]); }
  else if (t < 16384){ int e=t-12288; int nn=e>>6,k=e&63; Wo_t[e]=(short)f2bu(Wo[k*64+nn]); }
  else if (t < 20480){ int e=t-16384; int nn=e>>6,k=e&63; W1_t[e]=(short)f2bu(W1[k*64+nn]); }
  else if (t < 24576){ int e=t-20480; int nn=e>>6,k=e&63; W2_t[e]=(short)f2bu(W2[k*64+nn]); }
  else if (t < 49152){
    int e=t-24576;
    int g=e>>13, rem=e&8191, s=rem>>12, rem2=rem&4095, c=rem2>>6, k=rem2&63;
    const float* Wg = (g==0)?Wz:((g==1)?Wr:Wc);
    Wg_t[e] = (short)f2bu(Wg[((s?192:0)+k)*64 + c]);
  }
  else if (t < 73728){
    int e=t-49152;
    int g=e>>13, rem=e&8191, s=rem>>12, rem2=rem&4095, c=rem2>>6, k=rem2&63;
    const float* Wg = (g==0)?Wz:((g==1)?Wr:Wc);
    Wg_h[e] = (short)f2bu(Wg[((s?256:64)+k)*64 + c]);
  }
}

// ---------------------------------------------------------------------------
// K1: positional encoding pe[b,t,64], te-derived gate vectors U[b,t,6,64],
//     decay. 4 (b,t) pairs per 256-thread block: weight reads shared 4-way.
// ---------------------------------------------------------------------------
__global__ void k1_pe_u(const float* __restrict__ x, const float* __restrict__ delta_t,
                        const float* __restrict__ Wz, const float* __restrict__ bz,
                        const float* __restrict__ Wr, const float* __restrict__ br,
                        const float* __restrict__ Wc, const float* __restrict__ bc,
                        float* __restrict__ pe, float* __restrict__ U, float* __restrict__ decay)
{
  const int q  = threadIdx.x >> 6;          // sub-block 0..3
  const int d  = threadIdx.x & 63;          // 0..63
  const int bt = blockIdx.x*4 + q;          // b*256 + t
  __shared__ float pes[4][64];
  float tmv = x[(size_t)bt*129 + 128];      // times
  int j = d & 31;
  float ts = exp2f((float)j * (8.0f/31.0f));   // 256^(j/31)
  float st = tmv / ts;
  float v = (d < 32) ? sinf(st) : cosf(st);
  pes[q][d] = v;
  pe[(size_t)bt*64 + d] = v;
  __syncthreads();
  float a0=bz[d], a1=0.f, a2=br[d], a3=0.f, a4=bc[d], a5=0.f;
  for (int k=0;k<64;k++){
    float p = pes[q][k];
    a0 = fmaf(p, Wz[(128+k)*64+d], a0);
    a1 = fmaf(p, Wz[(320+k)*64+d], a1);
    a2 = fmaf(p, Wr[(128+k)*64+d], a2);
    a3 = fmaf(p, Wr[(320+k)*64+d], a3);
    a4 = fmaf(p, Wc[(128+k)*64+d], a4);
    a5 = fmaf(p, Wc[(320+k)*64+d], a5);
  }
  float* u = U + (size_t)bt*384;
  u[d]=a0; u[64+d]=a1; u[128+d]=a2; u[192+d]=a3; u[256+d]=a4; u[320+d]=a5;
  if (d==0) decay[bt] = expf(-fmaxf(delta_t[bt], 0.f));
}

// ---------------------------------------------------------------------------
// K2a: qf = xf@WQ_f, kf = xf@WK_f   (xf[b,n,t] = nufft[b,1,t,n])
// ---------------------------------------------------------------------------
__global__ void k2a_qfkf(const float* __restrict__ nufft, const float* __restrict__ WQf,
                         const float* __restrict__ WKf, float* __restrict__ qf, float* __restrict__ kf)
{
  const int bn = blockIdx.x, b = bn>>6, n = bn&63;
  const int u = threadIdx.x;  // 0..255
  __shared__ float xs[256];
  xs[u] = nufft[ ((((size_t)b*2)+1)*256 + u)*64 + n ];
  __syncthreads();
  float aq=0.f, ak=0.f;
  for (int t=0;t<256;t++){
    float xv = xs[t];
    aq = fmaf(xv, WQf[t*256+u], aq);
    ak = fmaf(xv, WKf[t*256+u], ak);
  }
  qf[(size_t)bn*256+u]=aq;
  kf[(size_t)bn*256+u]=ak;
}

// ---------------------------------------------------------------------------
// K2b: per-batch S=relu(qf·kf)/16, row-softmax -> soft[b,64,64]
// ---------------------------------------------------------------------------
__launch_bounds__(256, 1)
__global__ void k2b_soft(const float* __restrict__ qf, const float* __restrict__ kf,
                         float* __restrict__ soft)
{
  const int b = blockIdx.x, tid = threadIdx.x;
  __shared__ float qs[64*257];
  __shared__ float ksh[64*257];
  __shared__ float Ss[64*65];
  const float* qb = qf + ((size_t)b<<14);
  const float* kb = kf + ((size_t)b<<14);
  for (int e=tid; e<16384; e+=256){
    int r=e>>8, c=e&255;
    qs[r*257+c]=qb[e];
    ksh[r*257+c]=kb[e];
  }
  __syncthreads();
  const int n = tid>>2, m0 = (tid&3)<<4;
  float acc[16];
  #pragma unroll
  for (int i=0;i<16;i++) acc[i]=0.f;
  for (int t=0;t<256;t++){
    float qv = qs[n*257+t];
    #pragma unroll
    for (int i=0;i<16;i++) acc[i] = fmaf(qv, ksh[(m0+i)*257+t], acc[i]);
  }
  #pragma unroll
  for (int i=0;i<16;i++) Ss[n*65+m0+i] = fmaxf(acc[i],0.f)*(1.f/16.f);
  __syncthreads();
  if (tid < 64){
    float mx=-1e30f;
    for (int m=0;m<64;m++) mx=fmaxf(mx, Ss[tid*65+m]);
    float s=0.f;
    for (int m=0;m<64;m++) s += expf(Ss[tid*65+m]-mx);
    float inv=1.f/s;
    for (int m=0;m<64;m++) soft[((size_t)b<<12)+(tid<<6)+m] = expf(Ss[tid*65+m]-mx)*inv;
  }
}

// ---------------------------------------------------------------------------
// K2c: A = 0.5(sm+sm^T) with sm = softmax(0.5(A0+A0^T)); A0 = mean_b soft.
// ---------------------------------------------------------------------------
__global__ void k2c_A(const float* __restrict__ soft, short* __restrict__ Abf,
                      float* __restrict__ rs_out)
{
  const int tid = threadIdx.x; // 256
  __shared__ float A0[64*65];
  __shared__ float A1[64*65];
  for (int e=tid; e<4096; e+=256){
    int nn=e>>6, mm=e&63;
    float s=0.f;
    #pragma unroll
    for (int b=0;b<16;b++) s += soft[((size_t)b<<12)+e];
    A0[nn*65+mm] = s*(1.f/16.f);
  }
  __syncthreads();
  for (int e=tid; e<4096; e+=256){
    int nn=e>>6, mm=e&63;
    A1[nn*65+mm] = 0.5f*(A0[nn*65+mm]+A0[mm*65+nn]);
  }
  __syncthreads();
  if (tid < 64){
    float mx=-1e30f;
    for (int m=0;m<64;m++) mx=fmaxf(mx, A1[tid*65+m]);
    float s=0.f;
    for (int m=0;m<64;m++) s += expf(A1[tid*65+m]-mx);
    float inv=1.f/s;
    for (int m=0;m<64;m++) A0[tid*65+m] = expf(A1[tid*65+m]-mx)*inv;
  }
  __syncthreads();
  for (int e=tid; e<4096; e+=256){
    int nn=e>>6, mm=e&63;
    float a = 0.5f*(A0[nn*65+mm]+A0[mm*65+nn]);
    A1[nn*65+mm] = a;
    Abf[e] = (short)f2bu(a);
  }
  __syncthreads();
  if (tid < 64){
    float s=0.f;
    for (int m=0;m<64;m++) s += A1[tid*65+m];
    rs_out[tid]=s;
  }
}

// ---------------------------------------------------------------------------
// K3: per-(b,n) transformer head via MFMA -> x_tat (bf16).
// ---------------------------------------------------------------------------
__launch_bounds__(512, 1)
__global__ void k3_former(const float* __restrict__ x, const float* __restrict__ pe_g,
    const float* __restrict__ proj_w, const float* __restrict__ proj_b,
    const short* __restrict__ Wqkv_t, const float* __restrict__ bqkv,
    const short* __restrict__ Wo_t, const float* __restrict__ bo,
    const float* __restrict__ ln1g, const float* __restrict__ ln1b,
    const short* __restrict__ W1_t, const float* __restrict__ b1,
    const short* __restrict__ W2_t, const float* __restrict__ b2,
    const float* __restrict__ ln2g, const float* __restrict__ ln2b,
    const int* __restrict__ lengths, unsigned short* __restrict__ xtat)
{
  const int bn = blockIdx.x, b = bn>>6, n = bn&63;
  const int tid = threadIdx.x, w = tid>>6, lane = tid&63;
  const int l15 = lane&15, lhi = lane>>4;
  __shared__ short tp_s[16384];
  __shared__ short q_s[16384];
  __shared__ short k_s[16384];
  __shared__ short v_t[16384];
  __shared__ float valr[256], obsr[256];

  int len = lengths[b]; if (len<1) len=1;
  const int LT = (len+15)>>4;
  const int KB = (len+63)>>6;

  if (tid < 256){
    const float* xr = x + ((size_t)b*256+tid)*129;
    valr[tid]=xr[n]; obsr[tid]=xr[64+n];
  }
  for (int e=tid; e<16384; e+=512) v_t[e]=0;
  __syncthreads();

  const int nrows = LT<<4;
  for (int e=tid; e<(nrows<<6); e+=512){
    int t=e>>6, d=e&63;
    float ti = fmaf(valr[t],proj_w[d], fmaf(obsr[t],proj_w[64+d], proj_b[d]))
             + pe_g[(((size_t)b<<8)+t)*64+d];
    tp_s[swzo(t,d)] = (short)f2bu(ti);
  }
  __syncthreads();

  // ---- QKV ----
  #pragma unroll
  for (int j=0;j<2;j++){
    const int rt = w + (j<<3);
    if (rt < LT){
      s16x8 a0 = ldfrag(tp_s, rt<<4, lane, 0);
      s16x8 a1 = ldfrag(tp_s, rt<<4, lane, 1);
      const int rb = (rt<<4) + (lhi<<2);
      #pragma unroll
      for (int nt=0; nt<12; nt++){
        const short* wb = Wqkv_t + (((nt<<4)+l15)<<6) + (lhi<<3);
        s16x8 b0 = *(const s16x8*)wb;
        s16x8 b1v = *(const s16x8*)(wb+32);
        float bias = bqkv[(nt<<4)+l15];
        f32x4 acc = {bias,bias,bias,bias};
        acc = __builtin_amdgcn_mfma_f32_16x16x32_bf16(a0,b0,acc,0,0,0);
        acc = __builtin_amdgcn_mfma_f32_16x16x32_bf16(a1,b1v,acc,0,0,0);
        const int col = ((nt&3)<<4) + l15;
        if (nt<4){
          #pragma unroll
          for(int i=0;i<4;i++) q_s[swzo(rb+i,col)] = (short)f2bu(acc[i]*0.125f);
        } else if (nt<8){
          #pragma unroll
          for(int i=0;i<4;i++) k_s[swzo(rb+i,col)] = (short)f2bu(acc[i]);
        } else {
          #pragma unroll
          for(int i=0;i<4;i++) v_t[swzv(col, rb+i)] = (short)f2bu(acc[i]);
        }
      }
    }
  }
  __syncthreads();

  // ---- attention ----
  f32x4 Oac[2][4];
  float rsum[2][4];
  #pragma unroll
  for(int j=0;j<2;j++)
    #pragma unroll
    for(int dt=0;dt<4;dt++) Oac[j][dt]=(f32x4){0.f,0.f,0.f,0.f};
  #pragma unroll
  for(int j=0;j<2;j++)
    #pragma unroll
    for(int i=0;i<4;i++) rsum[j][i]=0.f;

  for (int kb=0; kb<KB; kb++){
    s16x8 kf[4][2];
    #pragma unroll
    for (int ct=0;ct<4;ct++){
      kf[ct][0]=ldfrag(k_s, (((kb<<2)+ct)<<4), lane, 0);
      kf[ct][1]=ldfrag(k_s, (((kb<<2)+ct)<<4), lane, 1);
    }
    #pragma unroll
    for (int j=0;j<2;j++){
      const int rt=w+(j<<3);
      if (rt < LT){
        s16x8 q0=ldfrag(q_s, rt<<4, lane, 0);
        s16x8 q1=ldfrag(q_s, rt<<4, lane, 1);
        const int rb=(rt<<4)+(lhi<<2);
        #pragma unroll
        for (int ct=0;ct<4;ct++){
          f32x4 s={0.f,0.f,0.f,0.f};
          s=__builtin_amdgcn_mfma_f32_16x16x32_bf16(q0,kf[ct][0],s,0,0,0);
          s=__builtin_amdgcn_mfma_f32_16x16x32_bf16(q1,kf[ct][1],s,0,0,0);
          const int key=(kb<<6)+(ct<<4)+l15;
          #pragma unroll
          for(int i=0;i<4;i++){
            float p = (key<len) ? __expf(s[i]) : 0.f;
            rsum[j][i]+=p;
            tp_s[swzo(rb+i,(ct<<4)+l15)] = (short)f2bu(p);
          }
        }
      }
    }
    __syncthreads();
    s16x8 vf[4][2];
    #pragma unroll
    for (int dt=0;dt<4;dt++){
      const int d=(dt<<4)+l15;
      #pragma unroll
      for (int kk=0;kk<2;kk++){
        const int k0=(kk<<5)+(lhi<<3);
        vf[dt][kk] = *(const s16x8*)(v_t + swzv(d, (kb<<6)+k0));
      }
    }
    #pragma unroll
    for (int j=0;j<2;j++){
      const int rt=w+(j<<3);
      if (rt < LT){
        s16x8 p0=ldfrag(tp_s, rt<<4, lane, 0);
        s16x8 p1=ldfrag(tp_s, rt<<4, lane, 1);
        #pragma unroll
        for (int dt=0;dt<4;dt++){
          Oac[j][dt]=__builtin_amdgcn_mfma_f32_16x16x32_bf16(p0,vf[dt][0],Oac[j][dt],0,0,0);
          Oac[j][dt]=__builtin_amdgcn_mfma_f32_16x16x32_bf16(p1,vf[dt][1],Oac[j][dt],0,0,0);
        }
      }
    }
    __syncthreads();
  }

  float inv[2][4];
  #pragma unroll
  for(int j=0;j<2;j++)
    #pragma unroll
    for(int i=0;i<4;i++){
      float v=rsum[j][i];
      v += __shfl_xor(v,1); v += __shfl_xor(v,2); v += __shfl_xor(v,4); v += __shfl_xor(v,8);
      inv[j][i]=1.f/v;
    }

  #pragma unroll
  for (int j=0;j<2;j++){
    const int rt=w+(j<<3);
    if (rt < LT){
      const int rb=(rt<<4)+(lhi<<2);
      #pragma unroll
      for (int dt=0;dt<4;dt++)
        #pragma unroll
        for (int i=0;i<4;i++)
          q_s[swzo(rb+i,(dt<<4)+l15)] = (short)f2bu(Oac[j][dt][i]*inv[j][i]);
    }
  }
  __syncthreads();

  f32x4 h1[2][4];
  #pragma unroll
  for (int j=0;j<2;j++){
    const int rt=w+(j<<3);
    if (rt < LT){
      s16x8 a0=ldfrag(q_s, rt<<4, lane, 0);
      s16x8 a1=ldfrag(q_s, rt<<4, lane, 1);
      const int rb=(rt<<4)+(lhi<<2);
      #pragma unroll
      for (int dt=0;dt<4;dt++){
        const int col=(dt<<4)+l15;
        const short* wb = Wo_t + (col<<6) + (lhi<<3);
        s16x8 b0=*(const s16x8*)wb, b1v=*(const s16x8*)(wb+32);
        float bias=bo[col];
        f32x4 acc={bias,bias,bias,bias};
        acc=__builtin_amdgcn_mfma_f32_16x16x32_bf16(a0,b0,acc,0,0,0);
        acc=__builtin_amdgcn_mfma_f32_16x16x32_bf16(a1,b1v,acc,0,0,0);
        #pragma unroll
        for(int i=0;i<4;i++){
          const int row=rb+i;
          acc[i]+= fmaf(valr[row],proj_w[col], fmaf(obsr[row],proj_w[64+col], proj_b[col]))
                 + pe_g[(((size_t)b<<8)+row)*64+col];
        }
        h1[j][dt]=acc;
      }
      f32x4 mu, rsq;
      #pragma unroll
      for(int i=0;i<4;i++){
        float sv = h1[j][0][i]+h1[j][1][i]+h1[j][2][i]+h1[j][3][i];
        sv += __shfl_xor(sv,1); sv+=__shfl_xor(sv,2); sv+=__shfl_xor(sv,4); sv+=__shfl_xor(sv,8);
        mu[i]=sv*(1.f/64.f);
      }
      #pragma unroll
      for(int i=0;i<4;i++){
        float sv=0.f;
        #pragma unroll
        for(int dt=0;dt<4;dt++){ float c=h1[j][dt][i]-mu[i]; sv=fmaf(c,c,sv); }
        sv += __shfl_xor(sv,1); sv+=__shfl_xor(sv,2); sv+=__shfl_xor(sv,4); sv+=__shfl_xor(sv,8);
        rsq[i]=1.f/sqrtf(sv*(1.f/64.f)+1e-5f);
      }
      #pragma unroll
      for(int dt=0;dt<4;dt++){
        const int col=(dt<<4)+l15;
        float g=ln1g[col], bb=ln1b[col];
        #pragma unroll
        for(int i=0;i<4;i++){
          float hv=(h1[j][dt][i]-mu[i])*rsq[i]*g+bb;
          h1[j][dt][i]=hv;
          k_s[swzo(rb+i,col)] = (short)f2bu(hv);
        }
      }
    }
  }
  __syncthreads();

  #pragma unroll
  for (int j=0;j<2;j++){
    const int rt=w+(j<<3);
    if (rt < LT){
      s16x8 a0=ldfrag(k_s, rt<<4, lane, 0);
      s16x8 a1=ldfrag(k_s, rt<<4, lane, 1);
      const int rb=(rt<<4)+(lhi<<2);
      #pragma unroll
      for (int dt=0;dt<4;dt++){
        const int col=(dt<<4)+l15;
        const short* wb = W1_t + (col<<6)+(lhi<<3);
        s16x8 b0=*(const s16x8*)wb, b1v=*(const s16x8*)(wb+32);
        float bias=b1[col];
        f32x4 acc={bias,bias,bias,bias};
        acc=__builtin_amdgcn_mfma_f32_16x16x32_bf16(a0,b0,acc,0,0,0);
        acc=__builtin_amdgcn_mfma_f32_16x16x32_bf16(a1,b1v,acc,0,0,0);
        #pragma unroll
        for(int i=0;i<4;i++) tp_s[swzo(rb+i,col)]=(short)f2bu(fmaxf(acc[i],0.f));
      }
    }
  }
  __syncthreads();

  #pragma unroll
  for (int j=0;j<2;j++){
    const int rt=w+(j<<3);
    if (rt < LT){
      s16x8 a0=ldfrag(tp_s, rt<<4, lane, 0);
      s16x8 a1=ldfrag(tp_s, rt<<4, lane, 1);
      const int rb=(rt<<4)+(lhi<<2);
      f32x4 to[4];
      #pragma unroll
      for (int dt=0;dt<4;dt++){
        const int col=(dt<<4)+l15;
        const short* wb = W2_t + (col<<6)+(lhi<<3);
        s16x8 b0=*(const s16x8*)wb, b1v=*(const s16x8*)(wb+32);
        float bias=b2[col];
        f32x4 acc={bias,bias,bias,bias};
        acc=__builtin_amdgcn_mfma_f32_16x16x32_bf16(a0,b0,acc,0,0,0);
        acc=__builtin_amdgcn_mfma_f32_16x16x32_bf16(a1,b1v,acc,0,0,0);
        acc += h1[j][dt];
        to[dt]=acc;
      }
      f32x4 mu, rsq;
      #pragma unroll
      for(int i=0;i<4;i++){
        float sv = to[0][i]+to[1][i]+to[2][i]+to[3][i];
        sv += __shfl_xor(sv,1); sv+=__shfl_xor(sv,2); sv+=__shfl_xor(sv,4); sv+=__shfl_xor(sv,8);
        mu[i]=sv*(1.f/64.f);
      }
      #pragma unroll
      for(int i=0;i<4;i++){
        float sv=0.f;
        #pragma unroll
        for(int dt=0;dt<4;dt++){ float c=to[dt][i]-mu[i]; sv=fmaf(c,c,sv); }
        sv += __shfl_xor(sv,1); sv+=__shfl_xor(sv,2); sv+=__shfl_xor(sv,4); sv+=__shfl_xor(sv,8);
        rsq[i]=1.f/sqrtf(sv*(1.f/64.f)+1e-5f);
      }
      #pragma unroll
      for(int dt=0;dt<4;dt++){
        const int col=(dt<<4)+l15;
        float g=ln2g[col], bb=ln2b[col];
        #pragma unroll
        for(int i=0;i<4;i++){
          const int row=rb+i;
          if (row < len){
            float tv=(to[dt][i]-mu[i])*rsq[i]*g+bb;
            float tin = fmaf(valr[row],proj_w[col], fmaf(obsr[row],proj_w[64+col], proj_b[col]))
                      + pe_g[(((size_t)b<<8)+row)*64+col];
            float ob = obsr[row];
            xtat[((size_t)bn<<14)+(row<<6)+col] = f2bu(ob*tin + (1.f-ob)*tv);
          }
        }
      }
    }
  }
}

// ---------------------------------------------------------------------------
// K35: precompute xt-dependent gate terms + fold u1+rs*u2.
//   Xall[b,t,g,d,n] (bf16) = (xt@Wg_x + (A@xt)@Wg_ax)[n,d] + u1g[d] + rs[n]*u2g[d]
// ---------------------------------------------------------------------------
__global__ void k35_xg(const unsigned short* __restrict__ xtat, const short* __restrict__ Abf,
                       const short* __restrict__ Wg_t, const int* __restrict__ lengths,
                       const float* __restrict__ U, const float* __restrict__ rs_g,
                       unsigned short* __restrict__ Xall)
{
  const int bt = blockIdx.x, b = bt>>8, t = bt&255;
  int len = lengths[b]; if (len<1) len=1;
  if (t >= len) return;
  const int tid = threadIdx.x, w = tid>>6, lane = tid&63;
  const int l15 = lane&15, lhi = lane>>4;
  __shared__ short xt_rm[4096], xt_tp[4096], axt_rm[4096];

  // load xt[n][d] = xtat[b,n,t,:]
  #pragma unroll
  for (int q=0;q<2;q++){
    int e = tid + (q<<8);
    int nn = e>>3, c0 = (e&7)<<3;
    s16x8 v = *(const s16x8*)((const short*)xtat + (((size_t)(b*64+nn)*256 + t)<<6) + c0);
    *(s16x8*)(xt_rm + swzo(nn,c0)) = v;
    #pragma unroll
    for (int jj=0;jj<8;jj++) xt_tp[swzo(c0+jj, nn)] = v[jj];
  }
  __syncthreads();

  // Axt = A @ xt ; wave w computes col-tile w (all 4 row tiles)
  {
    s16x8 bx[2];
    #pragma unroll
    for (int kk=0;kk<2;kk++) bx[kk]=ldfrag(xt_tp, w<<4, lane, kk);
    #pragma unroll
    for (int rt=0;rt<4;rt++){
      f32x4 acc={0.f,0.f,0.f,0.f};
      #pragma unroll
      for (int kk=0;kk<2;kk++){
        s16x8 af = *(const s16x8*)(Abf + ((rt<<4)+l15)*64 + (kk<<5) + (lhi<<3));
        acc=__builtin_amdgcn_mfma_f32_16x16x32_bf16(af,bx[kk],acc,0,0,0);
      }
      const int rb=(rt<<4)+(lhi<<2);
      #pragma unroll
      for(int i=0;i<4;i++) axt_rm[swzo(rb+i,(w<<4)+l15)] = (short)f2bu(acc[i]);
    }
  }
  __syncthreads();

  // Xg = xt@Wg_x + Axt@Wg_ax ; wave w -> out col-tile w for each gate
  s16x8 fx[4][2], fa[4][2];
  #pragma unroll
  for (int rt=0;rt<4;rt++)
    #pragma unroll
    for (int kk=0;kk<2;kk++){
      fx[rt][kk]=ldfrag(xt_rm, rt<<4, lane, kk);
      fa[rt][kk]=ldfrag(axt_rm, rt<<4, lane, kk);
    }
  const int dcol = (w<<4)+l15;
  f32x4 rsv[4];
  #pragma unroll
  for (int rt=0;rt<4;rt++) rsv[rt] = *(const f32x4*)(rs_g + (rt<<4) + (lhi<<2));
  const float* Ub = U + (size_t)bt*384;
  #pragma unroll
  for (int g=0; g<3; g++){
    s16x8 wbx[2], wba[2];
    #pragma unroll
    for (int kk=0;kk<2;kk++){
      wbx[kk] = *(const s16x8*)(Wg_t + (((g<<1)  )*64 + dcol)*64 + (kk<<5)+(lhi<<3));
      wba[kk] = *(const s16x8*)(Wg_t + (((g<<1)+1)*64 + dcol)*64 + (kk<<5)+(lhi<<3));
    }
    float u1 = Ub[(g<<7) + dcol];
    float u2 = Ub[(g<<7) + 64 + dcol];
    #pragma unroll
    for (int rt=0;rt<4;rt++){
      f32x4 acc={u1,u1,u1,u1};
      #pragma unroll
      for (int kk=0;kk<2;kk++){
        acc=__builtin_amdgcn_mfma_f32_16x16x32_bf16(fx[rt][kk],wbx[kk],acc,0,0,0);
        acc=__builtin_amdgcn_mfma_f32_16x16x32_bf16(fa[rt][kk],wba[kk],acc,0,0,0);
      }
      s16x4 pk;
      #pragma unroll
      for(int i=0;i<4;i++) pk[i]=(short)f2bu(acc[i] + rsv[rt][i]*u2);
      *(s16x4*)((short*)Xall + (((size_t)bt*3 + g)*64 + dcol)*64 + (rt<<4)+(lhi<<2)) = pk;
    }
  }
}

// ---------------------------------------------------------------------------
// K4: graph-GRU scan, 2 BATCHES PER BLOCK (16 waves = 2 groups x 8 waves).
//     __launch_bounds__(1024, 4): 4 waves/EU min => 1 block/CU, VGPR cap 128
//     (R9's (1024,1) let the allocator target 64 VGPR -> massive scratch
//     spills of the ~44 loop-invariant VGPRs; WRITE_SIZE 256->3072KB, 4.2x).
// ---------------------------------------------------------------------------
__launch_bounds__(1024, 4)
__global__ void k4_scan(const unsigned short* __restrict__ Xall,
                        const float* __restrict__ decay, const short* __restrict__ Abf,
                        const short* __restrict__ Wg_h,
                        const int* __restrict__ lengths, float* __restrict__ hT)
{
  const int tid = threadIdx.x;
  const int grp = tid >> 9;               // batch group 0..1
  const int stid = tid & 511;             // tid within group
  const int w = stid>>6, lane = stid&63;
  const int l15 = lane&15, lhi = lane>>4;
  const int pe_ = l15&1;
  const int b = blockIdx.x*2 + grp;
  const int gofs = grp << 13;             // byte offset of group's LDS tile
  // gate partition: n-tile rnt, d-tile pair dp
  const int rnt = w>>1, dp = w&1;
  const int nb_ = (rnt<<4) + (lhi<<2);
  const int d0 = (dp<<5) + l15, d1 = (dp<<5) + 16 + l15;
  // A-mult partition: n-tile pair (tmA0,tmA1), d-tile dnA
  const int tmA0 = (w&1)<<1, tmA1 = tmA0+1;
  const int dnA = w>>1;

  __shared__ short h_rm[2][4096], h_tp[2][4096], ah_rm[2][4096];
  __shared__ short rh_rm[2][4096], rh_tp[2][4096], arh_rm[2][4096];
  __shared__ float dec_s[2][256];

  int lenA = lengths[blockIdx.x*2];   if (lenA<1) lenA=1;
  int lenB = lengths[blockIdx.x*2+1]; if (lenB<1) lenB=1;
  const int len = grp ? lenB : lenA;
  const int lenmax = (lenA>lenB)?lenA:lenB;
  for (int e=stid; e<256; e+=512) dec_s[grp][e] = decay[b*256+e];

  // static A fragments (A-operand rows tmA0/tmA1)
  s16x8 aA[2][2];
  #pragma unroll
  for (int t2=0;t2<2;t2++)
    #pragma unroll
    for (int kk=0;kk<2;kk++)
      aA[t2][kk] = *(const s16x8*)(Abf + (((t2?tmA1:tmA0)<<4) + l15)*64 + (kk<<5) + (lhi<<3));

  // static gate weight B-frags: wf[g][s][kk][e]  (s=0: h slice, s=1: Ah slice)
  s16x8 wf[3][2][2][2];
  #pragma unroll
  for (int g=0;g<3;g++)
    #pragma unroll
    for (int s=0;s<2;s++)
      #pragma unroll
      for (int kk=0;kk<2;kk++)
        #pragma unroll
        for (int e=0;e<2;e++)
          wf[g][s][kk][e] = *(const s16x8*)(Wg_h + (((g*2+s)*64 + (e?d1:d0))<<6) + (kk<<5) + (lhi<<3));

  // ---- precomputed LDS byte offsets (loop-invariant, group offset folded) ----
  int tpo[2];
  #pragma unroll
  for (int e=0;e<2;e++){ int r = e?d1:d0; tpo[e] = gofs + r*128 + (((nb_)*2) ^ ((r&7)<<4)); }
  int rmo[4];
  { int dPr = ((dp<<1) + pe_)*16 + (l15 & ~1);
    #pragma unroll
    for (int i=0;i<4;i++){ int n = nb_+i; rmo[i] = gofs + n*128 + ((dPr*2) ^ ((n&7)<<4)); } }
  int amo[4];
  { int dAr = (dnA<<4) + (l15 & ~1);
    int tb = (pe_? tmA1 : tmA0)<<4;
    #pragma unroll
    for (int i=0;i<4;i++){ int n = tb + (lhi<<2) + i; amo[i] = gofs + n*128 + ((dAr*2) ^ ((n&7)<<4)); } }
  int rdT[2], rdR[2];
  { int r = (dnA<<4)+l15;
    #pragma unroll
    for (int kk=0;kk<2;kk++) rdT[kk] = gofs + r*128 + (((kk<<6) + (lhi<<4)) ^ ((r&7)<<4)); }
  { int r = (rnt<<4)+l15;
    #pragma unroll
    for (int kk=0;kk<2;kk++) rdR[kk] = gofs + r*128 + (((kk<<6) + (lhi<<4)) ^ ((r&7)<<4)); }

  f32x4 hreg[2] = {{0.f,0.f,0.f,0.f},{0.f,0.f,0.f,0.f}};
  f32x4 zz[2];

  const short* Xb = (const short*)Xall;
  s16x4 xzc[2], xrc[2], xcc[2], xzn[2], xrn[2], xcn[2];
  #pragma unroll
  for (int e=0;e<2;e++){ xzc[e]=(s16x4){0,0,0,0}; xrc[e]=xzc[e]; xcc[e]=xzc[e]; }
  {
    const short* base = Xb + ((size_t)(b*256))*12288;
    #pragma unroll
    for (int e=0;e<2;e++){
      int de = e?d1:d0;
      xzc[e] = *(const s16x4*)(base + (0*64 + de)*64 + nb_);
      xrc[e] = *(const s16x4*)(base + (1*64 + de)*64 + nb_);
      xcc[e] = *(const s16x4*)(base + (2*64 + de)*64 + nb_);
    }
  }
  __syncthreads();

  for (int t=0; t<lenmax; t++){
    const bool act = (t < len);
    // decay (skip when this group's batch is done)
    float dc = act ? dec_s[grp][t] : 1.f;
    #pragma unroll
    for (int e=0;e<2;e++)
      #pragma unroll
      for (int i=0;i<4;i++) hreg[e][i] *= dc;

    // prefetch X for t+1 (stays in flight across raw barriers)
    #pragma unroll
    for (int e=0;e<2;e++){ xzn[e]=(s16x4){0,0,0,0}; xrn[e]=xzn[e]; xcn[e]=xzn[e]; }
    if (t+1 < len){
      const short* base = Xb + ((size_t)(b*256 + t+1))*12288;
      #pragma unroll
      for (int e=0;e<2;e++){
        int de = e?d1:d0;
        xzn[e] = *(const s16x4*)(base + (0*64 + de)*64 + nb_);
        xrn[e] = *(const s16x4*)(base + (1*64 + de)*64 + nb_);
        xcn[e] = *(const s16x4*)(base + (2*64 + de)*64 + nb_);
      }
    }

    // ---- P0: stage h (tp: b64 per e; rm: b32 pair via DPP) ----
    #pragma unroll
    for (int e=0;e<2;e++){
      i32x2 v; v[0] = (int)cvtpk(hreg[e][0], hreg[e][1]);
               v[1] = (int)cvtpk(hreg[e][2], hreg[e][3]);
      *(i32x2*)((char*)h_tp + tpo[e]) = v;
    }
    #pragma unroll
    for (int i=0;i<4;i++){
      float v0 = hreg[0][i], v1 = hreg[1][i];
      float n0 = dppx1(v0), n1 = dppx1(v1);
      float lo = pe_ ? n1 : v0;
      float hi = pe_ ? v1 : n0;
      *(unsigned*)((char*)h_rm + rmo[i]) = cvtpk(lo, hi);
    }
    BAR();

    // ---- P1: Ah = A@h -> ah_rm ----
    {
      s16x8 bh0 = *(const s16x8*)((const char*)h_tp + rdT[0]);
      s16x8 bh1 = *(const s16x8*)((const char*)h_tp + rdT[1]);
      f32x4 a0v={0.f,0.f,0.f,0.f}, a1v={0.f,0.f,0.f,0.f};
      a0v = __builtin_amdgcn_mfma_f32_16x16x32_bf16(aA[0][0], bh0, a0v, 0,0,0);
      a0v = __builtin_amdgcn_mfma_f32_16x16x32_bf16(aA[0][1], bh1, a0v, 0,0,0);
      a1v = __builtin_amdgcn_mfma_f32_16x16x32_bf16(aA[1][0], bh0, a1v, 0,0,0);
      a1v = __builtin_amdgcn_mfma_f32_16x16x32_bf16(aA[1][1], bh1, a1v, 0,0,0);
      #pragma unroll
      for (int i=0;i<4;i++){
        float n0 = dppx1(a0v[i]), n1 = dppx1(a1v[i]);
        float lo = pe_ ? n1 : a0v[i];
        float hi = pe_ ? a1v[i] : n0;
        *(unsigned*)((char*)ah_rm + amo[i]) = cvtpk(lo, hi);
      }
    }
    BAR();

    // ---- P2: z,r gates ----
    {
      s16x8 fh0 = *(const s16x8*)((const char*)h_rm  + rdR[0]);
      s16x8 fh1 = *(const s16x8*)((const char*)h_rm  + rdR[1]);
      s16x8 fa0 = *(const s16x8*)((const char*)ah_rm + rdR[0]);
      s16x8 fa1 = *(const s16x8*)((const char*)ah_rm + rdR[1]);
      f32x4 gz[2], gr[2], rh[2];
      #pragma unroll
      for (int e=0;e<2;e++)
        #pragma unroll
        for (int i=0;i<4;i++){ gz[e][i]=bs2f(xzc[e][i]); gr[e][i]=bs2f(xrc[e][i]); }
      #pragma unroll
      for (int e=0;e<2;e++){
        gz[e] = __builtin_amdgcn_mfma_f32_16x16x32_bf16(fh0, wf[0][0][0][e], gz[e], 0,0,0);
        gz[e] = __builtin_amdgcn_mfma_f32_16x16x32_bf16(fh1, wf[0][0][1][e], gz[e], 0,0,0);
        gz[e] = __builtin_amdgcn_mfma_f32_16x16x32_bf16(fa0, wf[0][1][0][e], gz[e], 0,0,0);
        gz[e] = __builtin_amdgcn_mfma_f32_16x16x32_bf16(fa1, wf[0][1][1][e], gz[e], 0,0,0);
        gr[e] = __builtin_amdgcn_mfma_f32_16x16x32_bf16(fh0, wf[1][0][0][e], gr[e], 0,0,0);
        gr[e] = __builtin_amdgcn_mfma_f32_16x16x32_bf16(fh1, wf[1][0][1][e], gr[e], 0,0,0);
        gr[e] = __builtin_amdgcn_mfma_f32_16x16x32_bf16(fa0, wf[1][1][0][e], gr[e], 0,0,0);
        gr[e] = __builtin_amdgcn_mfma_f32_16x16x32_bf16(fa1, wf[1][1][1][e], gr[e], 0,0,0);
      }
      #pragma unroll
      for (int e=0;e<2;e++)
        #pragma unroll
        for (int i=0;i<4;i++){
          float zv = 1.f/(1.f+__expf(-gz[e][i]));
          float rv = 1.f/(1.f+__expf(-gr[e][i]));
          zz[e][i] = zv;
          rh[e][i] = rv * hreg[e][i];
        }
      // stage rh: tp b64 per e + rm b32 pairs via DPP
      #pragma unroll
      for (int e=0;e<2;e++){
        i32x2 v; v[0] = (int)cvtpk(rh[e][0], rh[e][1]);
                 v[1] = (int)cvtpk(rh[e][2], rh[e][3]);
        *(i32x2*)((char*)rh_tp + tpo[e]) = v;
      }
      #pragma unroll
      for (int i=0;i<4;i++){
        float v0 = rh[0][i], v1 = rh[1][i];
        float n0 = dppx1(v0), n1 = dppx1(v1);
        float lo = pe_ ? n1 : v0;
        float hi = pe_ ? v1 : n0;
        *(unsigned*)((char*)rh_rm + rmo[i]) = cvtpk(lo, hi);
      }
    }
    BAR();

    // ---- P3: Arh = A@rh -> arh_rm ----
    {
      s16x8 br0 = *(const s16x8*)((const char*)rh_tp + rdT[0]);
      s16x8 br1 = *(const s16x8*)((const char*)rh_tp + rdT[1]);
      f32x4 a0v={0.f,0.f,0.f,0.f}, a1v={0.f,0.f,0.f,0.f};
      a0v = __builtin_amdgcn_mfma_f32_16x16x32_bf16(aA[0][0], br0, a0v, 0,0,0);
      a0v = __builtin_amdgcn_mfma_f32_16x16x32_bf16(aA[0][1], br1, a0v, 0,0,0);
      a1v = __builtin_amdgcn_mfma_f32_16x16x32_bf16(aA[1][0], br0, a1v, 0,0,0);
      a1v = __builtin_amdgcn_mfma_f32_16x16x32_bf16(aA[1][1], br1, a1v, 0,0,0);
      #pragma unroll
      for (int i=0;i<4;i++){
        float n0 = dppx1(a0v[i]), n1 = dppx1(a1v[i]);
        float lo = pe_ ? n1 : a0v[i];
        float hi = pe_ ? a1v[i] : n0;
        *(unsigned*)((char*)arh_rm + amo[i]) = cvtpk(lo, hi);
      }
    }
    BAR();

    // ---- P4: c gate + h update ----
    {
      s16x8 fr0 = *(const s16x8*)((const char*)rh_rm  + rdR[0]);
      s16x8 fr1 = *(const s16x8*)((const char*)rh_rm  + rdR[1]);
      s16x8 fb0 = *(const s16x8*)((const char*)arh_rm + rdR[0]);
      s16x8 fb1 = *(const s16x8*)((const char*)arh_rm + rdR[1]);
      f32x4 gc[2];
      #pragma unroll
      for (int e=0;e<2;e++)
        #pragma unroll
        for (int i=0;i<4;i++) gc[e][i]=bs2f(xcc[e][i]);
      #pragma unroll
      for (int e=0;e<2;e++){
        gc[e] = __builtin_amdgcn_mfma_f32_16x16x32_bf16(fr0, wf[2][0][0][e], gc[e], 0,0,0);
        gc[e] = __builtin_amdgcn_mfma_f32_16x16x32_bf16(fr1, wf[2][0][1][e], gc[e], 0,0,0);
        gc[e] = __builtin_amdgcn_mfma_f32_16x16x32_bf16(fb0, wf[2][1][0][e], gc[e], 0,0,0);
        gc[e] = __builtin_amdgcn_mfma_f32_16x16x32_bf16(fb1, wf[2][1][1][e], gc[e], 0,0,0);
      }
      if (act){
        #pragma unroll
        for (int e=0;e<2;e++)
          #pragma unroll
          for (int i=0;i<4;i++){
            float cv = 1.f - 2.f/(__expf(2.f*gc[e][i])+1.f);   // tanh
            hreg[e][i] = fmaf(zz[e][i], hreg[e][i]-cv, cv);
          }
      }
    }

    // rotate prefetch
    #pragma unroll
    for (int e=0;e<2;e++){ xzc[e]=xzn[e]; xrc[e]=xrn[e]; xcc[e]=xcn[e]; }
  }

  // suffix decay for t in [len,256)
  float sp = 1.f;
  for (int t=len; t<256; t++) sp *= dec_s[grp][t];
  #pragma unroll
  for (int e=0;e<2;e++)
    #pragma unroll
    for (int i=0;i<4;i++)
      hT[(((size_t)b<<6) + nb_ + i)*64 + (e?d1:d0)] = hreg[e][i]*sp;
}

// ---------------------------------------------------------------------------
// K5: classifier head
// ---------------------------------------------------------------------------
__global__ void k5_head(const float* __restrict__ hT, const float* __restrict__ Wfin,
                        const float* __restrict__ bfin,
                        const float* __restrict__ stat, const float* __restrict__ We,
                        const float* __restrict__ be,
                        const float* __restrict__ Wc1, const float* __restrict__ bc1,
                        const float* __restrict__ Wc2, const float* __restrict__ bc2,
                        float* __restrict__ out)
{
  const int b = blockIdx.x, tid = threadIdx.x;
  __shared__ float cat[128];
  __shared__ float hcl[200];
  if (tid < 64){
    const float* hr = hT + (((size_t)b<<6)+tid)*64;
    float a = bfin[0];
    #pragma unroll
    for (int d=0;d<64;d++) a = fmaf(hr[d], Wfin[d], a);
    cat[tid]=a;
  } else if (tid < 128){
    int nn = tid-64;
    float a = be[nn];
    #pragma unroll
    for (int k=0;k<9;k++) a = fmaf(stat[b*9+k], We[k*64+nn], a);
    cat[tid]=a;
  }
  __syncthreads();
  if (tid < 200){
    float a = bc1[tid];
    for (int k=0;k<128;k++) a = fmaf(cat[k], Wc1[k*200+tid], a);
    hcl[tid] = fmaxf(a, 0.f);
  }
  __syncthreads();
  if (tid < 2){
    float a = bc2[tid];
    for (int k=0;k<200;k++) a = fmaf(hcl[k], Wc2[k*2+tid], a);
    out[b*2+tid] = a;
  }
}

// ---------------------------------------------------------------------------
extern "C" void kernel_launch(void* const* d_in, const int* in_sizes, int n_in,
                              void* d_out, int out_size, void* d_ws, size_t ws_size,
                              hipStream_t stream)
{
  const float* x       = (const float*)d_in[0];
  const float* nufft   = (const float*)d_in[1];
  const float* delta_t = (const float*)d_in[2];
  const float* stat    = (const float*)d_in[3];
  const int*   lengths = (const int*)  d_in[4];
  const float* proj_w  = (const float*)d_in[5];
  const float* proj_b  = (const float*)d_in[6];
  const float* Wqkv    = (const float*)d_in[7];
  const float* bqkv    = (const float*)d_in[8];
  const float* Wo      = (const float*)d_in[9];
  const float* bo      = (const float*)d_in[10];
  const float* ln1g    = (const float*)d_in[11];
  const float* ln1b    = (const float*)d_in[12];
  const float* W1      = (const float*)d_in[13];
  const float* b1      = (const float*)d_in[14];
  const float* W2      = (const float*)d_in[15];
  const float* b2      = (const float*)d_in[16];
  const float* ln2g    = (const float*)d_in[17];
  const float* ln2b    = (const float*)d_in[18];
  const float* WQf     = (const float*)d_in[19];
  const float* WKf     = (const float*)d_in[20];
  const float* Wz      = (const float*)d_in[21];
  const float* bz      = (const float*)d_in[22];
  const float* Wr      = (const float*)d_in[23];
  const float* br      = (const float*)d_in[24];
  const float* Wc      = (const float*)d_in[25];
  const float* bc      = (const float*)d_in[26];
  const float* Wfin    = (const float*)d_in[27];
  const float* bfin    = (const float*)d_in[28];
  const float* We      = (const float*)d_in[29];
  const float* be      = (const float*)d_in[30];
  const float* Wc1     = (const float*)d_in[31];
  const float* bc1     = (const float*)d_in[32];
  const float* Wc2     = (const float*)d_in[33];
  const float* bc2     = (const float*)d_in[34];
  float* out = (float*)d_out;

  char* ws = (char*)d_ws;
  size_t o = 0;
  float* pe    = (float*)(ws+o); o += (size_t)4096*64*4;
  float* U     = (float*)(ws+o); o += (size_t)4096*384*4;
  float* decay = (float*)(ws+o); o += (size_t)4096*4;
  unsigned short* xtat = (unsigned short*)(ws+o); o += (size_t)1024*256*64*2;
  float* qf    = (float*)(ws+o); o += (size_t)1024*256*4;
  float* kf    = (float*)(ws+o); o += (size_t)1024*256*4;
  float* soft  = (float*)(ws+o); o += (size_t)16*4096*4;
  short* Abf   = (short*)(ws+o); o += (size_t)4096*2;
  float* rs    = (float*)(ws+o); o += (size_t)64*4;
  float* hT    = (float*)(ws+o); o += (size_t)16*64*64*4;
  short* Wqkv_t= (short*)(ws+o); o += (size_t)12288*2;
  short* Wo_t  = (short*)(ws+o); o += (size_t)4096*2;
  short* W1_t  = (short*)(ws+o); o += (size_t)4096*2;
  short* W2_t  = (short*)(ws+o); o += (size_t)4096*2;
  short* Wg_t  = (short*)(ws+o); o += (size_t)24576*2;
  short* Wg_h  = (short*)(ws+o); o += (size_t)24576*2;
  unsigned short* Xall = (unsigned short*)(ws+o); o += (size_t)4096*3*4096*2;  // ~100 MB
  (void)ws_size; (void)in_sizes; (void)n_in; (void)out_size;

  hipLaunchKernelGGL(k0_prep,   dim3(288),  dim3(256), 0, stream,
                     Wqkv, Wo, W1, W2, Wz, Wr, Wc, Wqkv_t, Wo_t, W1_t, W2_t, Wg_t, Wg_h);
  hipLaunchKernelGGL(k1_pe_u,   dim3(1024), dim3(256), 0, stream,
                     x, delta_t, Wz, bz, Wr, br, Wc, bc, pe, U, decay);
  hipLaunchKernelGGL(k2a_qfkf,  dim3(1024), dim3(256), 0, stream,
                     nufft, WQf, WKf, qf, kf);
  hipLaunchKernelGGL(k2b_soft,  dim3(16),   dim3(256), 0, stream, qf, kf, soft);
  hipLaunchKernelGGL(k2c_A,     dim3(1),    dim3(256), 0, stream, soft, Abf, rs);
  hipLaunchKernelGGL(k3_former, dim3(1024), dim3(512), 0, stream,
                     x, pe, proj_w, proj_b, Wqkv_t, bqkv, Wo_t, bo, ln1g, ln1b,
                     W1_t, b1, W2_t, b2, ln2g, ln2b, lengths, xtat);
  hipLaunchKernelGGL(k35_xg,    dim3(4096), dim3(256), 0, stream,
                     xtat, Abf, Wg_t, lengths, U, rs, Xall);
  hipLaunchKernelGGL(k4_scan,   dim3(8),    dim3(1024), 0, stream,
                     Xall, decay, Abf, Wg_h, lengths, hT);
  hipLaunchKernelGGL(k5_head,   dim3(16),   dim3(256), 0, stream,
                     hT, Wfin, bfin, stat, We, be, Wc1, bc1, Wc2, bc2, out);
}

// Round 11
// 2863.577 us; speedup vs baseline: 1.0003x; 1.0003x over previous
//
#include <hip/hip_runtime.h>
#include <hip/hip_bf16.h>
#include <cmath>

#define DEV __device__ __forceinline__

typedef short s16x8 __attribute__((ext_vector_type(8)));
typedef short s16x4 __attribute__((ext_vector_type(4)));
typedef float f32x4 __attribute__((ext_vector_type(4)));
typedef int   i32x2 __attribute__((ext_vector_type(2)));

DEV unsigned short f2bu(float x){
  __hip_bfloat16 h = __float2bfloat16(x);
  return *reinterpret_cast<unsigned short*>(&h);
}
DEV float bs2f(unsigned short v){ return __uint_as_float(((unsigned)v)<<16); }
DEV float bs2f(short v){ return bs2f((unsigned short)v); }

DEV unsigned cvtpk(float lo, float hi){
  unsigned r;
  asm("v_cvt_pk_bf16_f32 %0, %1, %2" : "=v"(r) : "v"(lo), "v"(hi));
  return r;
}
DEV float dppx1(float v){   // value from lane^1 (quad_perm 1,0,3,2)
  int r = __builtin_amdgcn_mov_dpp(__float_as_int(v), 0xB1, 0xF, 0xF, true);
  return __int_as_float(r);
}

#define BAR() do { asm volatile("s_waitcnt lgkmcnt(0)" ::: "memory"); \
                   __builtin_amdgcn_s_barrier(); \
                   __builtin_amdgcn_sched_barrier(0); } while(0)

// swizzled [R][64] bf16 tile helpers (row stride 128B, byte ^= (row&7)<<4)
DEV int swzo(int row, int col){
  return (row*128 + ((col*2) ^ ((row&7)<<4))) >> 1;
}
DEV s16x8 ldfrag(const short* tile, int t16, int lane, int kk){
  int row = t16 + (lane & 15);
  int c0  = (kk<<5) + ((lane>>4)<<3);
  int off = (row*128 + ((c0<<1) ^ ((row&7)<<4))) >> 1;
  return *(const s16x8*)(tile + off);
}
// swizzled [64][256] bf16 (V^T) tile: row stride 512B
DEV int swzv(int d, int t){
  return (d*512 + ((t*2) ^ ((d&7)<<4))) >> 1;
}

// ---------------------------------------------------------------------------
// K0: weight prep. Wqkv_t[192][64], Wo_t/W1_t/W2_t[64][64] (bf16 transposed),
//     Wg_t[3][2][64c][64k] (gate slices xt:0.. / Axt:192..) for k35,
//     Wg_h[3][2][64c][64k] (gate slices h:64.. / Ah:256..) for k4.
// ---------------------------------------------------------------------------
__global__ void k0_prep(const float* __restrict__ Wqkv, const float* __restrict__ Wo,
                        const float* __restrict__ W1, const float* __restrict__ W2,
                        const float* __restrict__ Wz, const float* __restrict__ Wr,
                        const float* __restrict__ Wc,
                        short* __restrict__ Wqkv_t, short* __restrict__ Wo_t,
                        short* __restrict__ W1_t, short* __restrict__ W2_t,
                        short* __restrict__ Wg_t, short* __restrict__ Wg_h)
{
  int t = blockIdx.x*256 + threadIdx.x;
  if (t < 12288){ int nn=t>>6, k=t&63; Wqkv_t[t]=(short)f2bu(Wqkv[k*192+nn]); }
  else if (t < 16384){ int e=t-12288; int nn=e>>6,k=e&63; Wo_t[e]=(short)f2bu(Wo[k*64+nn]); }
  else if (t < 20480){ int e=t-16384; int nn=e>>6,k=e&63; W1_t[e]=(short)f2bu(W1[k*64+nn]); }
  else if (t < 24576){ int e=t-20480; int nn=e>>6,k=e&63; W2_t[e]=(short)f2bu(W2[k*64+nn]); }
  else if (t < 49152){
    int e=t-24576;
    int g=e>>13, rem=e&8191, s=rem>>12, rem2=rem&4095, c=rem2>>6, k=rem2&63;
    const float* Wg = (g==0)?Wz:((g==1)?Wr:Wc);
    Wg_t[e] = (short)f2bu(Wg[((s?192:0)+k)*64 + c]);
  }
  else if (t < 73728){
    int e=t-49152;
    int g=e>>13, rem=e&8191, s=rem>>12, rem2=rem&4095, c=rem2>>6, k=rem2&63;
    const float* Wg = (g==0)?Wz:((g==1)?Wr:Wc);
    Wg_h[e] = (short)f2bu(Wg[((s?256:64)+k)*64 + c]);
  }
}

// ---------------------------------------------------------------------------
// K1: positional encoding pe[b,t,64], te-derived gate vectors U[b,t,6,64],
//     decay. 4 (b,t) pairs per 256-thread block: weight reads shared 4-way.
// ---------------------------------------------------------------------------
__global__ void k1_pe_u(const float* __restrict__ x, const float* __restrict__ delta_t,
                        const float* __restrict__ Wz, const float* __restrict__ bz,
                        const float* __restrict__ Wr, const float* __restrict__ br,
                        const float* __restrict__ Wc, const float* __restrict__ bc,
                        float* __restrict__ pe, float* __restrict__ U, float* __restrict__ decay)
{
  const int q  = threadIdx.x >> 6;          // sub-block 0..3
  const int d  = threadIdx.x & 63;          // 0..63
  const int bt = blockIdx.x*4 + q;          // b*256 + t
  __shared__ float pes[4][64];
  float tmv = x[(size_t)bt*129 + 128];      // times
  int j = d & 31;
  float ts = exp2f((float)j * (8.0f/31.0f));   // 256^(j/31)
  float st = tmv / ts;
  float v = (d < 32) ? sinf(st) : cosf(st);
  pes[q][d] = v;
  pe[(size_t)bt*64 + d] = v;
  __syncthreads();
  float a0=bz[d], a1=0.f, a2=br[d], a3=0.f, a4=bc[d], a5=0.f;
  for (int k=0;k<64;k++){
    float p = pes[q][k];
    a0 = fmaf(p, Wz[(128+k)*64+d], a0);
    a1 = fmaf(p, Wz[(320+k)*64+d], a1);
    a2 = fmaf(p, Wr[(128+k)*64+d], a2);
    a3 = fmaf(p, Wr[(320+k)*64+d], a3);
    a4 = fmaf(p, Wc[(128+k)*64+d], a4);
    a5 = fmaf(p, Wc[(320+k)*64+d], a5);
  }
  float* u = U + (size_t)bt*384;
  u[d]=a0; u[64+d]=a1; u[128+d]=a2; u[192+d]=a3; u[256+d]=a4; u[320+d]=a5;
  if (d==0) decay[bt] = expf(-fmaxf(delta_t[bt], 0.f));
}

// ---------------------------------------------------------------------------
// K2a: qf = xf@WQ_f, kf = xf@WK_f   (xf[b,n,t] = nufft[b,1,t,n])
// ---------------------------------------------------------------------------
__global__ void k2a_qfkf(const float* __restrict__ nufft, const float* __restrict__ WQf,
                         const float* __restrict__ WKf, float* __restrict__ qf, float* __restrict__ kf)
{
  const int bn = blockIdx.x, b = bn>>6, n = bn&63;
  const int u = threadIdx.x;  // 0..255
  __shared__ float xs[256];
  xs[u] = nufft[ ((((size_t)b*2)+1)*256 + u)*64 + n ];
  __syncthreads();
  float aq=0.f, ak=0.f;
  for (int t=0;t<256;t++){
    float xv = xs[t];
    aq = fmaf(xv, WQf[t*256+u], aq);
    ak = fmaf(xv, WKf[t*256+u], ak);
  }
  qf[(size_t)bn*256+u]=aq;
  kf[(size_t)bn*256+u]=ak;
}

// ---------------------------------------------------------------------------
// K2b: per-batch S=relu(qf·kf)/16, row-softmax -> soft[b,64,64]
// ---------------------------------------------------------------------------
__launch_bounds__(256, 1)
__global__ void k2b_soft(const float* __restrict__ qf, const float* __restrict__ kf,
                         float* __restrict__ soft)
{
  const int b = blockIdx.x, tid = threadIdx.x;
  __shared__ float qs[64*257];
  __shared__ float ksh[64*257];
  __shared__ float Ss[64*65];
  const float* qb = qf + ((size_t)b<<14);
  const float* kb = kf + ((size_t)b<<14);
  for (int e=tid; e<16384; e+=256){
    int r=e>>8, c=e&255;
    qs[r*257+c]=qb[e];
    ksh[r*257+c]=kb[e];
  }
  __syncthreads();
  const int n = tid>>2, m0 = (tid&3)<<4;
  float acc[16];
  #pragma unroll
  for (int i=0;i<16;i++) acc[i]=0.f;
  for (int t=0;t<256;t++){
    float qv = qs[n*257+t];
    #pragma unroll
    for (int i=0;i<16;i++) acc[i] = fmaf(qv, ksh[(m0+i)*257+t], acc[i]);
  }
  #pragma unroll
  for (int i=0;i<16;i++) Ss[n*65+m0+i] = fmaxf(acc[i],0.f)*(1.f/16.f);
  __syncthreads();
  if (tid < 64){
    float mx=-1e30f;
    for (int m=0;m<64;m++) mx=fmaxf(mx, Ss[tid*65+m]);
    float s=0.f;
    for (int m=0;m<64;m++) s += expf(Ss[tid*65+m]-mx);
    float inv=1.f/s;
    for (int m=0;m<64;m++) soft[((size_t)b<<12)+(tid<<6)+m] = expf(Ss[tid*65+m]-mx)*inv;
  }
}

// ---------------------------------------------------------------------------
// K2c: A = 0.5(sm+sm^T) with sm = softmax(0.5(A0+A0^T)); A0 = mean_b soft.
// ---------------------------------------------------------------------------
__global__ void k2c_A(const float* __restrict__ soft, short* __restrict__ Abf,
                      float* __restrict__ rs_out)
{
  const int tid = threadIdx.x; // 256
  __shared__ float A0[64*65];
  __shared__ float A1[64*65];
  for (int e=tid; e<4096; e+=256){
    int nn=e>>6, mm=e&63;
    float s=0.f;
    #pragma unroll
    for (int b=0;b<16;b++) s += soft[((size_t)b<<12)+e];
    A0[nn*65+mm] = s*(1.f/16.f);
  }
  __syncthreads();
  for (int e=tid; e<4096; e+=256){
    int nn=e>>6, mm=e&63;
    A1[nn*65+mm] = 0.5f*(A0[nn*65+mm]+A0[mm*65+nn]);
  }
  __syncthreads();
  if (tid < 64){
    float mx=-1e30f;
    for (int m=0;m<64;m++) mx=fmaxf(mx, A1[tid*65+m]);
    float s=0.f;
    for (int m=0;m<64;m++) s += expf(A1[tid*65+m]-mx);
    float inv=1.f/s;
    for (int m=0;m<64;m++) A0[tid*65+m] = expf(A1[tid*65+m]-mx)*inv;
  }
  __syncthreads();
  for (int e=tid; e<4096; e+=256){
    int nn=e>>6, mm=e&63;
    float a = 0.5f*(A0[nn*65+mm]+A0[mm*65+nn]);
    A1[nn*65+mm] = a;
    Abf[e] = (short)f2bu(a);
  }
  __syncthreads();
  if (tid < 64){
    float s=0.f;
    for (int m=0;m<64;m++) s += A1[tid*65+m];
    rs_out[tid]=s;
  }
}

// ---------------------------------------------------------------------------
// K3: per-(b,n) transformer head via MFMA -> x_tat (bf16).
// ---------------------------------------------------------------------------
__launch_bounds__(512, 1)
__global__ void k3_former(const float* __restrict__ x, const float* __restrict__ pe_g,
    const float* __restrict__ proj_w, const float* __restrict__ proj_b,
    const short* __restrict__ Wqkv_t, const float* __restrict__ bqkv,
    const short* __restrict__ Wo_t, const float* __restrict__ bo,
    const float* __restrict__ ln1g, const float* __restrict__ ln1b,
    const short* __restrict__ W1_t, const float* __restrict__ b1,
    const short* __restrict__ W2_t, const float* __restrict__ b2,
    const float* __restrict__ ln2g, const float* __restrict__ ln2b,
    const int* __restrict__ lengths, unsigned short* __restrict__ xtat)
{
  const int bn = blockIdx.x, b = bn>>6, n = bn&63;
  const int tid = threadIdx.x, w = tid>>6, lane = tid&63;
  const int l15 = lane&15, lhi = lane>>4;
  __shared__ short tp_s[16384];
  __shared__ short q_s[16384];
  __shared__ short k_s[16384];
  __shared__ short v_t[16384];
  __shared__ float valr[256], obsr[256];

  int len = lengths[b]; if (len<1) len=1;
  const int LT = (len+15)>>4;
  const int KB = (len+63)>>6;

  if (tid < 256){
    const float* xr = x + ((size_t)b*256+tid)*129;
    valr[tid]=xr[n]; obsr[tid]=xr[64+n];
  }
  for (int e=tid; e<16384; e+=512) v_t[e]=0;
  __syncthreads();

  const int nrows = LT<<4;
  for (int e=tid; e<(nrows<<6); e+=512){
    int t=e>>6, d=e&63;
    float ti = fmaf(valr[t],proj_w[d], fmaf(obsr[t],proj_w[64+d], proj_b[d]))
             + pe_g[(((size_t)b<<8)+t)*64+d];
    tp_s[swzo(t,d)] = (short)f2bu(ti);
  }
  __syncthreads();

  // ---- QKV ----
  #pragma unroll
  for (int j=0;j<2;j++){
    const int rt = w + (j<<3);
    if (rt < LT){
      s16x8 a0 = ldfrag(tp_s, rt<<4, lane, 0);
      s16x8 a1 = ldfrag(tp_s, rt<<4, lane, 1);
      const int rb = (rt<<4) + (lhi<<2);
      #pragma unroll
      for (int nt=0; nt<12; nt++){
        const short* wb = Wqkv_t + (((nt<<4)+l15)<<6) + (lhi<<3);
        s16x8 b0 = *(const s16x8*)wb;
        s16x8 b1v = *(const s16x8*)(wb+32);
        float bias = bqkv[(nt<<4)+l15];
        f32x4 acc = {bias,bias,bias,bias};
        acc = __builtin_amdgcn_mfma_f32_16x16x32_bf16(a0,b0,acc,0,0,0);
        acc = __builtin_amdgcn_mfma_f32_16x16x32_bf16(a1,b1v,acc,0,0,0);
        const int col = ((nt&3)<<4) + l15;
        if (nt<4){
          #pragma unroll
          for(int i=0;i<4;i++) q_s[swzo(rb+i,col)] = (short)f2bu(acc[i]*0.125f);
        } else if (nt<8){
          #pragma unroll
          for(int i=0;i<4;i++) k_s[swzo(rb+i,col)] = (short)f2bu(acc[i]);
        } else {
          #pragma unroll
          for(int i=0;i<4;i++) v_t[swzv(col, rb+i)] = (short)f2bu(acc[i]);
        }
      }
    }
  }
  __syncthreads();

  // ---- attention ----
  f32x4 Oac[2][4];
  float rsum[2][4];
  #pragma unroll
  for(int j=0;j<2;j++)
    #pragma unroll
    for(int dt=0;dt<4;dt++) Oac[j][dt]=(f32x4){0.f,0.f,0.f,0.f};
  #pragma unroll
  for(int j=0;j<2;j++)
    #pragma unroll
    for(int i=0;i<4;i++) rsum[j][i]=0.f;

  for (int kb=0; kb<KB; kb++){
    s16x8 kf[4][2];
    #pragma unroll
    for (int ct=0;ct<4;ct++){
      kf[ct][0]=ldfrag(k_s, (((kb<<2)+ct)<<4), lane, 0);
      kf[ct][1]=ldfrag(k_s, (((kb<<2)+ct)<<4), lane, 1);
    }
    #pragma unroll
    for (int j=0;j<2;j++){
      const int rt=w+(j<<3);
      if (rt < LT){
        s16x8 q0=ldfrag(q_s, rt<<4, lane, 0);
        s16x8 q1=ldfrag(q_s, rt<<4, lane, 1);
        const int rb=(rt<<4)+(lhi<<2);
        #pragma unroll
        for (int ct=0;ct<4;ct++){
          f32x4 s={0.f,0.f,0.f,0.f};
          s=__builtin_amdgcn_mfma_f32_16x16x32_bf16(q0,kf[ct][0],s,0,0,0);
          s=__builtin_amdgcn_mfma_f32_16x16x32_bf16(q1,kf[ct][1],s,0,0,0);
          const int key=(kb<<6)+(ct<<4)+l15;
          #pragma unroll
          for(int i=0;i<4;i++){
            float p = (key<len) ? __expf(s[i]) : 0.f;
            rsum[j][i]+=p;
            tp_s[swzo(rb+i,(ct<<4)+l15)] = (short)f2bu(p);
          }
        }
      }
    }
    __syncthreads();
    s16x8 vf[4][2];
    #pragma unroll
    for (int dt=0;dt<4;dt++){
      const int d=(dt<<4)+l15;
      #pragma unroll
      for (int kk=0;kk<2;kk++){
        const int k0=(kk<<5)+(lhi<<3);
        vf[dt][kk] = *(const s16x8*)(v_t + swzv(d, (kb<<6)+k0));
      }
    }
    #pragma unroll
    for (int j=0;j<2;j++){
      const int rt=w+(j<<3);
      if (rt < LT){
        s16x8 p0=ldfrag(tp_s, rt<<4, lane, 0);
        s16x8 p1=ldfrag(tp_s, rt<<4, lane, 1);
        #pragma unroll
        for (int dt=0;dt<4;dt++){
          Oac[j][dt]=__builtin_amdgcn_mfma_f32_16x16x32_bf16(p0,vf[dt][0],Oac[j][dt],0,0,0);
          Oac[j][dt]=__builtin_amdgcn_mfma_f32_16x16x32_bf16(p1,vf[dt][1],Oac[j][dt],0,0,0);
        }
      }
    }
    __syncthreads();
  }

  float inv[2][4];
  #pragma unroll
  for(int j=0;j<2;j++)
    #pragma unroll
    for(int i=0;i<4;i++){
      float v=rsum[j][i];
      v += __shfl_xor(v,1); v += __shfl_xor(v,2); v += __shfl_xor(v,4); v += __shfl_xor(v,8);
      inv[j][i]=1.f/v;
    }

  #pragma unroll
  for (int j=0;j<2;j++){
    const int rt=w+(j<<3);
    if (rt < LT){
      const int rb=(rt<<4)+(lhi<<2);
      #pragma unroll
      for (int dt=0;dt<4;dt++)
        #pragma unroll
        for (int i=0;i<4;i++)
          q_s[swzo(rb+i,(dt<<4)+l15)] = (short)f2bu(Oac[j][dt][i]*inv[j][i]);
    }
  }
  __syncthreads();

  f32x4 h1[2][4];
  #pragma unroll
  for (int j=0;j<2;j++){
    const int rt=w+(j<<3);
    if (rt < LT){
      s16x8 a0=ldfrag(q_s, rt<<4, lane, 0);
      s16x8 a1=ldfrag(q_s, rt<<4, lane, 1);
      const int rb=(rt<<4)+(lhi<<2);
      #pragma unroll
      for (int dt=0;dt<4;dt++){
        const int col=(dt<<4)+l15;
        const short* wb = Wo_t + (col<<6) + (lhi<<3);
        s16x8 b0=*(const s16x8*)wb, b1v=*(const s16x8*)(wb+32);
        float bias=bo[col];
        f32x4 acc={bias,bias,bias,bias};
        acc=__builtin_amdgcn_mfma_f32_16x16x32_bf16(a0,b0,acc,0,0,0);
        acc=__builtin_amdgcn_mfma_f32_16x16x32_bf16(a1,b1v,acc,0,0,0);
        #pragma unroll
        for(int i=0;i<4;i++){
          const int row=rb+i;
          acc[i]+= fmaf(valr[row],proj_w[col], fmaf(obsr[row],proj_w[64+col], proj_b[col]))
                 + pe_g[(((size_t)b<<8)+row)*64+col];
        }
        h1[j][dt]=acc;
      }
      f32x4 mu, rsq;
      #pragma unroll
      for(int i=0;i<4;i++){
        float sv = h1[j][0][i]+h1[j][1][i]+h1[j][2][i]+h1[j][3][i];
        sv += __shfl_xor(sv,1); sv+=__shfl_xor(sv,2); sv+=__shfl_xor(sv,4); sv+=__shfl_xor(sv,8);
        mu[i]=sv*(1.f/64.f);
      }
      #pragma unroll
      for(int i=0;i<4;i++){
        float sv=0.f;
        #pragma unroll
        for(int dt=0;dt<4;dt++){ float c=h1[j][dt][i]-mu[i]; sv=fmaf(c,c,sv); }
        sv += __shfl_xor(sv,1); sv+=__shfl_xor(sv,2); sv+=__shfl_xor(sv,4); sv+=__shfl_xor(sv,8);
        rsq[i]=1.f/sqrtf(sv*(1.f/64.f)+1e-5f);
      }
      #pragma unroll
      for(int dt=0;dt<4;dt++){
        const int col=(dt<<4)+l15;
        float g=ln1g[col], bb=ln1b[col];
        #pragma unroll
        for(int i=0;i<4;i++){
          float hv=(h1[j][dt][i]-mu[i])*rsq[i]*g+bb;
          h1[j][dt][i]=hv;
          k_s[swzo(rb+i,col)] = (short)f2bu(hv);
        }
      }
    }
  }
  __syncthreads();

  #pragma unroll
  for (int j=0;j<2;j++){
    const int rt=w+(j<<3);
    if (rt < LT){
      s16x8 a0=ldfrag(k_s, rt<<4, lane, 0);
      s16x8 a1=ldfrag(k_s, rt<<4, lane, 1);
      const int rb=(rt<<4)+(lhi<<2);
      #pragma unroll
      for (int dt=0;dt<4;dt++){
        const int col=(dt<<4)+l15;
        const short* wb = W1_t + (col<<6)+(lhi<<3);
        s16x8 b0=*(const s16x8*)wb, b1v=*(const s16x8*)(wb+32);
        float bias=b1[col];
        f32x4 acc={bias,bias,bias,bias};
        acc=__builtin_amdgcn_mfma_f32_16x16x32_bf16(a0,b0,acc,0,0,0);
        acc=__builtin_amdgcn_mfma_f32_16x16x32_bf16(a1,b1v,acc,0,0,0);
        #pragma unroll
        for(int i=0;i<4;i++) tp_s[swzo(rb+i,col)]=(short)f2bu(fmaxf(acc[i],0.f));
      }
    }
  }
  __syncthreads();

  #pragma unroll
  for (int j=0;j<2;j++){
    const int rt=w+(j<<3);
    if (rt < LT){
      s16x8 a0=ldfrag(tp_s, rt<<4, lane, 0);
      s16x8 a1=ldfrag(tp_s, rt<<4, lane, 1);
      const int rb=(rt<<4)+(lhi<<2);
      f32x4 to[4];
      #pragma unroll
      for (int dt=0;dt<4;dt++){
        const int col=(dt<<4)+l15;
        const short* wb = W2_t + (col<<6)+(lhi<<3);
        s16x8 b0=*(const s16x8*)wb, b1v=*(const s16x8*)(wb+32);
        float bias=b2[col];
        f32x4 acc={bias,bias,bias,bias};
        acc=__builtin_amdgcn_mfma_f32_16x16x32_bf16(a0,b0,acc,0,0,0);
        acc=__builtin_amdgcn_mfma_f32_16x16x32_bf16(a1,b1v,acc,0,0,0);
        acc += h1[j][dt];
        to[dt]=acc;
      }
      f32x4 mu, rsq;
      #pragma unroll
      for(int i=0;i<4;i++){
        float sv = to[0][i]+to[1][i]+to[2][i]+to[3][i];
        sv += __shfl_xor(sv,1); sv+=__shfl_xor(sv,2); sv+=__shfl_xor(sv,4); sv+=__shfl_xor(sv,8);
        mu[i]=sv*(1.f/64.f);
      }
      #pragma unroll
      for(int i=0;i<4;i++){
        float sv=0.f;
        #pragma unroll
        for(int dt=0;dt<4;dt++){ float c=to[dt][i]-mu[i]; sv=fmaf(c,c,sv); }
        sv += __shfl_xor(sv,1); sv+=__shfl_xor(sv,2); sv+=__shfl_xor(sv,4); sv+=__shfl_xor(sv,8);
        rsq[i]=1.f/sqrtf(sv*(1.f/64.f)+1e-5f);
      }
      #pragma unroll
      for(int dt=0;dt<4;dt++){
        const int col=(dt<<4)+l15;
        float g=ln2g[col], bb=ln2b[col];
        #pragma unroll
        for(int i=0;i<4;i++){
          const int row=rb+i;
          if (row < len){
            float tv=(to[dt][i]-mu[i])*rsq[i]*g+bb;
            float tin = fmaf(valr[row],proj_w[col], fmaf(obsr[row],proj_w[64+col], proj_b[col]))
                      + pe_g[(((size_t)b<<8)+row)*64+col];
            float ob = obsr[row];
            xtat[((size_t)bn<<14)+(row<<6)+col] = f2bu(ob*tin + (1.f-ob)*tv);
          }
        }
      }
    }
  }
}

// ---------------------------------------------------------------------------
// K35: precompute xt-dependent gate terms + fold u1+rs*u2.
//   Xall[b,t,g,d,n] (bf16) = (xt@Wg_x + (A@xt)@Wg_ax)[n,d] + u1g[d] + rs[n]*u2g[d]
// ---------------------------------------------------------------------------
__global__ void k35_xg(const unsigned short* __restrict__ xtat, const short* __restrict__ Abf,
                       const short* __restrict__ Wg_t, const int* __restrict__ lengths,
                       const float* __restrict__ U, const float* __restrict__ rs_g,
                       unsigned short* __restrict__ Xall)
{
  const int bt = blockIdx.x, b = bt>>8, t = bt&255;
  int len = lengths[b]; if (len<1) len=1;
  if (t >= len) return;
  const int tid = threadIdx.x, w = tid>>6, lane = tid&63;
  const int l15 = lane&15, lhi = lane>>4;
  __shared__ short xt_rm[4096], xt_tp[4096], axt_rm[4096];

  // load xt[n][d] = xtat[b,n,t,:]
  #pragma unroll
  for (int q=0;q<2;q++){
    int e = tid + (q<<8);
    int nn = e>>3, c0 = (e&7)<<3;
    s16x8 v = *(const s16x8*)((const short*)xtat + (((size_t)(b*64+nn)*256 + t)<<6) + c0);
    *(s16x8*)(xt_rm + swzo(nn,c0)) = v;
    #pragma unroll
    for (int jj=0;jj<8;jj++) xt_tp[swzo(c0+jj, nn)] = v[jj];
  }
  __syncthreads();

  // Axt = A @ xt ; wave w computes col-tile w (all 4 row tiles)
  {
    s16x8 bx[2];
    #pragma unroll
    for (int kk=0;kk<2;kk++) bx[kk]=ldfrag(xt_tp, w<<4, lane, kk);
    #pragma unroll
    for (int rt=0;rt<4;rt++){
      f32x4 acc={0.f,0.f,0.f,0.f};
      #pragma unroll
      for (int kk=0;kk<2;kk++){
        s16x8 af = *(const s16x8*)(Abf + ((rt<<4)+l15)*64 + (kk<<5) + (lhi<<3));
        acc=__builtin_amdgcn_mfma_f32_16x16x32_bf16(af,bx[kk],acc,0,0,0);
      }
      const int rb=(rt<<4)+(lhi<<2);
      #pragma unroll
      for(int i=0;i<4;i++) axt_rm[swzo(rb+i,(w<<4)+l15)] = (short)f2bu(acc[i]);
    }
  }
  __syncthreads();

  // Xg = xt@Wg_x + Axt@Wg_ax ; wave w -> out col-tile w for each gate
  s16x8 fx[4][2], fa[4][2];
  #pragma unroll
  for (int rt=0;rt<4;rt++)
    #pragma unroll
    for (int kk=0;kk<2;kk++){
      fx[rt][kk]=ldfrag(xt_rm, rt<<4, lane, kk);
      fa[rt][kk]=ldfrag(axt_rm, rt<<4, lane, kk);
    }
  const int dcol = (w<<4)+l15;
  f32x4 rsv[4];
  #pragma unroll
  for (int rt=0;rt<4;rt++) rsv[rt] = *(const f32x4*)(rs_g + (rt<<4) + (lhi<<2));
  const float* Ub = U + (size_t)bt*384;
  #pragma unroll
  for (int g=0; g<3; g++){
    s16x8 wbx[2], wba[2];
    #pragma unroll
    for (int kk=0;kk<2;kk++){
      wbx[kk] = *(const s16x8*)(Wg_t + (((g<<1)  )*64 + dcol)*64 + (kk<<5)+(lhi<<3));
      wba[kk] = *(const s16x8*)(Wg_t + (((g<<1)+1)*64 + dcol)*64 + (kk<<5)+(lhi<<3));
    }
    float u1 = Ub[(g<<7) + dcol];
    float u2 = Ub[(g<<7) + 64 + dcol];
    #pragma unroll
    for (int rt=0;rt<4;rt++){
      f32x4 acc={u1,u1,u1,u1};
      #pragma unroll
      for (int kk=0;kk<2;kk++){
        acc=__builtin_amdgcn_mfma_f32_16x16x32_bf16(fx[rt][kk],wbx[kk],acc,0,0,0);
        acc=__builtin_amdgcn_mfma_f32_16x16x32_bf16(fa[rt][kk],wba[kk],acc,0,0,0);
      }
      s16x4 pk;
      #pragma unroll
      for(int i=0;i<4;i++) pk[i]=(short)f2bu(acc[i] + rsv[rt][i]*u2);
      *(s16x4*)((short*)Xall + (((size_t)bt*3 + g)*64 + dcol)*64 + (rt<<4)+(lhi<<2)) = pk;
    }
  }
}

// ---------------------------------------------------------------------------
// K4: graph-GRU scan, 2 BATCHES PER BLOCK (16 waves = 2 groups x 8 waves).
//     waves_per_eu max=4 CAPS occupancy at 4 waves/EU => VGPR budget 128
//     (launch_bounds' 2nd arg is only a MIN: R9/R10's allocator targeted
//     8 waves/EU => 64 VGPR => spilled ~44 loop-invariant VGPRs, 4.2x slow;
//     the 100KB LDS block caps the CU at 1 block anyway, so 8 waves/EU
//     could never materialize).
// ---------------------------------------------------------------------------
__attribute__((amdgpu_flat_work_group_size(1024, 1024), amdgpu_waves_per_eu(1, 4)))
__global__ void k4_scan(const unsigned short* __restrict__ Xall,
                        const float* __restrict__ decay, const short* __restrict__ Abf,
                        const short* __restrict__ Wg_h,
                        const int* __restrict__ lengths, float* __restrict__ hT)
{
  const int tid = threadIdx.x;
  const int grp = tid >> 9;               // batch group 0..1
  const int stid = tid & 511;             // tid within group
  const int w = stid>>6, lane = stid&63;
  const int l15 = lane&15, lhi = lane>>4;
  const int pe_ = l15&1;
  const int b = blockIdx.x*2 + grp;
  const int gofs = grp << 13;             // byte offset of group's LDS tile
  // gate partition: n-tile rnt, d-tile pair dp
  const int rnt = w>>1, dp = w&1;
  const int nb_ = (rnt<<4) + (lhi<<2);
  const int d0 = (dp<<5) + l15, d1 = (dp<<5) + 16 + l15;
  // A-mult partition: n-tile pair (tmA0,tmA1), d-tile dnA
  const int tmA0 = (w&1)<<1, tmA1 = tmA0+1;
  const int dnA = w>>1;

  __shared__ short h_rm[2][4096], h_tp[2][4096], ah_rm[2][4096];
  __shared__ short rh_rm[2][4096], rh_tp[2][4096], arh_rm[2][4096];
  __shared__ float dec_s[2][256];

  int lenA = lengths[blockIdx.x*2];   if (lenA<1) lenA=1;
  int lenB = lengths[blockIdx.x*2+1]; if (lenB<1) lenB=1;
  const int len = grp ? lenB : lenA;
  const int lenmax = (lenA>lenB)?lenA:lenB;
  for (int e=stid; e<256; e+=512) dec_s[grp][e] = decay[b*256+e];

  // static A fragments (A-operand rows tmA0/tmA1)
  s16x8 aA[2][2];
  #pragma unroll
  for (int t2=0;t2<2;t2++)
    #pragma unroll
    for (int kk=0;kk<2;kk++)
      aA[t2][kk] = *(const s16x8*)(Abf + (((t2?tmA1:tmA0)<<4) + l15)*64 + (kk<<5) + (lhi<<3));

  // static gate weight B-frags: wf[g][s][kk][e]  (s=0: h slice, s=1: Ah slice)
  s16x8 wf[3][2][2][2];
  #pragma unroll
  for (int g=0;g<3;g++)
    #pragma unroll
    for (int s=0;s<2;s++)
      #pragma unroll
      for (int kk=0;kk<2;kk++)
        #pragma unroll
        for (int e=0;e<2;e++)
          wf[g][s][kk][e] = *(const s16x8*)(Wg_h + (((g*2+s)*64 + (e?d1:d0))<<6) + (kk<<5) + (lhi<<3));

  // ---- precomputed LDS byte offsets (loop-invariant, group offset folded) ----
  int tpo[2];
  #pragma unroll
  for (int e=0;e<2;e++){ int r = e?d1:d0; tpo[e] = gofs + r*128 + (((nb_)*2) ^ ((r&7)<<4)); }
  int rmo[4];
  { int dPr = ((dp<<1) + pe_)*16 + (l15 & ~1);
    #pragma unroll
    for (int i=0;i<4;i++){ int n = nb_+i; rmo[i] = gofs + n*128 + ((dPr*2) ^ ((n&7)<<4)); } }
  int amo[4];
  { int dAr = (dnA<<4) + (l15 & ~1);
    int tb = (pe_? tmA1 : tmA0)<<4;
    #pragma unroll
    for (int i=0;i<4;i++){ int n = tb + (lhi<<2) + i; amo[i] = gofs + n*128 + ((dAr*2) ^ ((n&7)<<4)); } }
  int rdT[2], rdR[2];
  { int r = (dnA<<4)+l15;
    #pragma unroll
    for (int kk=0;kk<2;kk++) rdT[kk] = gofs + r*128 + (((kk<<6) + (lhi<<4)) ^ ((r&7)<<4)); }
  { int r = (rnt<<4)+l15;
    #pragma unroll
    for (int kk=0;kk<2;kk++) rdR[kk] = gofs + r*128 + (((kk<<6) + (lhi<<4)) ^ ((r&7)<<4)); }

  f32x4 hreg[2] = {{0.f,0.f,0.f,0.f},{0.f,0.f,0.f,0.f}};
  f32x4 zz[2];

  const short* Xb = (const short*)Xall;
  s16x4 xzc[2], xrc[2], xcc[2], xzn[2], xrn[2], xcn[2];
  #pragma unroll
  for (int e=0;e<2;e++){ xzc[e]=(s16x4){0,0,0,0}; xrc[e]=xzc[e]; xcc[e]=xzc[e]; }
  {
    const short* base = Xb + ((size_t)(b*256))*12288;
    #pragma unroll
    for (int e=0;e<2;e++){
      int de = e?d1:d0;
      xzc[e] = *(const s16x4*)(base + (0*64 + de)*64 + nb_);
      xrc[e] = *(const s16x4*)(base + (1*64 + de)*64 + nb_);
      xcc[e] = *(const s16x4*)(base + (2*64 + de)*64 + nb_);
    }
  }
  __syncthreads();

  for (int t=0; t<lenmax; t++){
    const bool act = (t < len);
    // decay (skip when this group's batch is done)
    float dc = act ? dec_s[grp][t] : 1.f;
    #pragma unroll
    for (int e=0;e<2;e++)
      #pragma unroll
      for (int i=0;i<4;i++) hreg[e][i] *= dc;

    // prefetch X for t+1 (stays in flight across raw barriers)
    #pragma unroll
    for (int e=0;e<2;e++){ xzn[e]=(s16x4){0,0,0,0}; xrn[e]=xzn[e]; xcn[e]=xzn[e]; }
    if (t+1 < len){
      const short* base = Xb + ((size_t)(b*256 + t+1))*12288;
      #pragma unroll
      for (int e=0;e<2;e++){
        int de = e?d1:d0;
        xzn[e] = *(const s16x4*)(base + (0*64 + de)*64 + nb_);
        xrn[e] = *(const s16x4*)(base + (1*64 + de)*64 + nb_);
        xcn[e] = *(const s16x4*)(base + (2*64 + de)*64 + nb_);
      }
    }

    // ---- P0: stage h (tp: b64 per e; rm: b32 pair via DPP) ----
    #pragma unroll
    for (int e=0;e<2;e++){
      i32x2 v; v[0] = (int)cvtpk(hreg[e][0], hreg[e][1]);
               v[1] = (int)cvtpk(hreg[e][2], hreg[e][3]);
      *(i32x2*)((char*)h_tp + tpo[e]) = v;
    }
    #pragma unroll
    for (int i=0;i<4;i++){
      float v0 = hreg[0][i], v1 = hreg[1][i];
      float n0 = dppx1(v0), n1 = dppx1(v1);
      float lo = pe_ ? n1 : v0;
      float hi = pe_ ? v1 : n0;
      *(unsigned*)((char*)h_rm + rmo[i]) = cvtpk(lo, hi);
    }
    BAR();

    // ---- P1: Ah = A@h -> ah_rm ----
    {
      s16x8 bh0 = *(const s16x8*)((const char*)h_tp + rdT[0]);
      s16x8 bh1 = *(const s16x8*)((const char*)h_tp + rdT[1]);
      f32x4 a0v={0.f,0.f,0.f,0.f}, a1v={0.f,0.f,0.f,0.f};
      a0v = __builtin_amdgcn_mfma_f32_16x16x32_bf16(aA[0][0], bh0, a0v, 0,0,0);
      a0v = __builtin_amdgcn_mfma_f32_16x16x32_bf16(aA[0][1], bh1, a0v, 0,0,0);
      a1v = __builtin_amdgcn_mfma_f32_16x16x32_bf16(aA[1][0], bh0, a1v, 0,0,0);
      a1v = __builtin_amdgcn_mfma_f32_16x16x32_bf16(aA[1][1], bh1, a1v, 0,0,0);
      #pragma unroll
      for (int i=0;i<4;i++){
        float n0 = dppx1(a0v[i]), n1 = dppx1(a1v[i]);
        float lo = pe_ ? n1 : a0v[i];
        float hi = pe_ ? a1v[i] : n0;
        *(unsigned*)((char*)ah_rm + amo[i]) = cvtpk(lo, hi);
      }
    }
    BAR();

    // ---- P2: z,r gates ----
    {
      s16x8 fh0 = *(const s16x8*)((const char*)h_rm  + rdR[0]);
      s16x8 fh1 = *(const s16x8*)((const char*)h_rm  + rdR[1]);
      s16x8 fa0 = *(const s16x8*)((const char*)ah_rm + rdR[0]);
      s16x8 fa1 = *(const s16x8*)((const char*)ah_rm + rdR[1]);
      f32x4 gz[2], gr[2], rh[2];
      #pragma unroll
      for (int e=0;e<2;e++)
        #pragma unroll
        for (int i=0;i<4;i++){ gz[e][i]=bs2f(xzc[e][i]); gr[e][i]=bs2f(xrc[e][i]); }
      #pragma unroll
      for (int e=0;e<2;e++){
        gz[e] = __builtin_amdgcn_mfma_f32_16x16x32_bf16(fh0, wf[0][0][0][e], gz[e], 0,0,0);
        gz[e] = __builtin_amdgcn_mfma_f32_16x16x32_bf16(fh1, wf[0][0][1][e], gz[e], 0,0,0);
        gz[e] = __builtin_amdgcn_mfma_f32_16x16x32_bf16(fa0, wf[0][1][0][e], gz[e], 0,0,0);
        gz[e] = __builtin_amdgcn_mfma_f32_16x16x32_bf16(fa1, wf[0][1][1][e], gz[e], 0,0,0);
        gr[e] = __builtin_amdgcn_mfma_f32_16x16x32_bf16(fh0, wf[1][0][0][e], gr[e], 0,0,0);
        gr[e] = __builtin_amdgcn_mfma_f32_16x16x32_bf16(fh1, wf[1][0][1][e], gr[e], 0,0,0);
        gr[e] = __builtin_amdgcn_mfma_f32_16x16x32_bf16(fa0, wf[1][1][0][e], gr[e], 0,0,0);
        gr[e] = __builtin_amdgcn_mfma_f32_16x16x32_bf16(fa1, wf[1][1][1][e], gr[e], 0,0,0);
      }
      #pragma unroll
      for (int e=0;e<2;e++)
        #pragma unroll
        for (int i=0;i<4;i++){
          float zv = 1.f/(1.f+__expf(-gz[e][i]));
          float rv = 1.f/(1.f+__expf(-gr[e][i]));
          zz[e][i] = zv;
          rh[e][i] = rv * hreg[e][i];
        }
      // stage rh: tp b64 per e + rm b32 pairs via DPP
      #pragma unroll
      for (int e=0;e<2;e++){
        i32x2 v; v[0] = (int)cvtpk(rh[e][0], rh[e][1]);
                 v[1] = (int)cvtpk(rh[e][2], rh[e][3]);
        *(i32x2*)((char*)rh_tp + tpo[e]) = v;
      }
      #pragma unroll
      for (int i=0;i<4;i++){
        float v0 = rh[0][i], v1 = rh[1][i];
        float n0 = dppx1(v0), n1 = dppx1(v1);
        float lo = pe_ ? n1 : v0;
        float hi = pe_ ? v1 : n0;
        *(unsigned*)((char*)rh_rm + rmo[i]) = cvtpk(lo, hi);
      }
    }
    BAR();

    // ---- P3: Arh = A@rh -> arh_rm ----
    {
      s16x8 br0 = *(const s16x8*)((const char*)rh_tp + rdT[0]);
      s16x8 br1 = *(const s16x8*)((const char*)rh_tp + rdT[1]);
      f32x4 a0v={0.f,0.f,0.f,0.f}, a1v={0.f,0.f,0.f,0.f};
      a0v = __builtin_amdgcn_mfma_f32_16x16x32_bf16(aA[0][0], br0, a0v, 0,0,0);
      a0v = __builtin_amdgcn_mfma_f32_16x16x32_bf16(aA[0][1], br1, a0v, 0,0,0);
      a1v = __builtin_amdgcn_mfma_f32_16x16x32_bf16(aA[1][0], br0, a1v, 0,0,0);
      a1v = __builtin_amdgcn_mfma_f32_16x16x32_bf16(aA[1][1], br1, a1v, 0,0,0);
      #pragma unroll
      for (int i=0;i<4;i++){
        float n0 = dppx1(a0v[i]), n1 = dppx1(a1v[i]);
        float lo = pe_ ? n1 : a0v[i];
        float hi = pe_ ? a1v[i] : n0;
        *(unsigned*)((char*)arh_rm + amo[i]) = cvtpk(lo, hi);
      }
    }
    BAR();

    // ---- P4: c gate + h update ----
    {
      s16x8 fr0 = *(const s16x8*)((const char*)rh_rm  + rdR[0]);
      s16x8 fr1 = *(const s16x8*)((const char*)rh_rm  + rdR[1]);
      s16x8 fb0 = *(const s16x8*)((const char*)arh_rm + rdR[0]);
      s16x8 fb1 = *(const s16x8*)((const char*)arh_rm + rdR[1]);
      f32x4 gc[2];
      #pragma unroll
      for (int e=0;e<2;e++)
        #pragma unroll
        for (int i=0;i<4;i++) gc[e][i]=bs2f(xcc[e][i]);
      #pragma unroll
      for (int e=0;e<2;e++){
        gc[e] = __builtin_amdgcn_mfma_f32_16x16x32_bf16(fr0, wf[2][0][0][e], gc[e], 0,0,0);
        gc[e] = __builtin_amdgcn_mfma_f32_16x16x32_bf16(fr1, wf[2][0][1][e], gc[e], 0,0,0);
        gc[e] = __builtin_amdgcn_mfma_f32_16x16x32_bf16(fb0, wf[2][1][0][e], gc[e], 0,0,0);
        gc[e] = __builtin_amdgcn_mfma_f32_16x16x32_bf16(fb1, wf[2][1][1][e], gc[e], 0,0,0);
      }
      if (act){
        #pragma unroll
        for (int e=0;e<2;e++)
          #pragma unroll
          for (int i=0;i<4;i++){
            float cv = 1.f - 2.f/(__expf(2.f*gc[e][i])+1.f);   // tanh
            hreg[e][i] = fmaf(zz[e][i], hreg[e][i]-cv, cv);
          }
      }
    }

    // rotate prefetch
    #pragma unroll
    for (int e=0;e<2;e++){ xzc[e]=xzn[e]; xrc[e]=xrn[e]; xcc[e]=xcn[e]; }
  }

  // suffix decay for t in [len,256)
  float sp = 1.f;
  for (int t=len; t<256; t++) sp *= dec_s[grp][t];
  #pragma unroll
  for (int e=0;e<2;e++)
    #pragma unroll
    for (int i=0;i<4;i++)
      hT[(((size_t)b<<6) + nb_ + i)*64 + (e?d1:d0)] = hreg[e][i]*sp;
}

// ---------------------------------------------------------------------------
// K5: classifier head
// ---------------------------------------------------------------------------
__global__ void k5_head(const float* __restrict__ hT, const float* __restrict__ Wfin,
                        const float* __restrict__ bfin,
                        const float* __restrict__ stat, const float* __restrict__ We,
                        const float* __restrict__ be,
                        const float* __restrict__ Wc1, const float* __restrict__ bc1,
                        const float* __restrict__ Wc2, const float* __restrict__ bc2,
                        float* __restrict__ out)
{
  const int b = blockIdx.x, tid = threadIdx.x;
  __shared__ float cat[128];
  __shared__ float hcl[200];
  if (tid < 64){
    const float* hr = hT + (((size_t)b<<6)+tid)*64;
    float a = bfin[0];
    #pragma unroll
    for (int d=0;d<64;d++) a = fmaf(hr[d], Wfin[d], a);
    cat[tid]=a;
  } else if (tid < 128){
    int nn = tid-64;
    float a = be[nn];
    #pragma unroll
    for (int k=0;k<9;k++) a = fmaf(stat[b*9+k], We[k*64+nn], a);
    cat[tid]=a;
  }
  __syncthreads();
  if (tid < 200){
    float a = bc1[tid];
    for (int k=0;k<128;k++) a = fmaf(cat[k], Wc1[k*200+tid], a);
    hcl[tid] = fmaxf(a, 0.f);
  }
  __syncthreads();
  if (tid < 2){
    float a = bc2[tid];
    for (int k=0;k<200;k++) a = fmaf(hcl[k], Wc2[k*2+tid], a);
    out[b*2+tid] = a;
  }
}

// ---------------------------------------------------------------------------
extern "C" void kernel_launch(void* const* d_in, const int* in_sizes, int n_in,
                              void* d_out, int out_size, void* d_ws, size_t ws_size,
                              hipStream_t stream)
{
  const float* x       = (const float*)d_in[0];
  const float* nufft   = (const float*)d_in[1];
  const float* delta_t = (const float*)d_in[2];
  const float* stat    = (const float*)d_in[3];
  const int*   lengths = (const int*)  d_in[4];
  const float* proj_w  = (const float*)d_in[5];
  const float* proj_b  = (const float*)d_in[6];
  const float* Wqkv    = (const float*)d_in[7];
  const float* bqkv    = (const float*)d_in[8];
  const float* Wo      = (const float*)d_in[9];
  const float* bo      = (const float*)d_in[10];
  const float* ln1g    = (const float*)d_in[11];
  const float* ln1b    = (const float*)d_in[12];
  const float* W1      = (const float*)d_in[13];
  const float* b1      = (const float*)d_in[14];
  const float* W2      = (const float*)d_in[15];
  const float* b2      = (const float*)d_in[16];
  const float* ln2g    = (const float*)d_in[17];
  const float* ln2b    = (const float*)d_in[18];
  const float* WQf     = (const float*)d_in[19];
  const float* WKf     = (const float*)d_in[20];
  const float* Wz      = (const float*)d_in[21];
  const float* bz      = (const float*)d_in[22];
  const float* Wr      = (const float*)d_in[23];
  const float* br      = (const float*)d_in[24];
  const float* Wc      = (const float*)d_in[25];
  const float* bc      = (const float*)d_in[26];
  const float* Wfin    = (const float*)d_in[27];
  const float* bfin    = (const float*)d_in[28];
  const float* We      = (const float*)d_in[29];
  const float* be      = (const float*)d_in[30];
  const float* Wc1     = (const float*)d_in[31];
  const float* bc1     = (const float*)d_in[32];
  const float* Wc2     = (const float*)d_in[33];
  const float* bc2     = (const float*)d_in[34];
  float* out = (float*)d_out;

  char* ws = (char*)d_ws;
  size_t o = 0;
  float* pe    = (float*)(ws+o); o += (size_t)4096*64*4;
  float* U     = (float*)(ws+o); o += (size_t)4096*384*4;
  float* decay = (float*)(ws+o); o += (size_t)4096*4;
  unsigned short* xtat = (unsigned short*)(ws+o); o += (size_t)1024*256*64*2;
  float* qf    = (float*)(ws+o); o += (size_t)1024*256*4;
  float* kf    = (float*)(ws+o); o += (size_t)1024*256*4;
  float* soft  = (float*)(ws+o); o += (size_t)16*4096*4;
  short* Abf   = (short*)(ws+o); o += (size_t)4096*2;
  float* rs    = (float*)(ws+o); o += (size_t)64*4;
  float* hT    = (float*)(ws+o); o += (size_t)16*64*64*4;
  short* Wqkv_t= (short*)(ws+o); o += (size_t)12288*2;
  short* Wo_t  = (short*)(ws+o); o += (size_t)4096*2;
  short* W1_t  = (short*)(ws+o); o += (size_t)4096*2;
  short* W2_t  = (short*)(ws+o); o += (size_t)4096*2;
  short* Wg_t  = (short*)(ws+o); o += (size_t)24576*2;
  short* Wg_h  = (short*)(ws+o); o += (size_t)24576*2;
  unsigned short* Xall = (unsigned short*)(ws+o); o += (size_t)4096*3*4096*2;  // ~100 MB
  (void)ws_size; (void)in_sizes; (void)n_in; (void)out_size;

  hipLaunchKernelGGL(k0_prep,   dim3(288),  dim3(256), 0, stream,
                     Wqkv, Wo, W1, W2, Wz, Wr, Wc, Wqkv_t, Wo_t, W1_t, W2_t, Wg_t, Wg_h);
  hipLaunchKernelGGL(k1_pe_u,   dim3(1024), dim3(256), 0, stream,
                     x, delta_t, Wz, bz, Wr, br, Wc, bc, pe, U, decay);
  hipLaunchKernelGGL(k2a_qfkf,  dim3(1024), dim3(256), 0, stream,
                     nufft, WQf, WKf, qf, kf);
  hipLaunchKernelGGL(k2b_soft,  dim3(16),   dim3(256), 0, stream, qf, kf, soft);
  hipLaunchKernelGGL(k2c_A,     dim3(1),    dim3(256), 0, stream, soft, Abf, rs);
  hipLaunchKernelGGL(k3_former, dim3(1024), dim3(512), 0, stream,
                     x, pe, proj_w, proj_b, Wqkv_t, bqkv, Wo_t, bo, ln1g, ln1b,
                     W1_t, b1, W2_t, b2, ln2g, ln2b, lengths, xtat);
  hipLaunchKernelGGL(k35_xg,    dim3(4096), dim3(256), 0, stream,
                     xtat, Abf, Wg_t, lengths, U, rs, Xall);
  hipLaunchKernelGGL(k4_scan,   dim3(8),    dim3(1024), 0, stream,
                     Xall, decay, Abf, Wg_h, lengths, hT);
  hipLaunchKernelGGL(k5_head,   dim3(16),   dim3(256), 0, stream,
                     hT, Wfin, bfin, stat, We, be, Wc1, bc1, Wc2, bc2, out);
}

// Round 12
// 860.778 us; speedup vs baseline: 3.3276x; 3.3267x over previous
//
#include <hip/hip_runtime.h>
#include <hip/hip_bf16.h>
#include <cmath>

#define DEV __device__ __forceinline__

typedef short s16x8 __attribute__((ext_vector_type(8)));
typedef short s16x4 __attribute__((ext_vector_type(4)));
typedef float f32x4 __attribute__((ext_vector_type(4)));
typedef int   i32x2 __attribute__((ext_vector_type(2)));

DEV unsigned short f2bu(float x){
  __hip_bfloat16 h = __float2bfloat16(x);
  return *reinterpret_cast<unsigned short*>(&h);
}
DEV float bs2f(unsigned short v){ return __uint_as_float(((unsigned)v)<<16); }
DEV float bs2f(short v){ return bs2f((unsigned short)v); }

DEV unsigned cvtpk(float lo, float hi){
  unsigned r;
  asm("v_cvt_pk_bf16_f32 %0, %1, %2" : "=v"(r) : "v"(lo), "v"(hi));
  return r;
}
DEV float dppx1(float v){   // value from lane^1 (quad_perm 1,0,3,2)
  int r = __builtin_amdgcn_mov_dpp(__float_as_int(v), 0xB1, 0xF, 0xF, true);
  return __int_as_float(r);
}

#define BAR() do { asm volatile("s_waitcnt lgkmcnt(0)" ::: "memory"); \
                   __builtin_amdgcn_s_barrier(); \
                   __builtin_amdgcn_sched_barrier(0); } while(0)

// swizzled [R][64] bf16 tile helpers (row stride 128B, byte ^= (row&7)<<4)
DEV int swzo(int row, int col){
  return (row*128 + ((col*2) ^ ((row&7)<<4))) >> 1;
}
DEV s16x8 ldfrag(const short* tile, int t16, int lane, int kk){
  int row = t16 + (lane & 15);
  int c0  = (kk<<5) + ((lane>>4)<<3);
  int off = (row*128 + ((c0<<1) ^ ((row&7)<<4))) >> 1;
  return *(const s16x8*)(tile + off);
}
// swizzled [64][256] bf16 (V^T) tile: row stride 512B
DEV int swzv(int d, int t){
  return (d*512 + ((t*2) ^ ((d&7)<<4))) >> 1;
}

// ---------------------------------------------------------------------------
// K1: positional encoding pe[b,t,64], gate vectors U[b,t,6,64], decay.
//     4 (b,t) pairs per 256-thread block. Blocks 0..287 additionally perform
//     the weight prep (former k0): Wqkv_t[192][64], Wo_t/W1_t/W2_t[64][64],
//     Wg_t[3][2][64c][64k] (xt/Axt slices), Wg_h[3][2][64c][64k] (h/Ah).
// ---------------------------------------------------------------------------
__global__ void k1_pe_u(const float* __restrict__ x, const float* __restrict__ delta_t,
                        const float* __restrict__ Wz, const float* __restrict__ bz,
                        const float* __restrict__ Wr, const float* __restrict__ br,
                        const float* __restrict__ Wc, const float* __restrict__ bc,
                        const float* __restrict__ Wqkv, const float* __restrict__ Wo,
                        const float* __restrict__ W1, const float* __restrict__ W2,
                        short* __restrict__ Wqkv_t, short* __restrict__ Wo_t,
                        short* __restrict__ W1_t, short* __restrict__ W2_t,
                        short* __restrict__ Wg_t, short* __restrict__ Wg_h,
                        float* __restrict__ pe, float* __restrict__ U, float* __restrict__ decay)
{
  // ---- folded k0 weight prep (blocks 0..287) ----
  if (blockIdx.x < 288){
    int t = blockIdx.x*256 + threadIdx.x;
    if (t < 12288){ int nn=t>>6, k=t&63; Wqkv_t[t]=(short)f2bu(Wqkv[k*192+nn]); }
    else if (t < 16384){ int e=t-12288; int nn=e>>6,k=e&63; Wo_t[e]=(short)f2bu(Wo[k*64+nn]); }
    else if (t < 20480){ int e=t-16384; int nn=e>>6,k=e&63; W1_t[e]=(short)f2bu(W1[k*64+nn]); }
    else if (t < 24576){ int e=t-20480; int nn=e>>6,k=e&63; W2_t[e]=(short)f2bu(W2[k*64+nn]); }
    else if (t < 49152){
      int e=t-24576;
      int g=e>>13, rem=e&8191, s=rem>>12, rem2=rem&4095, c=rem2>>6, k=rem2&63;
      const float* Wg = (g==0)?Wz:((g==1)?Wr:Wc);
      Wg_t[e] = (short)f2bu(Wg[((s?192:0)+k)*64 + c]);
    }
    else if (t < 73728){
      int e=t-49152;
      int g=e>>13, rem=e&8191, s=rem>>12, rem2=rem&4095, c=rem2>>6, k=rem2&63;
      const float* Wg = (g==0)?Wz:((g==1)?Wr:Wc);
      Wg_h[e] = (short)f2bu(Wg[((s?256:64)+k)*64 + c]);
    }
  }

  const int q  = threadIdx.x >> 6;          // sub-block 0..3
  const int d  = threadIdx.x & 63;          // 0..63
  const int bt = blockIdx.x*4 + q;          // b*256 + t
  __shared__ float pes[4][64];
  float tmv = x[(size_t)bt*129 + 128];      // times
  int j = d & 31;
  float ts = exp2f((float)j * (8.0f/31.0f));   // 256^(j/31)
  float st = tmv / ts;
  float v = (d < 32) ? sinf(st) : cosf(st);
  pes[q][d] = v;
  pe[(size_t)bt*64 + d] = v;
  __syncthreads();
  float a0=bz[d], a1=0.f, a2=br[d], a3=0.f, a4=bc[d], a5=0.f;
  for (int k=0;k<64;k++){
    float p = pes[q][k];
    a0 = fmaf(p, Wz[(128+k)*64+d], a0);
    a1 = fmaf(p, Wz[(320+k)*64+d], a1);
    a2 = fmaf(p, Wr[(128+k)*64+d], a2);
    a3 = fmaf(p, Wr[(320+k)*64+d], a3);
    a4 = fmaf(p, Wc[(128+k)*64+d], a4);
    a5 = fmaf(p, Wc[(320+k)*64+d], a5);
  }
  float* u = U + (size_t)bt*384;
  u[d]=a0; u[64+d]=a1; u[128+d]=a2; u[192+d]=a3; u[256+d]=a4; u[320+d]=a5;
  if (d==0) decay[bt] = expf(-fmaxf(delta_t[bt], 0.f));
}

// ---------------------------------------------------------------------------
// K2a: qf = xf@WQ_f, kf = xf@WK_f   (xf[b,n,t] = nufft[b,1,t,n])
// ---------------------------------------------------------------------------
__global__ void k2a_qfkf(const float* __restrict__ nufft, const float* __restrict__ WQf,
                         const float* __restrict__ WKf, float* __restrict__ qf, float* __restrict__ kf)
{
  const int bn = blockIdx.x, b = bn>>6, n = bn&63;
  const int u = threadIdx.x;  // 0..255
  __shared__ float xs[256];
  xs[u] = nufft[ ((((size_t)b*2)+1)*256 + u)*64 + n ];
  __syncthreads();
  float aq=0.f, ak=0.f;
  for (int t=0;t<256;t++){
    float xv = xs[t];
    aq = fmaf(xv, WQf[t*256+u], aq);
    ak = fmaf(xv, WKf[t*256+u], ak);
  }
  qf[(size_t)bn*256+u]=aq;
  kf[(size_t)bn*256+u]=ak;
}

// ---------------------------------------------------------------------------
// K2b: per-batch S=relu(qf·kf)/16, row-softmax -> soft[b,64,64]
// ---------------------------------------------------------------------------
__launch_bounds__(256, 1)
__global__ void k2b_soft(const float* __restrict__ qf, const float* __restrict__ kf,
                         float* __restrict__ soft)
{
  const int b = blockIdx.x, tid = threadIdx.x;
  __shared__ float qs[64*257];
  __shared__ float ksh[64*257];
  __shared__ float Ss[64*65];
  const float* qb = qf + ((size_t)b<<14);
  const float* kb = kf + ((size_t)b<<14);
  for (int e=tid; e<16384; e+=256){
    int r=e>>8, c=e&255;
    qs[r*257+c]=qb[e];
    ksh[r*257+c]=kb[e];
  }
  __syncthreads();
  const int n = tid>>2, m0 = (tid&3)<<4;
  float acc[16];
  #pragma unroll
  for (int i=0;i<16;i++) acc[i]=0.f;
  for (int t=0;t<256;t++){
    float qv = qs[n*257+t];
    #pragma unroll
    for (int i=0;i<16;i++) acc[i] = fmaf(qv, ksh[(m0+i)*257+t], acc[i]);
  }
  #pragma unroll
  for (int i=0;i<16;i++) Ss[n*65+m0+i] = fmaxf(acc[i],0.f)*(1.f/16.f);
  __syncthreads();
  if (tid < 64){
    float mx=-1e30f;
    for (int m=0;m<64;m++) mx=fmaxf(mx, Ss[tid*65+m]);
    float s=0.f;
    for (int m=0;m<64;m++) s += expf(Ss[tid*65+m]-mx);
    float inv=1.f/s;
    for (int m=0;m<64;m++) soft[((size_t)b<<12)+(tid<<6)+m] = expf(Ss[tid*65+m]-mx)*inv;
  }
}

// ---------------------------------------------------------------------------
// K2c: A = 0.5(sm+sm^T) with sm = softmax(0.5(A0+A0^T)); A0 = mean_b soft.
// ---------------------------------------------------------------------------
__global__ void k2c_A(const float* __restrict__ soft, short* __restrict__ Abf,
                      float* __restrict__ rs_out)
{
  const int tid = threadIdx.x; // 256
  __shared__ float A0[64*65];
  __shared__ float A1[64*65];
  for (int e=tid; e<4096; e+=256){
    int nn=e>>6, mm=e&63;
    float s=0.f;
    #pragma unroll
    for (int b=0;b<16;b++) s += soft[((size_t)b<<12)+e];
    A0[nn*65+mm] = s*(1.f/16.f);
  }
  __syncthreads();
  for (int e=tid; e<4096; e+=256){
    int nn=e>>6, mm=e&63;
    A1[nn*65+mm] = 0.5f*(A0[nn*65+mm]+A0[mm*65+nn]);
  }
  __syncthreads();
  if (tid < 64){
    float mx=-1e30f;
    for (int m=0;m<64;m++) mx=fmaxf(mx, A1[tid*65+m]);
    float s=0.f;
    for (int m=0;m<64;m++) s += expf(A1[tid*65+m]-mx);
    float inv=1.f/s;
    for (int m=0;m<64;m++) A0[tid*65+m] = expf(A1[tid*65+m]-mx)*inv;
  }
  __syncthreads();
  for (int e=tid; e<4096; e+=256){
    int nn=e>>6, mm=e&63;
    float a = 0.5f*(A0[nn*65+mm]+A0[mm*65+nn]);
    A1[nn*65+mm] = a;
    Abf[e] = (short)f2bu(a);
  }
  __syncthreads();
  if (tid < 64){
    float s=0.f;
    for (int m=0;m<64;m++) s += A1[tid*65+m];
    rs_out[tid]=s;
  }
}

// ---------------------------------------------------------------------------
// K3: per-(b,n) transformer head via MFMA -> x_tat (bf16).
// ---------------------------------------------------------------------------
__launch_bounds__(512, 1)
__global__ void k3_former(const float* __restrict__ x, const float* __restrict__ pe_g,
    const float* __restrict__ proj_w, const float* __restrict__ proj_b,
    const short* __restrict__ Wqkv_t, const float* __restrict__ bqkv,
    const short* __restrict__ Wo_t, const float* __restrict__ bo,
    const float* __restrict__ ln1g, const float* __restrict__ ln1b,
    const short* __restrict__ W1_t, const float* __restrict__ b1,
    const short* __restrict__ W2_t, const float* __restrict__ b2,
    const float* __restrict__ ln2g, const float* __restrict__ ln2b,
    const int* __restrict__ lengths, unsigned short* __restrict__ xtat)
{
  const int bn = blockIdx.x, b = bn>>6, n = bn&63;
  const int tid = threadIdx.x, w = tid>>6, lane = tid&63;
  const int l15 = lane&15, lhi = lane>>4;
  __shared__ short tp_s[16384];
  __shared__ short q_s[16384];
  __shared__ short k_s[16384];
  __shared__ short v_t[16384];
  __shared__ float valr[256], obsr[256];

  int len = lengths[b]; if (len<1) len=1;
  const int LT = (len+15)>>4;
  const int KB = (len+63)>>6;

  if (tid < 256){
    const float* xr = x + ((size_t)b*256+tid)*129;
    valr[tid]=xr[n]; obsr[tid]=xr[64+n];
  }
  for (int e=tid; e<16384; e+=512) v_t[e]=0;
  __syncthreads();

  const int nrows = LT<<4;
  for (int e=tid; e<(nrows<<6); e+=512){
    int t=e>>6, d=e&63;
    float ti = fmaf(valr[t],proj_w[d], fmaf(obsr[t],proj_w[64+d], proj_b[d]))
             + pe_g[(((size_t)b<<8)+t)*64+d];
    tp_s[swzo(t,d)] = (short)f2bu(ti);
  }
  __syncthreads();

  // ---- QKV ----
  #pragma unroll
  for (int j=0;j<2;j++){
    const int rt = w + (j<<3);
    if (rt < LT){
      s16x8 a0 = ldfrag(tp_s, rt<<4, lane, 0);
      s16x8 a1 = ldfrag(tp_s, rt<<4, lane, 1);
      const int rb = (rt<<4) + (lhi<<2);
      #pragma unroll
      for (int nt=0; nt<12; nt++){
        const short* wb = Wqkv_t + (((nt<<4)+l15)<<6) + (lhi<<3);
        s16x8 b0 = *(const s16x8*)wb;
        s16x8 b1v = *(const s16x8*)(wb+32);
        float bias = bqkv[(nt<<4)+l15];
        f32x4 acc = {bias,bias,bias,bias};
        acc = __builtin_amdgcn_mfma_f32_16x16x32_bf16(a0,b0,acc,0,0,0);
        acc = __builtin_amdgcn_mfma_f32_16x16x32_bf16(a1,b1v,acc,0,0,0);
        const int col = ((nt&3)<<4) + l15;
        if (nt<4){
          #pragma unroll
          for(int i=0;i<4;i++) q_s[swzo(rb+i,col)] = (short)f2bu(acc[i]*0.125f);
        } else if (nt<8){
          #pragma unroll
          for(int i=0;i<4;i++) k_s[swzo(rb+i,col)] = (short)f2bu(acc[i]);
        } else {
          #pragma unroll
          for(int i=0;i<4;i++) v_t[swzv(col, rb+i)] = (short)f2bu(acc[i]);
        }
      }
    }
  }
  __syncthreads();

  // ---- attention ----
  f32x4 Oac[2][4];
  float rsum[2][4];
  #pragma unroll
  for(int j=0;j<2;j++)
    #pragma unroll
    for(int dt=0;dt<4;dt++) Oac[j][dt]=(f32x4){0.f,0.f,0.f,0.f};
  #pragma unroll
  for(int j=0;j<2;j++)
    #pragma unroll
    for(int i=0;i<4;i++) rsum[j][i]=0.f;

  for (int kb=0; kb<KB; kb++){
    s16x8 kf[4][2];
    #pragma unroll
    for (int ct=0;ct<4;ct++){
      kf[ct][0]=ldfrag(k_s, (((kb<<2)+ct)<<4), lane, 0);
      kf[ct][1]=ldfrag(k_s, (((kb<<2)+ct)<<4), lane, 1);
    }
    #pragma unroll
    for (int j=0;j<2;j++){
      const int rt=w+(j<<3);
      if (rt < LT){
        s16x8 q0=ldfrag(q_s, rt<<4, lane, 0);
        s16x8 q1=ldfrag(q_s, rt<<4, lane, 1);
        const int rb=(rt<<4)+(lhi<<2);
        #pragma unroll
        for (int ct=0;ct<4;ct++){
          f32x4 s={0.f,0.f,0.f,0.f};
          s=__builtin_amdgcn_mfma_f32_16x16x32_bf16(q0,kf[ct][0],s,0,0,0);
          s=__builtin_amdgcn_mfma_f32_16x16x32_bf16(q1,kf[ct][1],s,0,0,0);
          const int key=(kb<<6)+(ct<<4)+l15;
          #pragma unroll
          for(int i=0;i<4;i++){
            float p = (key<len) ? __expf(s[i]) : 0.f;
            rsum[j][i]+=p;
            tp_s[swzo(rb+i,(ct<<4)+l15)] = (short)f2bu(p);
          }
        }
      }
    }
    __syncthreads();
    s16x8 vf[4][2];
    #pragma unroll
    for (int dt=0;dt<4;dt++){
      const int d=(dt<<4)+l15;
      #pragma unroll
      for (int kk=0;kk<2;kk++){
        const int k0=(kk<<5)+(lhi<<3);
        vf[dt][kk] = *(const s16x8*)(v_t + swzv(d, (kb<<6)+k0));
      }
    }
    #pragma unroll
    for (int j=0;j<2;j++){
      const int rt=w+(j<<3);
      if (rt < LT){
        s16x8 p0=ldfrag(tp_s, rt<<4, lane, 0);
        s16x8 p1=ldfrag(tp_s, rt<<4, lane, 1);
        #pragma unroll
        for (int dt=0;dt<4;dt++){
          Oac[j][dt]=__builtin_amdgcn_mfma_f32_16x16x32_bf16(p0,vf[dt][0],Oac[j][dt],0,0,0);
          Oac[j][dt]=__builtin_amdgcn_mfma_f32_16x16x32_bf16(p1,vf[dt][1],Oac[j][dt],0,0,0);
        }
      }
    }
    __syncthreads();
  }

  float inv[2][4];
  #pragma unroll
  for(int j=0;j<2;j++)
    #pragma unroll
    for(int i=0;i<4;i++){
      float v=rsum[j][i];
      v += __shfl_xor(v,1); v += __shfl_xor(v,2); v += __shfl_xor(v,4); v += __shfl_xor(v,8);
      inv[j][i]=1.f/v;
    }

  #pragma unroll
  for (int j=0;j<2;j++){
    const int rt=w+(j<<3);
    if (rt < LT){
      const int rb=(rt<<4)+(lhi<<2);
      #pragma unroll
      for (int dt=0;dt<4;dt++)
        #pragma unroll
        for (int i=0;i<4;i++)
          q_s[swzo(rb+i,(dt<<4)+l15)] = (short)f2bu(Oac[j][dt][i]*inv[j][i]);
    }
  }
  __syncthreads();

  f32x4 h1[2][4];
  #pragma unroll
  for (int j=0;j<2;j++){
    const int rt=w+(j<<3);
    if (rt < LT){
      s16x8 a0=ldfrag(q_s, rt<<4, lane, 0);
      s16x8 a1=ldfrag(q_s, rt<<4, lane, 1);
      const int rb=(rt<<4)+(lhi<<2);
      #pragma unroll
      for (int dt=0;dt<4;dt++){
        const int col=(dt<<4)+l15;
        const short* wb = Wo_t + (col<<6) + (lhi<<3);
        s16x8 b0=*(const s16x8*)wb, b1v=*(const s16x8*)(wb+32);
        float bias=bo[col];
        f32x4 acc={bias,bias,bias,bias};
        acc=__builtin_amdgcn_mfma_f32_16x16x32_bf16(a0,b0,acc,0,0,0);
        acc=__builtin_amdgcn_mfma_f32_16x16x32_bf16(a1,b1v,acc,0,0,0);
        #pragma unroll
        for(int i=0;i<4;i++){
          const int row=rb+i;
          acc[i]+= fmaf(valr[row],proj_w[col], fmaf(obsr[row],proj_w[64+col], proj_b[col]))
                 + pe_g[(((size_t)b<<8)+row)*64+col];
        }
        h1[j][dt]=acc;
      }
      f32x4 mu, rsq;
      #pragma unroll
      for(int i=0;i<4;i++){
        float sv = h1[j][0][i]+h1[j][1][i]+h1[j][2][i]+h1[j][3][i];
        sv += __shfl_xor(sv,1); sv+=__shfl_xor(sv,2); sv+=__shfl_xor(sv,4); sv+=__shfl_xor(sv,8);
        mu[i]=sv*(1.f/64.f);
      }
      #pragma unroll
      for(int i=0;i<4;i++){
        float sv=0.f;
        #pragma unroll
        for(int dt=0;dt<4;dt++){ float c=h1[j][dt][i]-mu[i]; sv=fmaf(c,c,sv); }
        sv += __shfl_xor(sv,1); sv+=__shfl_xor(sv,2); sv+=__shfl_xor(sv,4); sv+=__shfl_xor(sv,8);
        rsq[i]=1.f/sqrtf(sv*(1.f/64.f)+1e-5f);
      }
      #pragma unroll
      for(int dt=0;dt<4;dt++){
        const int col=(dt<<4)+l15;
        float g=ln1g[col], bb=ln1b[col];
        #pragma unroll
        for(int i=0;i<4;i++){
          float hv=(h1[j][dt][i]-mu[i])*rsq[i]*g+bb;
          h1[j][dt][i]=hv;
          k_s[swzo(rb+i,col)] = (short)f2bu(hv);
        }
      }
    }
  }
  __syncthreads();

  #pragma unroll
  for (int j=0;j<2;j++){
    const int rt=w+(j<<3);
    if (rt < LT){
      s16x8 a0=ldfrag(k_s, rt<<4, lane, 0);
      s16x8 a1=ldfrag(k_s, rt<<4, lane, 1);
      const int rb=(rt<<4)+(lhi<<2);
      #pragma unroll
      for (int dt=0;dt<4;dt++){
        const int col=(dt<<4)+l15;
        const short* wb = W1_t + (col<<6)+(lhi<<3);
        s16x8 b0=*(const s16x8*)wb, b1v=*(const s16x8*)(wb+32);
        float bias=b1[col];
        f32x4 acc={bias,bias,bias,bias};
        acc=__builtin_amdgcn_mfma_f32_16x16x32_bf16(a0,b0,acc,0,0,0);
        acc=__builtin_amdgcn_mfma_f32_16x16x32_bf16(a1,b1v,acc,0,0,0);
        #pragma unroll
        for(int i=0;i<4;i++) tp_s[swzo(rb+i,col)]=(short)f2bu(fmaxf(acc[i],0.f));
      }
    }
  }
  __syncthreads();

  #pragma unroll
  for (int j=0;j<2;j++){
    const int rt=w+(j<<3);
    if (rt < LT){
      s16x8 a0=ldfrag(tp_s, rt<<4, lane, 0);
      s16x8 a1=ldfrag(tp_s, rt<<4, lane, 1);
      const int rb=(rt<<4)+(lhi<<2);
      f32x4 to[4];
      #pragma unroll
      for (int dt=0;dt<4;dt++){
        const int col=(dt<<4)+l15;
        const short* wb = W2_t + (col<<6)+(lhi<<3);
        s16x8 b0=*(const s16x8*)wb, b1v=*(const s16x8*)(wb+32);
        float bias=b2[col];
        f32x4 acc={bias,bias,bias,bias};
        acc=__builtin_amdgcn_mfma_f32_16x16x32_bf16(a0,b0,acc,0,0,0);
        acc=__builtin_amdgcn_mfma_f32_16x16x32_bf16(a1,b1v,acc,0,0,0);
        acc += h1[j][dt];
        to[dt]=acc;
      }
      f32x4 mu, rsq;
      #pragma unroll
      for(int i=0;i<4;i++){
        float sv = to[0][i]+to[1][i]+to[2][i]+to[3][i];
        sv += __shfl_xor(sv,1); sv+=__shfl_xor(sv,2); sv+=__shfl_xor(sv,4); sv+=__shfl_xor(sv,8);
        mu[i]=sv*(1.f/64.f);
      }
      #pragma unroll
      for(int i=0;i<4;i++){
        float sv=0.f;
        #pragma unroll
        for(int dt=0;dt<4;dt++){ float c=to[dt][i]-mu[i]; sv=fmaf(c,c,sv); }
        sv += __shfl_xor(sv,1); sv+=__shfl_xor(sv,2); sv+=__shfl_xor(sv,4); sv+=__shfl_xor(sv,8);
        rsq[i]=1.f/sqrtf(sv*(1.f/64.f)+1e-5f);
      }
      #pragma unroll
      for(int dt=0;dt<4;dt++){
        const int col=(dt<<4)+l15;
        float g=ln2g[col], bb=ln2b[col];
        #pragma unroll
        for(int i=0;i<4;i++){
          const int row=rb+i;
          if (row < len){
            float tv=(to[dt][i]-mu[i])*rsq[i]*g+bb;
            float tin = fmaf(valr[row],proj_w[col], fmaf(obsr[row],proj_w[64+col], proj_b[col]))
                      + pe_g[(((size_t)b<<8)+row)*64+col];
            float ob = obsr[row];
            xtat[((size_t)bn<<14)+(row<<6)+col] = f2bu(ob*tin + (1.f-ob)*tv);
          }
        }
      }
    }
  }
}

// ---------------------------------------------------------------------------
// K35: precompute xt-dependent gate terms + fold u1+rs*u2.
//   Xall[b,t,g,d,n] (bf16) = (xt@Wg_x + (A@xt)@Wg_ax)[n,d] + u1g[d] + rs[n]*u2g[d]
// ---------------------------------------------------------------------------
__global__ void k35_xg(const unsigned short* __restrict__ xtat, const short* __restrict__ Abf,
                       const short* __restrict__ Wg_t, const int* __restrict__ lengths,
                       const float* __restrict__ U, const float* __restrict__ rs_g,
                       unsigned short* __restrict__ Xall)
{
  const int bt = blockIdx.x, b = bt>>8, t = bt&255;
  int len = lengths[b]; if (len<1) len=1;
  if (t >= len) return;
  const int tid = threadIdx.x, w = tid>>6, lane = tid&63;
  const int l15 = lane&15, lhi = lane>>4;
  __shared__ short xt_rm[4096], xt_tp[4096], axt_rm[4096];

  // load xt[n][d] = xtat[b,n,t,:]
  #pragma unroll
  for (int q=0;q<2;q++){
    int e = tid + (q<<8);
    int nn = e>>3, c0 = (e&7)<<3;
    s16x8 v = *(const s16x8*)((const short*)xtat + (((size_t)(b*64+nn)*256 + t)<<6) + c0);
    *(s16x8*)(xt_rm + swzo(nn,c0)) = v;
    #pragma unroll
    for (int jj=0;jj<8;jj++) xt_tp[swzo(c0+jj, nn)] = v[jj];
  }
  __syncthreads();

  // Axt = A @ xt ; wave w computes col-tile w (all 4 row tiles)
  {
    s16x8 bx[2];
    #pragma unroll
    for (int kk=0;kk<2;kk++) bx[kk]=ldfrag(xt_tp, w<<4, lane, kk);
    #pragma unroll
    for (int rt=0;rt<4;rt++){
      f32x4 acc={0.f,0.f,0.f,0.f};
      #pragma unroll
      for (int kk=0;kk<2;kk++){
        s16x8 af = *(const s16x8*)(Abf + ((rt<<4)+l15)*64 + (kk<<5) + (lhi<<3));
        acc=__builtin_amdgcn_mfma_f32_16x16x32_bf16(af,bx[kk],acc,0,0,0);
      }
      const int rb=(rt<<4)+(lhi<<2);
      #pragma unroll
      for(int i=0;i<4;i++) axt_rm[swzo(rb+i,(w<<4)+l15)] = (short)f2bu(acc[i]);
    }
  }
  __syncthreads();

  // Xg = xt@Wg_x + Axt@Wg_ax ; wave w -> out col-tile w for each gate
  s16x8 fx[4][2], fa[4][2];
  #pragma unroll
  for (int rt=0;rt<4;rt++)
    #pragma unroll
    for (int kk=0;kk<2;kk++){
      fx[rt][kk]=ldfrag(xt_rm, rt<<4, lane, kk);
      fa[rt][kk]=ldfrag(axt_rm, rt<<4, lane, kk);
    }
  const int dcol = (w<<4)+l15;
  f32x4 rsv[4];
  #pragma unroll
  for (int rt=0;rt<4;rt++) rsv[rt] = *(const f32x4*)(rs_g + (rt<<4) + (lhi<<2));
  const float* Ub = U + (size_t)bt*384;
  #pragma unroll
  for (int g=0; g<3; g++){
    s16x8 wbx[2], wba[2];
    #pragma unroll
    for (int kk=0;kk<2;kk++){
      wbx[kk] = *(const s16x8*)(Wg_t + (((g<<1)  )*64 + dcol)*64 + (kk<<5)+(lhi<<3));
      wba[kk] = *(const s16x8*)(Wg_t + (((g<<1)+1)*64 + dcol)*64 + (kk<<5)+(lhi<<3));
    }
    float u1 = Ub[(g<<7) + dcol];
    float u2 = Ub[(g<<7) + 64 + dcol];
    #pragma unroll
    for (int rt=0;rt<4;rt++){
      f32x4 acc={u1,u1,u1,u1};
      #pragma unroll
      for (int kk=0;kk<2;kk++){
        acc=__builtin_amdgcn_mfma_f32_16x16x32_bf16(fx[rt][kk],wbx[kk],acc,0,0,0);
        acc=__builtin_amdgcn_mfma_f32_16x16x32_bf16(fa[rt][kk],wba[kk],acc,0,0,0);
      }
      s16x4 pk;
      #pragma unroll
      for(int i=0;i<4;i++) pk[i]=(short)f2bu(acc[i] + rsv[rt][i]*u2);
      *(s16x4*)((short*)Xall + (((size_t)bt*3 + g)*64 + dcol)*64 + (rt<<4)+(lhi<<2)) = pk;
    }
  }
}

// ---------------------------------------------------------------------------
// K4: graph-GRU scan (R8-proven config: 512 thr, 8 waves, 1 batch/block,
//     4 raw barriers/step, DPP+cvt_pk packed staging, X prefetched 1 ahead).
//     612us measured, VGPR 108. 1024-thread grouped variants are dead: the
//     allocator pins 64 VGPR for 1024-thr blocks (launch_bounds min-arg and
//     waves_per_eu(1,4) both fail to bind) -> 44 loop VGPRs spill, 4.2x slow.
// ---------------------------------------------------------------------------
__launch_bounds__(512, 1)
__global__ void k4_scan(const unsigned short* __restrict__ Xall,
                        const float* __restrict__ decay, const short* __restrict__ Abf,
                        const short* __restrict__ Wg_h,
                        const int* __restrict__ lengths, float* __restrict__ hT)
{
  const int b = blockIdx.x, tid = threadIdx.x;
  const int w = tid>>6, lane = tid&63;
  const int l15 = lane&15, lhi = lane>>4;
  const int pe_ = l15&1;
  // gate partition: n-tile rnt, d-tile pair dp
  const int rnt = w>>1, dp = w&1;
  const int nb_ = (rnt<<4) + (lhi<<2);
  const int d0 = (dp<<5) + l15, d1 = (dp<<5) + 16 + l15;
  // A-mult partition: n-tile pair (tmA0,tmA1), d-tile dnA
  const int tmA0 = (w&1)<<1, tmA1 = tmA0+1;
  const int dnA = w>>1;

  __shared__ short h_rm[4096], h_tp[4096], ah_rm[4096];
  __shared__ short rh_rm[4096], rh_tp[4096], arh_rm[4096];
  __shared__ float dec_s[256];

  int len = lengths[b]; if (len<1) len=1;
  for (int e=tid; e<256; e+=512) dec_s[e] = decay[b*256+e];

  // static A fragments (A-operand rows tmA0/tmA1)
  s16x8 aA[2][2];
  #pragma unroll
  for (int t2=0;t2<2;t2++)
    #pragma unroll
    for (int kk=0;kk<2;kk++)
      aA[t2][kk] = *(const s16x8*)(Abf + (((t2?tmA1:tmA0)<<4) + l15)*64 + (kk<<5) + (lhi<<3));

  // static gate weight B-frags: wf[g][s][kk][e]  (s=0: h slice, s=1: Ah slice)
  s16x8 wf[3][2][2][2];
  #pragma unroll
  for (int g=0;g<3;g++)
    #pragma unroll
    for (int s=0;s<2;s++)
      #pragma unroll
      for (int kk=0;kk<2;kk++)
        #pragma unroll
        for (int e=0;e<2;e++)
          wf[g][s][kk][e] = *(const s16x8*)(Wg_h + (((g*2+s)*64 + (e?d1:d0))<<6) + (kk<<5) + (lhi<<3));

  // ---- precomputed LDS byte offsets (loop-invariant) ----
  int tpo[2];
  #pragma unroll
  for (int e=0;e<2;e++){ int r = e?d1:d0; tpo[e] = r*128 + (((nb_)*2) ^ ((r&7)<<4)); }
  int rmo[4];
  { int dPr = ((dp<<1) + pe_)*16 + (l15 & ~1);
    #pragma unroll
    for (int i=0;i<4;i++){ int n = nb_+i; rmo[i] = n*128 + ((dPr*2) ^ ((n&7)<<4)); } }
  int amo[4];
  { int dAr = (dnA<<4) + (l15 & ~1);
    int tb = (pe_? tmA1 : tmA0)<<4;
    #pragma unroll
    for (int i=0;i<4;i++){ int n = tb + (lhi<<2) + i; amo[i] = n*128 + ((dAr*2) ^ ((n&7)<<4)); } }
  int rdT[2], rdR[2];
  { int r = (dnA<<4)+l15;
    #pragma unroll
    for (int kk=0;kk<2;kk++) rdT[kk] = r*128 + (((kk<<6) + (lhi<<4)) ^ ((r&7)<<4)); }
  { int r = (rnt<<4)+l15;
    #pragma unroll
    for (int kk=0;kk<2;kk++) rdR[kk] = r*128 + (((kk<<6) + (lhi<<4)) ^ ((r&7)<<4)); }

  f32x4 hreg[2] = {{0.f,0.f,0.f,0.f},{0.f,0.f,0.f,0.f}};
  f32x4 zz[2];

  const short* Xb = (const short*)Xall;
  s16x4 xzc[2], xrc[2], xcc[2], xzn[2], xrn[2], xcn[2];
  #pragma unroll
  for (int e=0;e<2;e++){ xzc[e]=(s16x4){0,0,0,0}; xrc[e]=xzc[e]; xcc[e]=xzc[e]; }
  {
    const short* base = Xb + ((size_t)(b*256))*12288;
    #pragma unroll
    for (int e=0;e<2;e++){
      int de = e?d1:d0;
      xzc[e] = *(const s16x4*)(base + (0*64 + de)*64 + nb_);
      xrc[e] = *(const s16x4*)(base + (1*64 + de)*64 + nb_);
      xcc[e] = *(const s16x4*)(base + (2*64 + de)*64 + nb_);
    }
  }
  __syncthreads();

  for (int t=0; t<len; t++){
    // decay
    float dc = dec_s[t];
    #pragma unroll
    for (int e=0;e<2;e++)
      #pragma unroll
      for (int i=0;i<4;i++) hreg[e][i] *= dc;

    // prefetch X for t+1 (stays in flight across raw barriers)
    #pragma unroll
    for (int e=0;e<2;e++){ xzn[e]=(s16x4){0,0,0,0}; xrn[e]=xzn[e]; xcn[e]=xzn[e]; }
    if (t+1 < len){
      const short* base = Xb + ((size_t)(b*256 + t+1))*12288;
      #pragma unroll
      for (int e=0;e<2;e++){
        int de = e?d1:d0;
        xzn[e] = *(const s16x4*)(base + (0*64 + de)*64 + nb_);
        xrn[e] = *(const s16x4*)(base + (1*64 + de)*64 + nb_);
        xcn[e] = *(const s16x4*)(base + (2*64 + de)*64 + nb_);
      }
    }

    // ---- P0: stage h (tp: b64 per e; rm: b32 pair via DPP) ----
    #pragma unroll
    for (int e=0;e<2;e++){
      i32x2 v; v[0] = (int)cvtpk(hreg[e][0], hreg[e][1]);
               v[1] = (int)cvtpk(hreg[e][2], hreg[e][3]);
      *(i32x2*)((char*)h_tp + tpo[e]) = v;
    }
    #pragma unroll
    for (int i=0;i<4;i++){
      float v0 = hreg[0][i], v1 = hreg[1][i];
      float n0 = dppx1(v0), n1 = dppx1(v1);
      float lo = pe_ ? n1 : v0;
      float hi = pe_ ? v1 : n0;
      *(unsigned*)((char*)h_rm + rmo[i]) = cvtpk(lo, hi);
    }
    BAR();

    // ---- P1: Ah = A@h -> ah_rm ----
    {
      s16x8 bh0 = *(const s16x8*)((const char*)h_tp + rdT[0]);
      s16x8 bh1 = *(const s16x8*)((const char*)h_tp + rdT[1]);
      f32x4 a0v={0.f,0.f,0.f,0.f}, a1v={0.f,0.f,0.f,0.f};
      a0v = __builtin_amdgcn_mfma_f32_16x16x32_bf16(aA[0][0], bh0, a0v, 0,0,0);
      a0v = __builtin_amdgcn_mfma_f32_16x16x32_bf16(aA[0][1], bh1, a0v, 0,0,0);
      a1v = __builtin_amdgcn_mfma_f32_16x16x32_bf16(aA[1][0], bh0, a1v, 0,0,0);
      a1v = __builtin_amdgcn_mfma_f32_16x16x32_bf16(aA[1][1], bh1, a1v, 0,0,0);
      #pragma unroll
      for (int i=0;i<4;i++){
        float n0 = dppx1(a0v[i]), n1 = dppx1(a1v[i]);
        float lo = pe_ ? n1 : a0v[i];
        float hi = pe_ ? a1v[i] : n0;
        *(unsigned*)((char*)ah_rm + amo[i]) = cvtpk(lo, hi);
      }
    }
    BAR();

    // ---- P2: z,r gates ----
    {
      s16x8 fh0 = *(const s16x8*)((const char*)h_rm  + rdR[0]);
      s16x8 fh1 = *(const s16x8*)((const char*)h_rm  + rdR[1]);
      s16x8 fa0 = *(const s16x8*)((const char*)ah_rm + rdR[0]);
      s16x8 fa1 = *(const s16x8*)((const char*)ah_rm + rdR[1]);
      f32x4 gz[2], gr[2], rh[2];
      #pragma unroll
      for (int e=0;e<2;e++)
        #pragma unroll
        for (int i=0;i<4;i++){ gz[e][i]=bs2f(xzc[e][i]); gr[e][i]=bs2f(xrc[e][i]); }
      #pragma unroll
      for (int e=0;e<2;e++){
        gz[e] = __builtin_amdgcn_mfma_f32_16x16x32_bf16(fh0, wf[0][0][0][e], gz[e], 0,0,0);
        gz[e] = __builtin_amdgcn_mfma_f32_16x16x32_bf16(fh1, wf[0][0][1][e], gz[e], 0,0,0);
        gz[e] = __builtin_amdgcn_mfma_f32_16x16x32_bf16(fa0, wf[0][1][0][e], gz[e], 0,0,0);
        gz[e] = __builtin_amdgcn_mfma_f32_16x16x32_bf16(fa1, wf[0][1][1][e], gz[e], 0,0,0);
        gr[e] = __builtin_amdgcn_mfma_f32_16x16x32_bf16(fh0, wf[1][0][0][e], gr[e], 0,0,0);
        gr[e] = __builtin_amdgcn_mfma_f32_16x16x32_bf16(fh1, wf[1][0][1][e], gr[e], 0,0,0);
        gr[e] = __builtin_amdgcn_mfma_f32_16x16x32_bf16(fa0, wf[1][1][0][e], gr[e], 0,0,0);
        gr[e] = __builtin_amdgcn_mfma_f32_16x16x32_bf16(fa1, wf[1][1][1][e], gr[e], 0,0,0);
      }
      #pragma unroll
      for (int e=0;e<2;e++)
        #pragma unroll
        for (int i=0;i<4;i++){
          float zv = 1.f/(1.f+__expf(-gz[e][i]));
          float rv = 1.f/(1.f+__expf(-gr[e][i]));
          zz[e][i] = zv;
          rh[e][i] = rv * hreg[e][i];
        }
      // stage rh: tp b64 per e + rm b32 pairs via DPP
      #pragma unroll
      for (int e=0;e<2;e++){
        i32x2 v; v[0] = (int)cvtpk(rh[e][0], rh[e][1]);
                 v[1] = (int)cvtpk(rh[e][2], rh[e][3]);
        *(i32x2*)((char*)rh_tp + tpo[e]) = v;
      }
      #pragma unroll
      for (int i=0;i<4;i++){
        float v0 = rh[0][i], v1 = rh[1][i];
        float n0 = dppx1(v0), n1 = dppx1(v1);
        float lo = pe_ ? n1 : v0;
        float hi = pe_ ? v1 : n0;
        *(unsigned*)((char*)rh_rm + rmo[i]) = cvtpk(lo, hi);
      }
    }
    BAR();

    // ---- P3: Arh = A@rh -> arh_rm ----
    {
      s16x8 br0 = *(const s16x8*)((const char*)rh_tp + rdT[0]);
      s16x8 br1 = *(const s16x8*)((const char*)rh_tp + rdT[1]);
      f32x4 a0v={0.f,0.f,0.f,0.f}, a1v={0.f,0.f,0.f,0.f};
      a0v = __builtin_amdgcn_mfma_f32_16x16x32_bf16(aA[0][0], br0, a0v, 0,0,0);
      a0v = __builtin_amdgcn_mfma_f32_16x16x32_bf16(aA[0][1], br1, a0v, 0,0,0);
      a1v = __builtin_amdgcn_mfma_f32_16x16x32_bf16(aA[1][0], br0, a1v, 0,0,0);
      a1v = __builtin_amdgcn_mfma_f32_16x16x32_bf16(aA[1][1], br1, a1v, 0,0,0);
      #pragma unroll
      for (int i=0;i<4;i++){
        float n0 = dppx1(a0v[i]), n1 = dppx1(a1v[i]);
        float lo = pe_ ? n1 : a0v[i];
        float hi = pe_ ? a1v[i] : n0;
        *(unsigned*)((char*)arh_rm + amo[i]) = cvtpk(lo, hi);
      }
    }
    BAR();

    // ---- P4: c gate + h update ----
    {
      s16x8 fr0 = *(const s16x8*)((const char*)rh_rm  + rdR[0]);
      s16x8 fr1 = *(const s16x8*)((const char*)rh_rm  + rdR[1]);
      s16x8 fb0 = *(const s16x8*)((const char*)arh_rm + rdR[0]);
      s16x8 fb1 = *(const s16x8*)((const char*)arh_rm + rdR[1]);
      f32x4 gc[2];
      #pragma unroll
      for (int e=0;e<2;e++)
        #pragma unroll
        for (int i=0;i<4;i++) gc[e][i]=bs2f(xcc[e][i]);
      #pragma unroll
      for (int e=0;e<2;e++){
        gc[e] = __builtin_amdgcn_mfma_f32_16x16x32_bf16(fr0, wf[2][0][0][e], gc[e], 0,0,0);
        gc[e] = __builtin_amdgcn_mfma_f32_16x16x32_bf16(fr1, wf[2][0][1][e], gc[e], 0,0,0);
        gc[e] = __builtin_amdgcn_mfma_f32_16x16x32_bf16(fb0, wf[2][1][0][e], gc[e], 0,0,0);
        gc[e] = __builtin_amdgcn_mfma_f32_16x16x32_bf16(fb1, wf[2][1][1][e], gc[e], 0,0,0);
      }
      #pragma unroll
      for (int e=0;e<2;e++)
        #pragma unroll
        for (int i=0;i<4;i++){
          float cv = 1.f - 2.f/(__expf(2.f*gc[e][i])+1.f);   // tanh
          hreg[e][i] = fmaf(zz[e][i], hreg[e][i]-cv, cv);
        }
    }

    // rotate prefetch
    #pragma unroll
    for (int e=0;e<2;e++){ xzc[e]=xzn[e]; xrc[e]=xrn[e]; xcc[e]=xcn[e]; }
  }

  // suffix decay for t in [len,256)
  float sp = 1.f;
  for (int t=len; t<256; t++) sp *= dec_s[t];
  #pragma unroll
  for (int e=0;e<2;e++)
    #pragma unroll
    for (int i=0;i<4;i++)
      hT[(((size_t)b<<6) + nb_ + i)*64 + (e?d1:d0)] = hreg[e][i]*sp;
}

// ---------------------------------------------------------------------------
// K5: classifier head
// ---------------------------------------------------------------------------
__global__ void k5_head(const float* __restrict__ hT, const float* __restrict__ Wfin,
                        const float* __restrict__ bfin,
                        const float* __restrict__ stat, const float* __restrict__ We,
                        const float* __restrict__ be,
                        const float* __restrict__ Wc1, const float* __restrict__ bc1,
                        const float* __restrict__ Wc2, const float* __restrict__ bc2,
                        float* __restrict__ out)
{
  const int b = blockIdx.x, tid = threadIdx.x;
  __shared__ float cat[128];
  __shared__ float hcl[200];
  if (tid < 64){
    const float* hr = hT + (((size_t)b<<6)+tid)*64;
    float a = bfin[0];
    #pragma unroll
    for (int d=0;d<64;d++) a = fmaf(hr[d], Wfin[d], a);
    cat[tid]=a;
  } else if (tid < 128){
    int nn = tid-64;
    float a = be[nn];
    #pragma unroll
    for (int k=0;k<9;k++) a = fmaf(stat[b*9+k], We[k*64+nn], a);
    cat[tid]=a;
  }
  __syncthreads();
  if (tid < 200){
    float a = bc1[tid];
    for (int k=0;k<128;k++) a = fmaf(cat[k], Wc1[k*200+tid], a);
    hcl[tid] = fmaxf(a, 0.f);
  }
  __syncthreads();
  if (tid < 2){
    float a = bc2[tid];
    for (int k=0;k<200;k++) a = fmaf(hcl[k], Wc2[k*2+tid], a);
    out[b*2+tid] = a;
  }
}

// ---------------------------------------------------------------------------
extern "C" void kernel_launch(void* const* d_in, const int* in_sizes, int n_in,
                              void* d_out, int out_size, void* d_ws, size_t ws_size,
                              hipStream_t stream)
{
  const float* x       = (const float*)d_in[0];
  const float* nufft   = (const float*)d_in[1];
  const float* delta_t = (const float*)d_in[2];
  const float* stat    = (const float*)d_in[3];
  const int*   lengths = (const int*)  d_in[4];
  const float* proj_w  = (const float*)d_in[5];
  const float* proj_b  = (const float*)d_in[6];
  const float* Wqkv    = (const float*)d_in[7];
  const float* bqkv    = (const float*)d_in[8];
  const float* Wo      = (const float*)d_in[9];
  const float* bo      = (const float*)d_in[10];
  const float* ln1g    = (const float*)d_in[11];
  const float* ln1b    = (const float*)d_in[12];
  const float* W1      = (const float*)d_in[13];
  const float* b1      = (const float*)d_in[14];
  const float* W2      = (const float*)d_in[15];
  const float* b2      = (const float*)d_in[16];
  const float* ln2g    = (const float*)d_in[17];
  const float* ln2b    = (const float*)d_in[18];
  const float* WQf     = (const float*)d_in[19];
  const float* WKf     = (const float*)d_in[20];
  const float* Wz      = (const float*)d_in[21];
  const float* bz      = (const float*)d_in[22];
  const float* Wr      = (const float*)d_in[23];
  const float* br      = (const float*)d_in[24];
  const float* Wc      = (const float*)d_in[25];
  const float* bc      = (const float*)d_in[26];
  const float* Wfin    = (const float*)d_in[27];
  const float* bfin    = (const float*)d_in[28];
  const float* We      = (const float*)d_in[29];
  const float* be      = (const float*)d_in[30];
  const float* Wc1     = (const float*)d_in[31];
  const float* bc1     = (const float*)d_in[32];
  const float* Wc2     = (const float*)d_in[33];
  const float* bc2     = (const float*)d_in[34];
  float* out = (float*)d_out;

  char* ws = (char*)d_ws;
  size_t o = 0;
  float* pe    = (float*)(ws+o); o += (size_t)4096*64*4;
  float* U     = (float*)(ws+o); o += (size_t)4096*384*4;
  float* decay = (float*)(ws+o); o += (size_t)4096*4;
  unsigned short* xtat = (unsigned short*)(ws+o); o += (size_t)1024*256*64*2;
  float* qf    = (float*)(ws+o); o += (size_t)1024*256*4;
  float* kf    = (float*)(ws+o); o += (size_t)1024*256*4;
  float* soft  = (float*)(ws+o); o += (size_t)16*4096*4;
  short* Abf   = (short*)(ws+o); o += (size_t)4096*2;
  float* rs    = (float*)(ws+o); o += (size_t)64*4;
  float* hT    = (float*)(ws+o); o += (size_t)16*64*64*4;
  short* Wqkv_t= (short*)(ws+o); o += (size_t)12288*2;
  short* Wo_t  = (short*)(ws+o); o += (size_t)4096*2;
  short* W1_t  = (short*)(ws+o); o += (size_t)4096*2;
  short* W2_t  = (short*)(ws+o); o += (size_t)4096*2;
  short* Wg_t  = (short*)(ws+o); o += (size_t)24576*2;
  short* Wg_h  = (short*)(ws+o); o += (size_t)24576*2;
  unsigned short* Xall = (unsigned short*)(ws+o); o += (size_t)4096*3*4096*2;  // ~100 MB
  (void)ws_size; (void)in_sizes; (void)n_in; (void)out_size;

  hipLaunchKernelGGL(k1_pe_u,   dim3(1024), dim3(256), 0, stream,
                     x, delta_t, Wz, bz, Wr, br, Wc, bc,
                     Wqkv, Wo, W1, W2, Wqkv_t, Wo_t, W1_t, W2_t, Wg_t, Wg_h,
                     pe, U, decay);
  hipLaunchKernelGGL(k2a_qfkf,  dim3(1024), dim3(256), 0, stream,
                     nufft, WQf, WKf, qf, kf);
  hipLaunchKernelGGL(k2b_soft,  dim3(16),   dim3(256), 0, stream, qf, kf, soft);
  hipLaunchKernelGGL(k2c_A,     dim3(1),    dim3(256), 0, stream, soft, Abf, rs);
  hipLaunchKernelGGL(k3_former, dim3(1024), dim3(512), 0, stream,
                     x, pe, proj_w, proj_b, Wqkv_t, bqkv, Wo_t, bo, ln1g, ln1b,
                     W1_t, b1, W2_t, b2, ln2g, ln2b, lengths, xtat);
  hipLaunchKernelGGL(k35_xg,    dim3(4096), dim3(256), 0, stream,
                     xtat, Abf, Wg_t, lengths, U, rs, Xall);
  hipLaunchKernelGGL(k4_scan,   dim3(16),   dim3(512), 0, stream,
                     Xall, decay, Abf, Wg_h, lengths, hT);
  hipLaunchKernelGGL(k5_head,   dim3(16),   dim3(256), 0, stream,
                     hT, Wfin, bfin, stat, We, be, Wc1, bc1, Wc2, bc2, out);
}

// Round 14
// 858.970 us; speedup vs baseline: 3.3346x; 1.0021x over previous
//
#include <hip/hip_runtime.h>
#include <hip/hip_bf16.h>
#include <cmath>

#define DEV __device__ __forceinline__

typedef short s16x8 __attribute__((ext_vector_type(8)));
typedef short s16x4 __attribute__((ext_vector_type(4)));
typedef float f32x4 __attribute__((ext_vector_type(4)));
typedef int   i32x2 __attribute__((ext_vector_type(2)));

DEV unsigned short f2bu(float x){
  __hip_bfloat16 h = __float2bfloat16(x);
  return *reinterpret_cast<unsigned short*>(&h);
}
DEV float bs2f(unsigned short v){ return __uint_as_float(((unsigned)v)<<16); }
DEV float bs2f(short v){ return bs2f((unsigned short)v); }

DEV unsigned cvtpk(float lo, float hi){
  unsigned r;
  asm("v_cvt_pk_bf16_f32 %0, %1, %2" : "=v"(r) : "v"(lo), "v"(hi));
  return r;
}
DEV float dppx1(float v){   // value from lane^1 (quad_perm 1,0,3,2)
  int r = __builtin_amdgcn_mov_dpp(__float_as_int(v), 0xB1, 0xF, 0xF, true);
  return __int_as_float(r);
}

#define BAR() do { asm volatile("s_waitcnt lgkmcnt(0)" ::: "memory"); \
                   __builtin_amdgcn_s_barrier(); \
                   __builtin_amdgcn_sched_barrier(0); } while(0)

// swizzled [R][64] bf16 tile helpers (row stride 128B, byte ^= (row&7)<<4)
DEV int swzo(int row, int col){
  return (row*128 + ((col*2) ^ ((row&7)<<4))) >> 1;
}
DEV s16x8 ldfrag(const short* tile, int t16, int lane, int kk){
  int row = t16 + (lane & 15);
  int c0  = (kk<<5) + ((lane>>4)<<3);
  int off = (row*128 + ((c0<<1) ^ ((row&7)<<4))) >> 1;
  return *(const s16x8*)(tile + off);
}
// swizzled [64][256] bf16 (V^T) tile: row stride 512B
DEV int swzv(int d, int t){
  return (d*512 + ((t*2) ^ ((d&7)<<4))) >> 1;
}

// ---------------------------------------------------------------------------
// K1: positional encoding pe[b,t,64], gate vectors U[b,t,6,64], decay.
//     4 (b,t) pairs per 256-thread block. Blocks 0..287 additionally perform
//     the weight prep (former k0): Wqkv_t[192][64], Wo_t/W1_t/W2_t[64][64],
//     Wg_t[3][2][64c][64k] (xt/Axt slices), Wg_h[3][2][64c][64k] (h/Ah).
// ---------------------------------------------------------------------------
__global__ void k1_pe_u(const float* __restrict__ x, const float* __restrict__ delta_t,
                        const float* __restrict__ Wz, const float* __restrict__ bz,
                        const float* __restrict__ Wr, const float* __restrict__ br,
                        const float* __restrict__ Wc, const float* __restrict__ bc,
                        const float* __restrict__ Wqkv, const float* __restrict__ Wo,
                        const float* __restrict__ W1, const float* __restrict__ W2,
                        short* __restrict__ Wqkv_t, short* __restrict__ Wo_t,
                        short* __restrict__ W1_t, short* __restrict__ W2_t,
                        short* __restrict__ Wg_t, short* __restrict__ Wg_h,
                        float* __restrict__ pe, float* __restrict__ U, float* __restrict__ decay)
{
  // ---- folded k0 weight prep (blocks 0..287) ----
  if (blockIdx.x < 288){
    int t = blockIdx.x*256 + threadIdx.x;
    if (t < 12288){ int nn=t>>6, k=t&63; Wqkv_t[t]=(short)f2bu(Wqkv[k*192+nn]); }
    else if (t < 16384){ int e=t-12288; int nn=e>>6,k=e&63; Wo_t[e]=(short)f2bu(Wo[k*64+nn]); }
    else if (t < 20480){ int e=t-16384; int nn=e>>6,k=e&63; W1_t[e]=(short)f2bu(W1[k*64+nn]); }
    else if (t < 24576){ int e=t-20480; int nn=e>>6,k=e&63; W2_t[e]=(short)f2bu(W2[k*64+nn]); }
    else if (t < 49152){
      int e=t-24576;
      int g=e>>13, rem=e&8191, s=rem>>12, rem2=rem&4095, c=rem2>>6, k=rem2&63;
      const float* Wg = (g==0)?Wz:((g==1)?Wr:Wc);
      Wg_t[e] = (short)f2bu(Wg[((s?192:0)+k)*64 + c]);
    }
    else if (t < 73728){
      int e=t-49152;
      int g=e>>13, rem=e&8191, s=rem>>12, rem2=rem&4095, c=rem2>>6, k=rem2&63;
      const float* Wg = (g==0)?Wz:((g==1)?Wr:Wc);
      Wg_h[e] = (short)f2bu(Wg[((s?256:64)+k)*64 + c]);
    }
  }

  const int q  = threadIdx.x >> 6;          // sub-block 0..3
  const int d  = threadIdx.x & 63;          // 0..63
  const int bt = blockIdx.x*4 + q;          // b*256 + t
  __shared__ float pes[4][64];
  float tmv = x[(size_t)bt*129 + 128];      // times
  int j = d & 31;
  float ts = exp2f((float)j * (8.0f/31.0f));   // 256^(j/31)
  float st = tmv / ts;
  float v = (d < 32) ? sinf(st) : cosf(st);
  pes[q][d] = v;
  pe[(size_t)bt*64 + d] = v;
  __syncthreads();
  float a0=bz[d], a1=0.f, a2=br[d], a3=0.f, a4=bc[d], a5=0.f;
  for (int k=0;k<64;k++){
    float p = pes[q][k];
    a0 = fmaf(p, Wz[(128+k)*64+d], a0);
    a1 = fmaf(p, Wz[(320+k)*64+d], a1);
    a2 = fmaf(p, Wr[(128+k)*64+d], a2);
    a3 = fmaf(p, Wr[(320+k)*64+d], a3);
    a4 = fmaf(p, Wc[(128+k)*64+d], a4);
    a5 = fmaf(p, Wc[(320+k)*64+d], a5);
  }
  float* u = U + (size_t)bt*384;
  u[d]=a0; u[64+d]=a1; u[128+d]=a2; u[192+d]=a3; u[256+d]=a4; u[320+d]=a5;
  if (d==0) decay[bt] = expf(-fmaxf(delta_t[bt], 0.f));
}

// ---------------------------------------------------------------------------
// K2a: qf = xf@WQ_f, kf = xf@WK_f   (xf[b,n,t] = nufft[b,1,t,n])
// ---------------------------------------------------------------------------
__global__ void k2a_qfkf(const float* __restrict__ nufft, const float* __restrict__ WQf,
                         const float* __restrict__ WKf, float* __restrict__ qf, float* __restrict__ kf)
{
  const int bn = blockIdx.x, b = bn>>6, n = bn&63;
  const int u = threadIdx.x;  // 0..255
  __shared__ float xs[256];
  xs[u] = nufft[ ((((size_t)b*2)+1)*256 + u)*64 + n ];
  __syncthreads();
  float aq=0.f, ak=0.f;
  for (int t=0;t<256;t++){
    float xv = xs[t];
    aq = fmaf(xv, WQf[t*256+u], aq);
    ak = fmaf(xv, WKf[t*256+u], ak);
  }
  qf[(size_t)bn*256+u]=aq;
  kf[(size_t)bn*256+u]=ak;
}

// ---------------------------------------------------------------------------
// K2b: per-batch S=relu(qf·kf)/16, row-softmax -> soft[b,64,64]
// ---------------------------------------------------------------------------
__launch_bounds__(256, 1)
__global__ void k2b_soft(const float* __restrict__ qf, const float* __restrict__ kf,
                         float* __restrict__ soft)
{
  const int b = blockIdx.x, tid = threadIdx.x;
  __shared__ float qs[64*257];
  __shared__ float ksh[64*257];
  __shared__ float Ss[64*65];
  const float* qb = qf + ((size_t)b<<14);
  const float* kb = kf + ((size_t)b<<14);
  for (int e=tid; e<16384; e+=256){
    int r=e>>8, c=e&255;
    qs[r*257+c]=qb[e];
    ksh[r*257+c]=kb[e];
  }
  __syncthreads();
  const int n = tid>>2, m0 = (tid&3)<<4;
  float acc[16];
  #pragma unroll
  for (int i=0;i<16;i++) acc[i]=0.f;
  for (int t=0;t<256;t++){
    float qv = qs[n*257+t];
    #pragma unroll
    for (int i=0;i<16;i++) acc[i] = fmaf(qv, ksh[(m0+i)*257+t], acc[i]);
  }
  #pragma unroll
  for (int i=0;i<16;i++) Ss[n*65+m0+i] = fmaxf(acc[i],0.f)*(1.f/16.f);
  __syncthreads();
  if (tid < 64){
    float mx=-1e30f;
    for (int m=0;m<64;m++) mx=fmaxf(mx, Ss[tid*65+m]);
    float s=0.f;
    for (int m=0;m<64;m++) s += expf(Ss[tid*65+m]-mx);
    float inv=1.f/s;
    for (int m=0;m<64;m++) soft[((size_t)b<<12)+(tid<<6)+m] = expf(Ss[tid*65+m]-mx)*inv;
  }
}

// ---------------------------------------------------------------------------
// K2c: A = 0.5(sm+sm^T) with sm = softmax(0.5(A0+A0^T)); A0 = mean_b soft.
// ---------------------------------------------------------------------------
__global__ void k2c_A(const float* __restrict__ soft, short* __restrict__ Abf,
                      float* __restrict__ rs_out)
{
  const int tid = threadIdx.x; // 256
  __shared__ float A0[64*65];
  __shared__ float A1[64*65];
  for (int e=tid; e<4096; e+=256){
    int nn=e>>6, mm=e&63;
    float s=0.f;
    #pragma unroll
    for (int b=0;b<16;b++) s += soft[((size_t)b<<12)+e];
    A0[nn*65+mm] = s*(1.f/16.f);
  }
  __syncthreads();
  for (int e=tid; e<4096; e+=256){
    int nn=e>>6, mm=e&63;
    A1[nn*65+mm] = 0.5f*(A0[nn*65+mm]+A0[mm*65+nn]);
  }
  __syncthreads();
  if (tid < 64){
    float mx=-1e30f;
    for (int m=0;m<64;m++) mx=fmaxf(mx, A1[tid*65+m]);
    float s=0.f;
    for (int m=0;m<64;m++) s += expf(A1[tid*65+m]-mx);
    float inv=1.f/s;
    for (int m=0;m<64;m++) A0[tid*65+m] = expf(A1[tid*65+m]-mx)*inv;
  }
  __syncthreads();
  for (int e=tid; e<4096; e+=256){
    int nn=e>>6, mm=e&63;
    float a = 0.5f*(A0[nn*65+mm]+A0[mm*65+nn]);
    A1[nn*65+mm] = a;
    Abf[e] = (short)f2bu(a);
  }
  __syncthreads();
  if (tid < 64){
    float s=0.f;
    for (int m=0;m<64;m++) s += A1[tid*65+m];
    rs_out[tid]=s;
  }
}

// ---------------------------------------------------------------------------
// K3: per-(b,n) transformer head via MFMA -> x_tat (bf16).
// ---------------------------------------------------------------------------
__launch_bounds__(512, 1)
__global__ void k3_former(const float* __restrict__ x, const float* __restrict__ pe_g,
    const float* __restrict__ proj_w, const float* __restrict__ proj_b,
    const short* __restrict__ Wqkv_t, const float* __restrict__ bqkv,
    const short* __restrict__ Wo_t, const float* __restrict__ bo,
    const float* __restrict__ ln1g, const float* __restrict__ ln1b,
    const short* __restrict__ W1_t, const float* __restrict__ b1,
    const short* __restrict__ W2_t, const float* __restrict__ b2,
    const float* __restrict__ ln2g, const float* __restrict__ ln2b,
    const int* __restrict__ lengths, unsigned short* __restrict__ xtat)
{
  const int bn = blockIdx.x, b = bn>>6, n = bn&63;
  const int tid = threadIdx.x, w = tid>>6, lane = tid&63;
  const int l15 = lane&15, lhi = lane>>4;
  __shared__ short tp_s[16384];
  __shared__ short q_s[16384];
  __shared__ short k_s[16384];
  __shared__ short v_t[16384];
  __shared__ float valr[256], obsr[256];

  int len = lengths[b]; if (len<1) len=1;
  const int LT = (len+15)>>4;
  const int KB = (len+63)>>6;

  if (tid < 256){
    const float* xr = x + ((size_t)b*256+tid)*129;
    valr[tid]=xr[n]; obsr[tid]=xr[64+n];
  }
  for (int e=tid; e<16384; e+=512) v_t[e]=0;
  __syncthreads();

  const int nrows = LT<<4;
  for (int e=tid; e<(nrows<<6); e+=512){
    int t=e>>6, d=e&63;
    float ti = fmaf(valr[t],proj_w[d], fmaf(obsr[t],proj_w[64+d], proj_b[d]))
             + pe_g[(((size_t)b<<8)+t)*64+d];
    tp_s[swzo(t,d)] = (short)f2bu(ti);
  }
  __syncthreads();

  // ---- QKV ----
  #pragma unroll
  for (int j=0;j<2;j++){
    const int rt = w + (j<<3);
    if (rt < LT){
      s16x8 a0 = ldfrag(tp_s, rt<<4, lane, 0);
      s16x8 a1 = ldfrag(tp_s, rt<<4, lane, 1);
      const int rb = (rt<<4) + (lhi<<2);
      #pragma unroll
      for (int nt=0; nt<12; nt++){
        const short* wb = Wqkv_t + (((nt<<4)+l15)<<6) + (lhi<<3);
        s16x8 b0 = *(const s16x8*)wb;
        s16x8 b1v = *(const s16x8*)(wb+32);
        float bias = bqkv[(nt<<4)+l15];
        f32x4 acc = {bias,bias,bias,bias};
        acc = __builtin_amdgcn_mfma_f32_16x16x32_bf16(a0,b0,acc,0,0,0);
        acc = __builtin_amdgcn_mfma_f32_16x16x32_bf16(a1,b1v,acc,0,0,0);
        const int col = ((nt&3)<<4) + l15;
        if (nt<4){
          #pragma unroll
          for(int i=0;i<4;i++) q_s[swzo(rb+i,col)] = (short)f2bu(acc[i]*0.125f);
        } else if (nt<8){
          #pragma unroll
          for(int i=0;i<4;i++) k_s[swzo(rb+i,col)] = (short)f2bu(acc[i]);
        } else {
          #pragma unroll
          for(int i=0;i<4;i++) v_t[swzv(col, rb+i)] = (short)f2bu(acc[i]);
        }
      }
    }
  }
  __syncthreads();

  // ---- attention ----
  f32x4 Oac[2][4];
  float rsum[2][4];
  #pragma unroll
  for(int j=0;j<2;j++)
    #pragma unroll
    for(int dt=0;dt<4;dt++) Oac[j][dt]=(f32x4){0.f,0.f,0.f,0.f};
  #pragma unroll
  for(int j=0;j<2;j++)
    #pragma unroll
    for(int i=0;i<4;i++) rsum[j][i]=0.f;

  for (int kb=0; kb<KB; kb++){
    s16x8 kf[4][2];
    #pragma unroll
    for (int ct=0;ct<4;ct++){
      kf[ct][0]=ldfrag(k_s, (((kb<<2)+ct)<<4), lane, 0);
      kf[ct][1]=ldfrag(k_s, (((kb<<2)+ct)<<4), lane, 1);
    }
    #pragma unroll
    for (int j=0;j<2;j++){
      const int rt=w+(j<<3);
      if (rt < LT){
        s16x8 q0=ldfrag(q_s, rt<<4, lane, 0);
        s16x8 q1=ldfrag(q_s, rt<<4, lane, 1);
        const int rb=(rt<<4)+(lhi<<2);
        #pragma unroll
        for (int ct=0;ct<4;ct++){
          f32x4 s={0.f,0.f,0.f,0.f};
          s=__builtin_amdgcn_mfma_f32_16x16x32_bf16(q0,kf[ct][0],s,0,0,0);
          s=__builtin_amdgcn_mfma_f32_16x16x32_bf16(q1,kf[ct][1],s,0,0,0);
          const int key=(kb<<6)+(ct<<4)+l15;
          #pragma unroll
          for(int i=0;i<4;i++){
            float p = (key<len) ? __expf(s[i]) : 0.f;
            rsum[j][i]+=p;
            tp_s[swzo(rb+i,(ct<<4)+l15)] = (short)f2bu(p);
          }
        }
      }
    }
    __syncthreads();
    s16x8 vf[4][2];
    #pragma unroll
    for (int dt=0;dt<4;dt++){
      const int d=(dt<<4)+l15;
      #pragma unroll
      for (int kk=0;kk<2;kk++){
        const int k0=(kk<<5)+(lhi<<3);
        vf[dt][kk] = *(const s16x8*)(v_t + swzv(d, (kb<<6)+k0));
      }
    }
    #pragma unroll
    for (int j=0;j<2;j++){
      const int rt=w+(j<<3);
      if (rt < LT){
        s16x8 p0=ldfrag(tp_s, rt<<4, lane, 0);
        s16x8 p1=ldfrag(tp_s, rt<<4, lane, 1);
        #pragma unroll
        for (int dt=0;dt<4;dt++){
          Oac[j][dt]=__builtin_amdgcn_mfma_f32_16x16x32_bf16(p0,vf[dt][0],Oac[j][dt],0,0,0);
          Oac[j][dt]=__builtin_amdgcn_mfma_f32_16x16x32_bf16(p1,vf[dt][1],Oac[j][dt],0,0,0);
        }
      }
    }
    __syncthreads();
  }

  float inv[2][4];
  #pragma unroll
  for(int j=0;j<2;j++)
    #pragma unroll
    for(int i=0;i<4;i++){
      float v=rsum[j][i];
      v += __shfl_xor(v,1); v += __shfl_xor(v,2); v += __shfl_xor(v,4); v += __shfl_xor(v,8);
      inv[j][i]=1.f/v;
    }

  #pragma unroll
  for (int j=0;j<2;j++){
    const int rt=w+(j<<3);
    if (rt < LT){
      const int rb=(rt<<4)+(lhi<<2);
      #pragma unroll
      for (int dt=0;dt<4;dt++)
        #pragma unroll
        for (int i=0;i<4;i++)
          q_s[swzo(rb+i,(dt<<4)+l15)] = (short)f2bu(Oac[j][dt][i]*inv[j][i]);
    }
  }
  __syncthreads();

  f32x4 h1[2][4];
  #pragma unroll
  for (int j=0;j<2;j++){
    const int rt=w+(j<<3);
    if (rt < LT){
      s16x8 a0=ldfrag(q_s, rt<<4, lane, 0);
      s16x8 a1=ldfrag(q_s, rt<<4, lane, 1);
      const int rb=(rt<<4)+(lhi<<2);
      #pragma unroll
      for (int dt=0;dt<4;dt++){
        const int col=(dt<<4)+l15;
        const short* wb = Wo_t + (col<<6) + (lhi<<3);
        s16x8 b0=*(const s16x8*)wb, b1v=*(const s16x8*)(wb+32);
        float bias=bo[col];
        f32x4 acc={bias,bias,bias,bias};
        acc=__builtin_amdgcn_mfma_f32_16x16x32_bf16(a0,b0,acc,0,0,0);
        acc=__builtin_amdgcn_mfma_f32_16x16x32_bf16(a1,b1v,acc,0,0,0);
        #pragma unroll
        for(int i=0;i<4;i++){
          const int row=rb+i;
          acc[i]+= fmaf(valr[row],proj_w[col], fmaf(obsr[row],proj_w[64+col], proj_b[col]))
                 + pe_g[(((size_t)b<<8)+row)*64+col];
        }
        h1[j][dt]=acc;
      }
      f32x4 mu, rsq;
      #pragma unroll
      for(int i=0;i<4;i++){
        float sv = h1[j][0][i]+h1[j][1][i]+h1[j][2][i]+h1[j][3][i];
        sv += __shfl_xor(sv,1); sv+=__shfl_xor(sv,2); sv+=__shfl_xor(sv,4); sv+=__shfl_xor(sv,8);
        mu[i]=sv*(1.f/64.f);
      }
      #pragma unroll
      for(int i=0;i<4;i++){
        float sv=0.f;
        #pragma unroll
        for(int dt=0;dt<4;dt++){ float c=h1[j][dt][i]-mu[i]; sv=fmaf(c,c,sv); }
        sv += __shfl_xor(sv,1); sv+=__shfl_xor(sv,2); sv+=__shfl_xor(sv,4); sv+=__shfl_xor(sv,8);
        rsq[i]=1.f/sqrtf(sv*(1.f/64.f)+1e-5f);
      }
      #pragma unroll
      for(int dt=0;dt<4;dt++){
        const int col=(dt<<4)+l15;
        float g=ln1g[col], bb=ln1b[col];
        #pragma unroll
        for(int i=0;i<4;i++){
          float hv=(h1[j][dt][i]-mu[i])*rsq[i]*g+bb;
          h1[j][dt][i]=hv;
          k_s[swzo(rb+i,col)] = (short)f2bu(hv);
        }
      }
    }
  }
  __syncthreads();

  #pragma unroll
  for (int j=0;j<2;j++){
    const int rt=w+(j<<3);
    if (rt < LT){
      s16x8 a0=ldfrag(k_s, rt<<4, lane, 0);
      s16x8 a1=ldfrag(k_s, rt<<4, lane, 1);
      const int rb=(rt<<4)+(lhi<<2);
      #pragma unroll
      for (int dt=0;dt<4;dt++){
        const int col=(dt<<4)+l15;
        const short* wb = W1_t + (col<<6)+(lhi<<3);
        s16x8 b0=*(const s16x8*)wb, b1v=*(const s16x8*)(wb+32);
        float bias=b1[col];
        f32x4 acc={bias,bias,bias,bias};
        acc=__builtin_amdgcn_mfma_f32_16x16x32_bf16(a0,b0,acc,0,0,0);
        acc=__builtin_amdgcn_mfma_f32_16x16x32_bf16(a1,b1v,acc,0,0,0);
        #pragma unroll
        for(int i=0;i<4;i++) tp_s[swzo(rb+i,col)]=(short)f2bu(fmaxf(acc[i],0.f));
      }
    }
  }
  __syncthreads();

  #pragma unroll
  for (int j=0;j<2;j++){
    const int rt=w+(j<<3);
    if (rt < LT){
      s16x8 a0=ldfrag(tp_s, rt<<4, lane, 0);
      s16x8 a1=ldfrag(tp_s, rt<<4, lane, 1);
      const int rb=(rt<<4)+(lhi<<2);
      f32x4 to[4];
      #pragma unroll
      for (int dt=0;dt<4;dt++){
        const int col=(dt<<4)+l15;
        const short* wb = W2_t + (col<<6)+(lhi<<3);
        s16x8 b0=*(const s16x8*)wb, b1v=*(const s16x8*)(wb+32);
        float bias=b2[col];
        f32x4 acc={bias,bias,bias,bias};
        acc=__builtin_amdgcn_mfma_f32_16x16x32_bf16(a0,b0,acc,0,0,0);
        acc=__builtin_amdgcn_mfma_f32_16x16x32_bf16(a1,b1v,acc,0,0,0);
        acc += h1[j][dt];
        to[dt]=acc;
      }
      f32x4 mu, rsq;
      #pragma unroll
      for(int i=0;i<4;i++){
        float sv = to[0][i]+to[1][i]+to[2][i]+to[3][i];
        sv += __shfl_xor(sv,1); sv+=__shfl_xor(sv,2); sv+=__shfl_xor(sv,4); sv+=__shfl_xor(sv,8);
        mu[i]=sv*(1.f/64.f);
      }
      #pragma unroll
      for(int i=0;i<4;i++){
        float sv=0.f;
        #pragma unroll
        for(int dt=0;dt<4;dt++){ float c=to[dt][i]-mu[i]; sv=fmaf(c,c,sv); }
        sv += __shfl_xor(sv,1); sv+=__shfl_xor(sv,2); sv+=__shfl_xor(sv,4); sv+=__shfl_xor(sv,8);
        rsq[i]=1.f/sqrtf(sv*(1.f/64.f)+1e-5f);
      }
      #pragma unroll
      for(int dt=0;dt<4;dt++){
        const int col=(dt<<4)+l15;
        float g=ln2g[col], bb=ln2b[col];
        #pragma unroll
        for(int i=0;i<4;i++){
          const int row=rb+i;
          if (row < len){
            float tv=(to[dt][i]-mu[i])*rsq[i]*g+bb;
            float tin = fmaf(valr[row],proj_w[col], fmaf(obsr[row],proj_w[64+col], proj_b[col]))
                      + pe_g[(((size_t)b<<8)+row)*64+col];
            float ob = obsr[row];
            xtat[((size_t)bn<<14)+(row<<6)+col] = f2bu(ob*tin + (1.f-ob)*tv);
          }
        }
      }
    }
  }
}

// ---------------------------------------------------------------------------
// K35: precompute xt-dependent gate terms + fold u1+rs*u2.
//   Xall[b,t,g,d,n] (bf16) = (xt@Wg_x + (A@xt)@Wg_ax)[n,d] + u1g[d] + rs[n]*u2g[d]
// ---------------------------------------------------------------------------
__global__ void k35_xg(const unsigned short* __restrict__ xtat, const short* __restrict__ Abf,
                       const short* __restrict__ Wg_t, const int* __restrict__ lengths,
                       const float* __restrict__ U, const float* __restrict__ rs_g,
                       unsigned short* __restrict__ Xall)
{
  const int bt = blockIdx.x, b = bt>>8, t = bt&255;
  int len = lengths[b]; if (len<1) len=1;
  if (t >= len) return;
  const int tid = threadIdx.x, w = tid>>6, lane = tid&63;
  const int l15 = lane&15, lhi = lane>>4;
  __shared__ short xt_rm[4096], xt_tp[4096], axt_rm[4096];

  // load xt[n][d] = xtat[b,n,t,:]
  #pragma unroll
  for (int q=0;q<2;q++){
    int e = tid + (q<<8);
    int nn = e>>3, c0 = (e&7)<<3;
    s16x8 v = *(const s16x8*)((const short*)xtat + (((size_t)(b*64+nn)*256 + t)<<6) + c0);
    *(s16x8*)(xt_rm + swzo(nn,c0)) = v;
    #pragma unroll
    for (int jj=0;jj<8;jj++) xt_tp[swzo(c0+jj, nn)] = v[jj];
  }
  __syncthreads();

  // Axt = A @ xt ; wave w computes col-tile w (all 4 row tiles)
  {
    s16x8 bx[2];
    #pragma unroll
    for (int kk=0;kk<2;kk++) bx[kk]=ldfrag(xt_tp, w<<4, lane, kk);
    #pragma unroll
    for (int rt=0;rt<4;rt++){
      f32x4 acc={0.f,0.f,0.f,0.f};
      #pragma unroll
      for (int kk=0;kk<2;kk++){
        s16x8 af = *(const s16x8*)(Abf + ((rt<<4)+l15)*64 + (kk<<5) + (lhi<<3));
        acc=__builtin_amdgcn_mfma_f32_16x16x32_bf16(af,bx[kk],acc,0,0,0);
      }
      const int rb=(rt<<4)+(lhi<<2);
      #pragma unroll
      for(int i=0;i<4;i++) axt_rm[swzo(rb+i,(w<<4)+l15)] = (short)f2bu(acc[i]);
    }
  }
  __syncthreads();

  // Xg = xt@Wg_x + Axt@Wg_ax ; wave w -> out col-tile w for each gate
  s16x8 fx[4][2], fa[4][2];
  #pragma unroll
  for (int rt=0;rt<4;rt++)
    #pragma unroll
    for (int kk=0;kk<2;kk++){
      fx[rt][kk]=ldfrag(xt_rm, rt<<4, lane, kk);
      fa[rt][kk]=ldfrag(axt_rm, rt<<4, lane, kk);
    }
  const int dcol = (w<<4)+l15;
  f32x4 rsv[4];
  #pragma unroll
  for (int rt=0;rt<4;rt++) rsv[rt] = *(const f32x4*)(rs_g + (rt<<4) + (lhi<<2));
  const float* Ub = U + (size_t)bt*384;
  #pragma unroll
  for (int g=0; g<3; g++){
    s16x8 wbx[2], wba[2];
    #pragma unroll
    for (int kk=0;kk<2;kk++){
      wbx[kk] = *(const s16x8*)(Wg_t + (((g<<1)  )*64 + dcol)*64 + (kk<<5)+(lhi<<3));
      wba[kk] = *(const s16x8*)(Wg_t + (((g<<1)+1)*64 + dcol)*64 + (kk<<5)+(lhi<<3));
    }
    float u1 = Ub[(g<<7) + dcol];
    float u2 = Ub[(g<<7) + 64 + dcol];
    #pragma unroll
    for (int rt=0;rt<4;rt++){
      f32x4 acc={u1,u1,u1,u1};
      #pragma unroll
      for (int kk=0;kk<2;kk++){
        acc=__builtin_amdgcn_mfma_f32_16x16x32_bf16(fx[rt][kk],wbx[kk],acc,0,0,0);
        acc=__builtin_amdgcn_mfma_f32_16x16x32_bf16(fa[rt][kk],wba[kk],acc,0,0,0);
      }
      s16x4 pk;
      #pragma unroll
      for(int i=0;i<4;i++) pk[i]=(short)f2bu(acc[i] + rsv[rt][i]*u2);
      *(s16x4*)((short*)Xall + (((size_t)bt*3 + g)*64 + dcol)*64 + (rt<<4)+(lhi<<2)) = pk;
    }
  }
}

// ---------------------------------------------------------------------------
// K4: graph-GRU scan (R8-proven config: 512 thr, 8 waves, 1 batch/block,
//     4 raw barriers/step, DPP+cvt_pk packed staging, X prefetched 1 ahead).
//     612us measured, VGPR 108.
// ---------------------------------------------------------------------------
__launch_bounds__(512, 1)
__global__ void k4_scan(const unsigned short* __restrict__ Xall,
                        const float* __restrict__ decay, const short* __restrict__ Abf,
                        const short* __restrict__ Wg_h,
                        const int* __restrict__ lengths, float* __restrict__ hT)
{
  const int b = blockIdx.x, tid = threadIdx.x;
  const int w = tid>>6, lane = tid&63;
  const int l15 = lane&15, lhi = lane>>4;
  const int pe_ = l15&1;
  // gate partition: n-tile rnt, d-tile pair dp
  const int rnt = w>>1, dp = w&1;
  const int nb_ = (rnt<<4) + (lhi<<2);
  const int d0 = (dp<<5) + l15, d1 = (dp<<5) + 16 + l15;
  // A-mult partition: n-tile pair (tmA0,tmA1), d-tile dnA
  const int tmA0 = (w&1)<<1, tmA1 = tmA0+1;
  const int dnA = w>>1;

  __shared__ short h_rm[4096], h_tp[4096], ah_rm[4096];
  __shared__ short rh_rm[4096], rh_tp[4096], arh_rm[4096];
  __shared__ float dec_s[256];

  int len = lengths[b]; if (len<1) len=1;
  for (int e=tid; e<256; e+=512) dec_s[e] = decay[b*256+e];

  // static A fragments (A-operand rows tmA0/tmA1)
  s16x8 aA[2][2];
  #pragma unroll
  for (int t2=0;t2<2;t2++)
    #pragma unroll
    for (int kk=0;kk<2;kk++)
      aA[t2][kk] = *(const s16x8*)(Abf + (((t2?tmA1:tmA0)<<4) + l15)*64 + (kk<<5) + (lhi<<3));

  // static gate weight B-frags: wf[g][s][kk][e]  (s=0: h slice, s=1: Ah slice)
  s16x8 wf[3][2][2][2];
  #pragma unroll
  for (int g=0;g<3;g++)
    #pragma unroll
    for (int s=0;s<2;s++)
      #pragma unroll
      for (int kk=0;kk<2;kk++)
        #pragma unroll
        for (int e=0;e<2;e++)
          wf[g][s][kk][e] = *(const s16x8*)(Wg_h + (((g*2+s)*64 + (e?d1:d0))<<6) + (kk<<5) + (lhi<<3));

  // ---- precomputed LDS byte offsets (loop-invariant) ----
  int tpo[2];
  #pragma unroll
  for (int e=0;e<2;e++){ int r = e?d1:d0; tpo[e] = r*128 + (((nb_)*2) ^ ((r&7)<<4)); }
  int rmo[4];
  { int dPr = ((dp<<1) + pe_)*16 + (l15 & ~1);
    #pragma unroll
    for (int i=0;i<4;i++){ int n = nb_+i; rmo[i] = n*128 + ((dPr*2) ^ ((n&7)<<4)); } }
  int amo[4];
  { int dAr = (dnA<<4) + (l15 & ~1);
    int tb = (pe_? tmA1 : tmA0)<<4;
    #pragma unroll
    for (int i=0;i<4;i++){ int n = tb + (lhi<<2) + i; amo[i] = n*128 + ((dAr*2) ^ ((n&7)<<4)); } }
  int rdT[2], rdR[2];
  { int r = (dnA<<4)+l15;
    #pragma unroll
    for (int kk=0;kk<2;kk++) rdT[kk] = r*128 + (((kk<<6) + (lhi<<4)) ^ ((r&7)<<4)); }
  { int r = (rnt<<4)+l15;
    #pragma unroll
    for (int kk=0;kk<2;kk++) rdR[kk] = r*128 + (((kk<<6) + (lhi<<4)) ^ ((r&7)<<4)); }

  f32x4 hreg[2] = {{0.f,0.f,0.f,0.f},{0.f,0.f,0.f,0.f}};
  f32x4 zz[2];

  const short* Xb = (const short*)Xall;
  s16x4 xzc[2], xrc[2], xcc[2], xzn[2], xrn[2], xcn[2];
  #pragma unroll
  for (int e=0;e<2;e++){ xzc[e]=(s16x4){0,0,0,0}; xrc[e]=xzc[e]; xcc[e]=xzc[e]; }
  {
    const short* base = Xb + ((size_t)(b*256))*12288;
    #pragma unroll
    for (int e=0;e<2;e++){
      int de = e?d1:d0;
      xzc[e] = *(const s16x4*)(base + (0*64 + de)*64 + nb_);
      xrc[e] = *(const s16x4*)(base + (1*64 + de)*64 + nb_);
      xcc[e] = *(const s16x4*)(base + (2*64 + de)*64 + nb_);
    }
  }
  __syncthreads();

  for (int t=0; t<len; t++){
    // decay
    float dc = dec_s[t];
    #pragma unroll
    for (int e=0;e<2;e++)
      #pragma unroll
      for (int i=0;i<4;i++) hreg[e][i] *= dc;

    // prefetch X for t+1 (stays in flight across raw barriers)
    #pragma unroll
    for (int e=0;e<2;e++){ xzn[e]=(s16x4){0,0,0,0}; xrn[e]=xzn[e]; xcn[e]=xzn[e]; }
    if (t+1 < len){
      const short* base = Xb + ((size_t)(b*256 + t+1))*12288;
      #pragma unroll
      for (int e=0;e<2;e++){
        int de = e?d1:d0;
        xzn[e] = *(const s16x4*)(base + (0*64 + de)*64 + nb_);
        xrn[e] = *(const s16x4*)(base + (1*64 + de)*64 + nb_);
        xcn[e] = *(const s16x4*)(base + (2*64 + de)*64 + nb_);
      }
    }

    // ---- P0: stage h (tp: b64 per e; rm: b32 pair via DPP) ----
    #pragma unroll
    for (int e=0;e<2;e++){
      i32x2 v; v[0] = (int)cvtpk(hreg[e][0], hreg[e][1]);
               v[1] = (int)cvtpk(hreg[e][2], hreg[e][3]);
      *(i32x2*)((char*)h_tp + tpo[e]) = v;
    }
    #pragma unroll
    for (int i=0;i<4;i++){
      float v0 = hreg[0][i], v1 = hreg[1][i];
      float n0 = dppx1(v0), n1 = dppx1(v1);
      float lo = pe_ ? n1 : v0;
      float hi = pe_ ? v1 : n0;
      *(unsigned*)((char*)h_rm + rmo[i]) = cvtpk(lo, hi);
    }
    BAR();

    // ---- P1: Ah = A@h -> ah_rm ----
    {
      s16x8 bh0 = *(const s16x8*)((const char*)h_tp + rdT[0]);
      s16x8 bh1 = *(const s16x8*)((const char*)h_tp + rdT[1]);
      f32x4 a0v={0.f,0.f,0.f,0.f}, a1v={0.f,0.f,0.f,0.f};
      a0v = __builtin_amdgcn_mfma_f32_16x16x32_bf16(aA[0][0], bh0, a0v, 0,0,0);
      a0v = __builtin_amdgcn_mfma_f32_16x16x32_bf16(aA[0][1], bh1, a0v, 0,0,0);
      a1v = __builtin_amdgcn_mfma_f32_16x16x32_bf16(aA[1][0], bh0, a1v, 0,0,0);
      a1v = __builtin_amdgcn_mfma_f32_16x16x32_bf16(aA[1][1], bh1, a1v, 0,0,0);
      #pragma unroll
      for (int i=0;i<4;i++){
        float n0 = dppx1(a0v[i]), n1 = dppx1(a1v[i]);
        float lo = pe_ ? n1 : a0v[i];
        float hi = pe_ ? a1v[i] : n0;
        *(unsigned*)((char*)ah_rm + amo[i]) = cvtpk(lo, hi);
      }
    }
    BAR();

    // ---- P2: z,r gates ----
    {
      s16x8 fh0 = *(const s16x8*)((const char*)h_rm  + rdR[0]);
      s16x8 fh1 = *(const s16x8*)((const char*)h_rm  + rdR[1]);
      s16x8 fa0 = *(const s16x8*)((const char*)ah_rm + rdR[0]);
      s16x8 fa1 = *(const s16x8*)((const char*)ah_rm + rdR[1]);
      f32x4 gz[2], gr[2], rh[2];
      #pragma unroll
      for (int e=0;e<2;e++)
        #pragma unroll
        for (int i=0;i<4;i++){ gz[e][i]=bs2f(xzc[e][i]); gr[e][i]=bs2f(xrc[e][i]); }
      #pragma unroll
      for (int e=0;e<2;e++){
        gz[e] = __builtin_amdgcn_mfma_f32_16x16x32_bf16(fh0, wf[0][0][0][e], gz[e], 0,0,0);
        gz[e] = __builtin_amdgcn_mfma_f32_16x16x32_bf16(fh1, wf[0][0][1][e], gz[e], 0,0,0);
        gz[e] = __builtin_amdgcn_mfma_f32_16x16x32_bf16(fa0, wf[0][1][0][e], gz[e], 0,0,0);
        gz[e] = __builtin_amdgcn_mfma_f32_16x16x32_bf16(fa1, wf[0][1][1][e], gz[e], 0,0,0);
        gr[e] = __builtin_amdgcn_mfma_f32_16x16x32_bf16(fh0, wf[1][0][0][e], gr[e], 0,0,0);
        gr[e] = __builtin_amdgcn_mfma_f32_16x16x32_bf16(fh1, wf[1][0][1][e], gr[e], 0,0,0);
        gr[e] = __builtin_amdgcn_mfma_f32_16x16x32_bf16(fa0, wf[1][1][0][e], gr[e], 0,0,0);
        gr[e] = __builtin_amdgcn_mfma_f32_16x16x32_bf16(fa1, wf[1][1][1][e], gr[e], 0,0,0);
      }
      #pragma unroll
      for (int e=0;e<2;e++)
        #pragma unroll
        for (int i=0;i<4;i++){
          float zv = 1.f/(1.f+__expf(-gz[e][i]));
          float rv = 1.f/(1.f+__expf(-gr[e][i]));
          zz[e][i] = zv;
          rh[e][i] = rv * hreg[e][i];
        }
      // stage rh: tp b64 per e + rm b32 pairs via DPP
      #pragma unroll
      for (int e=0;e<2;e++){
        i32x2 v; v[0] = (int)cvtpk(rh[e][0], rh[e][1]);
                 v[1] = (int)cvtpk(rh[e][2], rh[e][3]);
        *(i32x2*)((char*)rh_tp + tpo[e]) = v;
      }
      #pragma unroll
      for (int i=0;i<4;i++){
        float v0 = rh[0][i], v1 = rh[1][i];
        float n0 = dppx1(v0), n1 = dppx1(v1);
        float lo = pe_ ? n1 : v0;
        float hi = pe_ ? v1 : n0;
        *(unsigned*)((char*)rh_rm + rmo[i]) = cvtpk(lo, hi);
      }
    }
    BAR();

    // ---- P3: Arh = A@rh -> arh_rm ----
    {
      s16x8 br0 = *(const s16x8*)((const char*)rh_tp + rdT[0]);
      s16x8 br1 = *(const s16x8*)((const char*)rh_tp + rdT[1]);
      f32x4 a0v={0.f,0.f,0.f,0.f}, a1v={0.f,0.f,0.f,0.f};
      a0v = __builtin_amdgcn_mfma_f32_16x16x32_bf16(aA[0][0], br0, a0v, 0,0,0);
      a0v = __builtin_amdgcn_mfma_f32_16x16x32_bf16(aA[0][1], br1, a0v, 0,0,0);
      a1v = __builtin_amdgcn_mfma_f32_16x16x32_bf16(aA[1][0], br0, a1v, 0,0,0);
      a1v = __builtin_amdgcn_mfma_f32_16x16x32_bf16(aA[1][1], br1, a1v, 0,0,0);
      #pragma unroll
      for (int i=0;i<4;i++){
        float n0 = dppx1(a0v[i]), n1 = dppx1(a1v[i]);
        float lo = pe_ ? n1 : a0v[i];
        float hi = pe_ ? a1v[i] : n0;
        *(unsigned*)((char*)arh_rm + amo[i]) = cvtpk(lo, hi);
      }
    }
    BAR();

    // ---- P4: c gate + h update ----
    {
      s16x8 fr0 = *(const s16x8*)((const char*)rh_rm  + rdR[0]);
      s16x8 fr1 = *(const s16x8*)((const char*)rh_rm  + rdR[1]);
      s16x8 fb0 = *(const s16x8*)((const char*)arh_rm + rdR[0]);
      s16x8 fb1 = *(const s16x8*)((const char*)arh_rm + rdR[1]);
      f32x4 gc[2];
      #pragma unroll
      for (int e=0;e<2;e++)
        #pragma unroll
        for (int i=0;i<4;i++) gc[e][i]=bs2f(xcc[e][i]);
      #pragma unroll
      for (int e=0;e<2;e++){
        gc[e] = __builtin_amdgcn_mfma_f32_16x16x32_bf16(fr0, wf[2][0][0][e], gc[e], 0,0,0);
        gc[e] = __builtin_amdgcn_mfma_f32_16x16x32_bf16(fr1, wf[2][0][1][e], gc[e], 0,0,0);
        gc[e] = __builtin_amdgcn_mfma_f32_16x16x32_bf16(fb0, wf[2][1][0][e], gc[e], 0,0,0);
        gc[e] = __builtin_amdgcn_mfma_f32_16x16x32_bf16(fb1, wf[2][1][1][e], gc[e], 0,0,0);
      }
      #pragma unroll
      for (int e=0;e<2;e++)
        #pragma unroll
        for (int i=0;i<4;i++){
          float cv = 1.f - 2.f/(__expf(2.f*gc[e][i])+1.f);   // tanh
          hreg[e][i] = fmaf(zz[e][i], hreg[e][i]-cv, cv);
        }
    }

    // rotate prefetch
    #pragma unroll
    for (int e=0;e<2;e++){ xzc[e]=xzn[e]; xrc[e]=xrn[e]; xcc[e]=xcn[e]; }
  }

  // suffix decay for t in [len,256)
  float sp = 1.f;
  for (int t=len; t<256; t++) sp *= dec_s[t];
  #pragma unroll
  for (int e=0;e<2;e++)
    #pragma unroll
    for (int i=0;i<4;i++)
      hT[(((size_t)b<<6) + nb_ + i)*64 + (e?d1:d0)] = hreg[e][i]*sp;
}

// ---------------------------------------------------------------------------
// K5: classifier head
// ---------------------------------------------------------------------------
__global__ void k5_head(const float* __restrict__ hT, const float* __restrict__ Wfin,
                        const float* __restrict__ bfin,
                        const float* __restrict__ stat, const float* __restrict__ We,
                        const float* __restrict__ be,
                        const float* __restrict__ Wc1, const float* __restrict__ bc1,
                        const float* __restrict__ Wc2, const float* __restrict__ bc2,
                        float* __restrict__ out)
{
  const int b = blockIdx.x, tid = threadIdx.x;
  __shared__ float cat[128];
  __shared__ float hcl[200];
  if (tid < 64){
    const float* hr = hT + (((size_t)b<<6)+tid)*64;
    float a = bfin[0];
    #pragma unroll
    for (int d=0;d<64;d++) a = fmaf(hr[d], Wfin[d], a);
    cat[tid]=a;
  } else if (tid < 128){
    int nn = tid-64;
    float a = be[nn];
    #pragma unroll
    for (int k=0;k<9;k++) a = fmaf(stat[b*9+k], We[k*64+nn], a);
    cat[tid]=a;
  }
  __syncthreads();
  if (tid < 200){
    float a = bc1[tid];
    for (int k=0;k<128;k++) a = fmaf(cat[k], Wc1[k*200+tid], a);
    hcl[tid] = fmaxf(a, 0.f);
  }
  __syncthreads();
  if (tid < 2){
    float a = bc2[tid];
    for (int k=0;k<200;k++) a = fmaf(hcl[k], Wc2[k*2+tid], a);
    out[b*2+tid] = a;
  }
}

// ---------------------------------------------------------------------------
extern "C" void kernel_launch(void* const* d_in, const int* in_sizes, int n_in,
                              void* d_out, int out_size, void* d_ws, size_t ws_size,
                              hipStream_t stream)
{
  const float* x       = (const float*)d_in[0];
  const float* nufft   = (const float*)d_in[1];
  const float* delta_t = (const float*)d_in[2];
  const float* stat    = (const float*)d_in[3];
  const int*   lengths = (const int*)  d_in[4];
  const float* proj_w  = (const float*)d_in[5];
  const float* proj_b  = (const float*)d_in[6];
  const float* Wqkv    = (const float*)d_in[7];
  const float* bqkv    = (const float*)d_in[8];
  const float* Wo      = (const float*)d_in[9];
  const float* bo      = (const float*)d_in[10];
  const float* ln1g    = (const float*)d_in[11];
  const float* ln1b    = (const float*)d_in[12];
  const float* W1      = (const float*)d_in[13];
  const float* b1      = (const float*)d_in[14];
  const float* W2      = (const float*)d_in[15];
  const float* b2      = (const float*)d_in[16];
  const float* ln2g    = (const float*)d_in[17];
  const float* ln2b    = (const float*)d_in[18];
  const float* WQf     = (const float*)d_in[19];
  const float* WKf     = (const float*)d_in[20];
  const float* Wz      = (const float*)d_in[21];
  const float* bz      = (const float*)d_in[22];
  const float* Wr      = (const float*)d_in[23];
  const float* br      = (const float*)d_in[24];
  const float* Wc      = (const float*)d_in[25];
  const float* bc      = (const float*)d_in[26];
  const float* Wfin    = (const float*)d_in[27];
  const float* bfin    = (const float*)d_in[28];
  const float* We      = (const float*)d_in[29];
  const float* be      = (const float*)d_in[30];
  const float* Wc1     = (const float*)d_in[31];
  const float* bc1     = (const float*)d_in[32];
  const float* Wc2     = (const float*)d_in[33];
  const float* bc2     = (const float*)d_in[34];
  float* out = (float*)d_out;

  char* ws = (char*)d_ws;
  size_t o = 0;
  float* pe    = (float*)(ws+o); o += (size_t)4096*64*4;
  float* U     = (float*)(ws+o); o += (size_t)4096*384*4;
  float* decay = (float*)(ws+o); o += (size_t)4096*4;
  unsigned short* xtat = (unsigned short*)(ws+o); o += (size_t)1024*256*64*2;
  float* qf    = (float*)(ws+o); o += (size_t)1024*256*4;
  float* kf    = (float*)(ws+o); o += (size_t)1024*256*4;
  float* soft  = (float*)(ws+o); o += (size_t)16*4096*4;
  short* Abf   = (short*)(ws+o); o += (size_t)4096*2;
  float* rs    = (float*)(ws+o); o += (size_t)64*4;
  float* hT    = (float*)(ws+o); o += (size_t)16*64*64*4;
  short* Wqkv_t= (short*)(ws+o); o += (size_t)12288*2;
  short* Wo_t  = (short*)(ws+o); o += (size_t)4096*2;
  short* W1_t  = (short*)(ws+o); o += (size_t)4096*2;
  short* W2_t  = (short*)(ws+o); o += (size_t)4096*2;
  short* Wg_t  = (short*)(ws+o); o += (size_t)24576*2;
  short* Wg_h  = (short*)(ws+o); o += (size_t)24576*2;
  unsigned short* Xall = (unsigned short*)(ws+o); o += (size_t)4096*3*4096*2;  // ~100 MB
  (void)ws_size; (void)in_sizes; (void)n_in; (void)out_size;

  hipLaunchKernelGGL(k1_pe_u,   dim3(1024), dim3(256), 0, stream,
                     x, delta_t, Wz, bz, Wr, br, Wc, bc,
                     Wqkv, Wo, W1, W2, Wqkv_t, Wo_t, W1_t, W2_t, Wg_t, Wg_h,
                     pe, U, decay);
  hipLaunchKernelGGL(k2a_qfkf,  dim3(1024), dim3(256), 0, stream,
                     nufft, WQf, WKf, qf, kf);
  hipLaunchKernelGGL(k2b_soft,  dim3(16),   dim3(256), 0, stream, qf, kf, soft);
  hipLaunchKernelGGL(k2c_A,     dim3(1),    dim3(256), 0, stream, soft, Abf, rs);
  hipLaunchKernelGGL(k3_former, dim3(1024), dim3(512), 0, stream,
                     x, pe, proj_w, proj_b, Wqkv_t, bqkv, Wo_t, bo, ln1g, ln1b,
                     W1_t, b1, W2_t, b2, ln2g, ln2b, lengths, xtat);
  hipLaunchKernelGGL(k35_xg,    dim3(4096), dim3(256), 0, stream,
                     xtat, Abf, Wg_t, lengths, U, rs, Xall);
  hipLaunchKernelGGL(k4_scan,   dim3(16),   dim3(512), 0, stream,
                     Xall, decay, Abf, Wg_h, lengths, hT);
  hipLaunchKernelGGL(k5_head,   dim3(16),   dim3(256), 0, stream,
                     hT, Wfin, bfin, stat, We, be, Wc1, bc1, Wc2, bc2, out);
}